// Round 8
// baseline (406.176 us; speedup 1.0000x reference)
//
#include <hip/hip_runtime.h>
#include <hip/hip_bf16.h>

#define BB 128
#define LL 512
#define DW 256
#define DP 64
#define NF 512
#define DD 384       // D = DW + 2*DP
#define DWIN 1152    // 3*D
#define RR 512       // nr
#define LP 514       // LL + 2 pad rows

typedef __attribute__((ext_vector_type(8))) short short8;
typedef __attribute__((ext_vector_type(4))) short short4v;
typedef __attribute__((ext_vector_type(8))) _Float16 half8;
typedef __attribute__((ext_vector_type(4))) float f32x4;

typedef __attribute__((address_space(1))) const void* gas_t;
typedef __attribute__((address_space(3))) void* las_t;

__device__ __forceinline__ void stage16(const void* g, void* l) {
    __builtin_amdgcn_global_load_lds((gas_t)g, (las_t)l, 16, 0, 0);
}

__device__ inline short f2b(float v) {
    __hip_bfloat16 h = __float2bfloat16(v);
    return *reinterpret_cast<short*>(&h);
}
__device__ inline float b2f(short s) {
    unsigned u = ((unsigned)(unsigned short)s) << 16;
    return __uint_as_float(u);
}
// XCD-chunked bijective swizzle (nwg % 8 == 0)
__device__ inline int xcd_swz(int bid, int nwg) {
    return (bid & 7) * (nwg >> 3) + (bid >> 3);
}

// ---------- small kernels (fp32-exact path for alpha) ----------
__global__ void k_ve(const float* __restrict__ We1, const float* __restrict__ We2,
                     const float* __restrict__ e1, const float* __restrict__ e2,
                     float* __restrict__ v1, float* __restrict__ v2) {
    int b = blockIdx.x;
    int d = threadIdx.x; // 256
    __shared__ float s1[DW], s2[DW];
    s1[d] = e1[b * DW + d];
    s2[d] = e2[b * DW + d];
    __syncthreads();
    float a1 = 0.f, a2 = 0.f;
    for (int e = 0; e < DW; ++e) {
        a1 += We1[d * DW + e] * s1[e];
        a2 += We2[d * DW + e] * s2[e];
    }
    v1[b * DW + d] = a1;
    v2[b * DW + d] = a2;
}

__global__ __launch_bounds__(256) void k_logits(
    const float* __restrict__ x,
    const float* __restrict__ v1, const float* __restrict__ v2,
    float* __restrict__ A1, float* __restrict__ A2) {
    int row = blockIdx.x * 4 + (threadIdx.x >> 6);   // b*LL + l
    int lane = threadIdx.x & 63;
    int b = row >> 9;
    f32x4 xv = *(const f32x4*)(x + (size_t)row * DW + lane * 4);
    f32x4 w1 = *(const f32x4*)(v1 + b * DW + lane * 4);
    f32x4 w2 = *(const f32x4*)(v2 + b * DW + lane * 4);
    float p1 = xv[0] * w1[0] + xv[1] * w1[1] + xv[2] * w1[2] + xv[3] * w1[3];
    float p2 = xv[0] * w2[0] + xv[1] * w2[1] + xv[2] * w2[2] + xv[3] * w2[3];
    for (int off = 32; off; off >>= 1) {
        p1 += __shfl_down(p1, off);
        p2 += __shfl_down(p2, off);
    }
    if (lane == 0) { A1[row] = p1; A2[row] = p2; }
}

__global__ void k_alpha(const float* __restrict__ A1, const float* __restrict__ A2,
                        float* __restrict__ alpha) {
    int b = blockIdx.x;
    int l = threadIdx.x; // 512
    __shared__ float s[LL];
    float a1 = A1[b * LL + l], a2 = A2[b * LL + l];

    s[l] = a1; __syncthreads();
    for (int st = 256; st; st >>= 1) { if (l < st) s[l] = fmaxf(s[l], s[l + st]); __syncthreads(); }
    float m1 = s[0]; __syncthreads();
    float e1x = expf(a1 - m1);
    s[l] = e1x; __syncthreads();
    for (int st = 256; st; st >>= 1) { if (l < st) s[l] += s[l + st]; __syncthreads(); }
    float d1 = s[0]; __syncthreads();

    s[l] = a2; __syncthreads();
    for (int st = 256; st; st >>= 1) { if (l < st) s[l] = fmaxf(s[l], s[l + st]); __syncthreads(); }
    float m2 = s[0]; __syncthreads();
    float e2x = expf(a2 - m2);
    s[l] = e2x; __syncthreads();
    for (int st = 256; st; st >>= 1) { if (l < st) s[l] += s[l + st]; __syncthreads(); }
    float d2 = s[0];

    alpha[b * LL + l] = 0.5f * (e1x / d1 + e2x / d2);
}

// ---------- packing: px_pad[b][row][d] bf16, rows 0 and 513 zero ----------
__global__ __launch_bounds__(256) void k_pack_px(const float* __restrict__ x,
                                                 const float* __restrict__ pv,
                                                 short* __restrict__ pxp) {
    int idx = blockIdx.x * 256 + threadIdx.x;   // 128*514*48 = 3,158,016
    int d8 = (idx % 48) * 8;
    int row = (idx / 48) % LP;
    int b = idx / (48 * LP);
    short8 v = (short8){0, 0, 0, 0, 0, 0, 0, 0};
    if (row >= 1 && row <= LL) {
        int l = row - 1;
        const float* src = (d8 < DW) ? (x + ((size_t)b * LL + l) * DW + d8)
                                     : (pv + ((size_t)b * LL + l) * (2 * DP) + (d8 - DW));
        f32x4 u0 = *(const f32x4*)(src);
        f32x4 u1 = *(const f32x4*)(src + 4);
#pragma unroll
        for (int jj = 0; jj < 4; ++jj) { v[jj] = f2b(u0[jj]); v[jj + 4] = f2b(u1[jj]); }
    }
    *(short8*)(pxp + ((size_t)b * LP + row) * DD + d8) = v;
}

__global__ __launch_bounds__(256) void k_pack_w(const float* __restrict__ cw,
                                                short* __restrict__ cwb) {
    int idx = blockIdx.x * 256 + threadIdx.x;   // 512*1152/8 = 73,728
    const float* src = cw + (size_t)idx * 8;
    f32x4 u0 = *(const f32x4*)(src);
    f32x4 u1 = *(const f32x4*)(src + 4);
    short8 v;
#pragma unroll
    for (int jj = 0; jj < 4; ++jj) { v[jj] = f2b(u0[jj]); v[jj + 4] = f2b(u1[jj]); }
    *(short8*)(cwb + (size_t)idx * 8) = v;
}

// ---------- W2t[r][f] = sum_t rel_w[r,t]*U[f,t], split hi/lo bf16 ----------
__global__ void k_w2t(const float* __restrict__ U, const float* __restrict__ relw,
                      short* __restrict__ Qh, short* __restrict__ Ql) {
    __shared__ float As[16][65], Bs[16][65];
    int r0 = blockIdx.y * 64, f0 = blockIdx.x * 64;
    int tid = threadIdx.x, ty = tid >> 4, tx = tid & 15;
    float acc[4][4] = {};
    for (int k0 = 0; k0 < NF; k0 += 16) {
        for (int i = 0; i < 4; ++i) {
            int lin = tid + 256 * i;
            int kk = lin & 15, mm = lin >> 4;
            As[kk][mm] = relw[(r0 + mm) * NF + k0 + kk];
            Bs[kk][mm] = U[(f0 + mm) * NF + k0 + kk];
        }
        __syncthreads();
        for (int kk = 0; kk < 16; ++kk) {
            float av[4], bv[4];
            for (int i = 0; i < 4; ++i) av[i] = As[kk][ty * 4 + i];
            for (int j = 0; j < 4; ++j) bv[j] = Bs[kk][tx * 4 + j];
            for (int i = 0; i < 4; ++i)
                for (int j = 0; j < 4; ++j) acc[i][j] += av[i] * bv[j];
        }
        __syncthreads();
    }
    for (int i = 0; i < 4; ++i)
        for (int j = 0; j < 4; ++j) {
            float vv = acc[i][j];
            short hi = f2b(vv);
            size_t o = (size_t)(r0 + ty * 4 + i) * NF + f0 + tx * 4 + j;
            Qh[o] = hi;
            Ql[o] = f2b(vv - b2f(hi));
        }
}

// ---------- conv MFMA via global_load_lds, 2-phase double-buffered ----------
__global__ __launch_bounds__(256) void k_conv_mfma(
    const short* __restrict__ pxp, const short* __restrict__ cwb,
    const float* __restrict__ conv_b, const float* __restrict__ alpha,
    short* __restrict__ conv_lf, short* __restrict__ conv_fl) {
    int wg = xcd_swz(blockIdx.x, 2048);
    int b = wg >> 4;
    int l0 = ((wg >> 2) & 3) * 128;
    int f0 = (wg & 3) * 128;
    int tid = threadIdx.x;
    int lane = tid & 63, w = tid >> 6;
    int wm = w >> 1, wn = w & 1;
    int lr = lane & 15, lg = lane >> 4;

    // [0,32768): two staging buffers {As[128][32],Bs[128][32]} x2
    // epilogue reuses whole region as T[128][136] (34816B)
    __shared__ __align__(16) char smem[34816];
    short (*T)[136] = (short(*)[136])smem;

    f32x4 acc[4][4];
    for (int i = 0; i < 4; ++i)
        for (int j = 0; j < 4; ++j) acc[i][j] = (f32x4){0.f, 0.f, 0.f, 0.f};

    // staging geometry: wave w stages rows [w*32, w*32+32), 16 rows per call
    int rowA = lane >> 2;               // 0..15
    int sw = (lane & 3) ^ (rowA & 3);   // pre-swizzled source slot
    const short* gA = pxp + ((size_t)b * LP + l0 + w * 32 + rowA) * DD + sw * 8;
    const short* gB = cwb + (size_t)(f0 + w * 32 + rowA) * DWIN + sw * 8;
    int rsw = (lg ^ (lr & 3)) * 8;      // read-side swizzled slot offset
    int rA = wm * 64, rB = wn * 64;

    // prologue: stage tile 0 into buf 0
    {
        char* base = smem;
        stage16(gA, base + w * 2048);
        stage16(gA + 16 * DD, base + w * 2048 + 1024);
        stage16(gB, base + 8192 + w * 2048);
        stage16(gB + (size_t)16 * DWIN, base + 8192 + w * 2048 + 1024);
    }
    __syncthreads();

    for (int t = 0; t < 36; ++t) {
        if (t + 1 < 36) {
            int k0 = (t + 1) * 32;
            char* base = smem + ((t + 1) & 1) * 16384;
            stage16(gA + k0, base + w * 2048);
            stage16(gA + 16 * DD + k0, base + w * 2048 + 1024);
            stage16(gB + k0, base + 8192 + w * 2048);
            stage16(gB + (size_t)16 * DWIN + k0, base + 8192 + w * 2048 + 1024);
        }
        const short (*Ac)[32] = (const short(*)[32])(smem + (t & 1) * 16384);
        const short (*Bc)[32] = (const short(*)[32])(smem + (t & 1) * 16384 + 8192);
        short8 af[4], bf[4];
#pragma unroll
        for (int mi = 0; mi < 4; ++mi)
            af[mi] = *(const short8*)(&Ac[rA + mi * 16 + lr][rsw]);
#pragma unroll
        for (int ni = 0; ni < 4; ++ni)
            bf[ni] = *(const short8*)(&Bc[rB + ni * 16 + lr][rsw]);
#pragma unroll
        for (int mi = 0; mi < 4; ++mi)
#pragma unroll
            for (int ni = 0; ni < 4; ++ni)
                acc[mi][ni] = __builtin_amdgcn_mfma_f32_16x16x32_bf16(
                    af[mi], bf[ni], acc[mi][ni], 0, 0, 0);
        __syncthreads();   // drains prefetch (vmcnt 0) + releases buf[(t+1)&1] for next stage
    }
    // all LDS reads done (last barrier) -> safe to reuse smem as T

    int lbase = l0 + wm * 64, fbase = f0 + wn * 64;
#pragma unroll
    for (int mi = 0; mi < 4; ++mi) {
        f32x4 av = *(const f32x4*)(alpha + (size_t)b * LL + lbase + mi * 16 + lg * 4);
        int lrow = lbase + mi * 16 + lg * 4;
#pragma unroll
        for (int ni = 0; ni < 4; ++ni) {
            int f = fbase + ni * 16 + lr;
            float bias = conv_b[f];
            short4v o;
#pragma unroll
            for (int r = 0; r < 4; ++r) {
                float val = tanhf(av[r] * acc[mi][ni][r] + bias);
                short sv = f2b(val);
                o[r] = sv;
                conv_lf[((size_t)b * LL + lrow + r) * NF + f] = sv;
            }
            *(short4v*)(&T[wn * 64 + ni * 16 + lr][wm * 64 + mi * 16 + lg * 4]) = o;
        }
    }
    __syncthreads();
#pragma unroll
    for (int i = 0; i < 8; ++i) {
        int lin = tid + 256 * i;
        int frow = lin >> 4;
        int q = lin & 15;
        short8 v = *(const short8*)(&T[frow][q * 8]);
        *(short8*)(conv_fl + ((size_t)b * NF + f0 + frow) * LL + l0 + q * 8) = v;
    }
}

// ---------- G MFMA: Gp[b][r][l] = sum_f (Qh+Ql)[r,f]*conv_lf[b,l,f], f16 out ----------
__global__ __launch_bounds__(256) void k_g_mfma(
    const short* __restrict__ Qh, const short* __restrict__ Ql,
    const short* __restrict__ convlf, _Float16* __restrict__ Gp) {
    int wg = xcd_swz(blockIdx.x, 2048);
    int b = wg >> 4;
    int r0 = ((wg >> 2) & 3) * 128;   // M
    int l0 = (wg & 3) * 128;          // N
    int tid = threadIdx.x, lane = tid & 63, w = tid >> 6;
    int wm = w >> 1, wn = w & 1;
    int lr = lane & 15, lg = lane >> 4;

    __shared__ __align__(16) char smem[32768];

    f32x4 acc[4][4];
    for (int i = 0; i < 4; ++i)
        for (int j = 0; j < 4; ++j) acc[i][j] = (f32x4){0.f, 0.f, 0.f, 0.f};

    int rowA = lane >> 2;
    int sw = (lane & 3) ^ (rowA & 3);
    size_t aoff = (size_t)(r0 + w * 32 + rowA) * NF + sw * 8;
    const short* gB = convlf + (size_t)b * LL * NF + (size_t)(l0 + w * 32 + rowA) * NF + sw * 8;
    int rsw = (lg ^ (lr & 3)) * 8;
    int rA = wm * 64, rB = wn * 64;

    // tile t: A source = (t<16?Qh:Ql) + (t&15)*32
    {
        const short* gAt = Qh + aoff;
        char* base = smem;
        stage16(gAt, base + w * 2048);
        stage16(gAt + 16 * NF, base + w * 2048 + 1024);
        stage16(gB, base + 8192 + w * 2048);
        stage16(gB + 16 * NF, base + 8192 + w * 2048 + 1024);
    }
    __syncthreads();

    for (int t = 0; t < 32; ++t) {
        if (t + 1 < 32) {
            int tn = t + 1;
            const short* gAt = ((tn < 16) ? Qh : Ql) + aoff + (tn & 15) * 32;
            int f0k = (tn & 15) * 32;
            char* base = smem + (tn & 1) * 16384;
            stage16(gAt, base + w * 2048);
            stage16(gAt + 16 * NF, base + w * 2048 + 1024);
            stage16(gB + f0k, base + 8192 + w * 2048);
            stage16(gB + 16 * NF + f0k, base + 8192 + w * 2048 + 1024);
        }
        const short (*Ac)[32] = (const short(*)[32])(smem + (t & 1) * 16384);
        const short (*Bc)[32] = (const short(*)[32])(smem + (t & 1) * 16384 + 8192);
        short8 af[4], bf[4];
#pragma unroll
        for (int mi = 0; mi < 4; ++mi)
            af[mi] = *(const short8*)(&Ac[rA + mi * 16 + lr][rsw]);
#pragma unroll
        for (int ni = 0; ni < 4; ++ni)
            bf[ni] = *(const short8*)(&Bc[rB + ni * 16 + lr][rsw]);
#pragma unroll
        for (int mi = 0; mi < 4; ++mi)
#pragma unroll
            for (int ni = 0; ni < 4; ++ni)
                acc[mi][ni] = __builtin_amdgcn_mfma_f32_16x16x32_bf16(
                    af[mi], bf[ni], acc[mi][ni], 0, 0, 0);
        __syncthreads();
    }

    int rbase = r0 + wm * 64, lbase = l0 + wn * 64;
#pragma unroll
    for (int mi = 0; mi < 4; ++mi)
#pragma unroll
        for (int ni = 0; ni < 4; ++ni)
#pragma unroll
            for (int rr = 0; rr < 4; ++rr) {
                int r = rbase + mi * 16 + lg * 4 + rr;
                int l = lbase + ni * 16 + lr;
                Gp[((size_t)b * RR + r) * LL + l] = (_Float16)acc[mi][ni][rr];
            }
}

// ---------- softmax over l per (b,r) row: f16 logits -> normalized bf16 P, in place ----------
__global__ __launch_bounds__(256) void k_softmax(_Float16* __restrict__ Gp) {
    const float LOG2E = 1.4426950408889634f;
    int row = blockIdx.x * 4 + (threadIdx.x >> 6);   // b*RR + r
    int lane = threadIdx.x & 63;
    _Float16* base = Gp + (size_t)row * LL;
    half8 hv = *(const half8*)(base + lane * 8);
    float v[8];
#pragma unroll
    for (int j = 0; j < 8; ++j) v[j] = (float)hv[j];
    float m = v[0];
#pragma unroll
    for (int j = 1; j < 8; ++j) m = fmaxf(m, v[j]);
    for (int off = 1; off < 64; off <<= 1) m = fmaxf(m, __shfl_xor(m, off));
    float s = 0.f;
    float p[8];
#pragma unroll
    for (int j = 0; j < 8; ++j) { p[j] = exp2f((v[j] - m) * LOG2E); s += p[j]; }
    for (int off = 1; off < 64; off <<= 1) s += __shfl_xor(s, off);
    float inv = 1.f / s;
    short8 o;
#pragma unroll
    for (int j = 0; j < 8; ++j) o[j] = f2b(p[j] * inv);
    *(short8*)((short*)base + lane * 8) = o;
}

// ---------- wo MFMA: out[b,f] = relu(max_r sum_l conv_fl[b,f,l]*P[b,r,l]) ----------
__global__ __launch_bounds__(256) void k_wo_mfma(
    const short* __restrict__ convfl, const short* __restrict__ P,
    float* __restrict__ out) {
    int wg = xcd_swz(blockIdx.x, 2048);
    int b = wg >> 4;
    int f0 = ((wg >> 2) & 3) * 128;   // M
    int r0 = (wg & 3) * 128;          // N
    int tid = threadIdx.x, lane = tid & 63, w = tid >> 6;
    int wm = w >> 1, wn = w & 1;
    int lr = lane & 15, lg = lane >> 4;

    __shared__ __align__(16) char smem[32768];

    f32x4 acc[4][4];
    for (int i = 0; i < 4; ++i)
        for (int j = 0; j < 4; ++j) acc[i][j] = (f32x4){0.f, 0.f, 0.f, 0.f};

    int rowA = lane >> 2;
    int sw = (lane & 3) ^ (rowA & 3);
    const short* gA = convfl + (size_t)b * NF * LL + (size_t)(f0 + w * 32 + rowA) * LL + sw * 8;
    const short* gB = P + (size_t)b * RR * LL + (size_t)(r0 + w * 32 + rowA) * LL + sw * 8;
    int rsw = (lg ^ (lr & 3)) * 8;
    int rA = wm * 64, rB = wn * 64;

    {
        char* base = smem;
        stage16(gA, base + w * 2048);
        stage16(gA + 16 * LL, base + w * 2048 + 1024);
        stage16(gB, base + 8192 + w * 2048);
        stage16(gB + 16 * LL, base + 8192 + w * 2048 + 1024);
    }
    __syncthreads();

    for (int t = 0; t < 16; ++t) {
        if (t + 1 < 16) {
            int k0 = (t + 1) * 32;
            char* base = smem + ((t + 1) & 1) * 16384;
            stage16(gA + k0, base + w * 2048);
            stage16(gA + 16 * LL + k0, base + w * 2048 + 1024);
            stage16(gB + k0, base + 8192 + w * 2048);
            stage16(gB + 16 * LL + k0, base + 8192 + w * 2048 + 1024);
        }
        const short (*Ac)[32] = (const short(*)[32])(smem + (t & 1) * 16384);
        const short (*Bc)[32] = (const short(*)[32])(smem + (t & 1) * 16384 + 8192);
        short8 af[4], bf[4];
#pragma unroll
        for (int mi = 0; mi < 4; ++mi)
            af[mi] = *(const short8*)(&Ac[rA + mi * 16 + lr][rsw]);
#pragma unroll
        for (int ni = 0; ni < 4; ++ni)
            bf[ni] = *(const short8*)(&Bc[rB + ni * 16 + lr][rsw]);
#pragma unroll
        for (int mi = 0; mi < 4; ++mi)
#pragma unroll
            for (int ni = 0; ni < 4; ++ni)
                acc[mi][ni] = __builtin_amdgcn_mfma_f32_16x16x32_bf16(
                    af[mi], bf[ni], acc[mi][ni], 0, 0, 0);
        __syncthreads();
    }

    int fbase = f0 + wm * 64;
#pragma unroll
    for (int mi = 0; mi < 4; ++mi)
#pragma unroll
        for (int rr = 0; rr < 4; ++rr) {
            float m = acc[mi][0][rr];
#pragma unroll
            for (int ni = 1; ni < 4; ++ni) m = fmaxf(m, acc[mi][ni][rr]);
            m = fmaxf(m, __shfl_xor(m, 1));
            m = fmaxf(m, __shfl_xor(m, 2));
            m = fmaxf(m, __shfl_xor(m, 4));
            m = fmaxf(m, __shfl_xor(m, 8));
            if (lr == 0 && m > 0.f) {
                int f = fbase + mi * 16 + lg * 4 + rr;
                atomicMax((int*)&out[(size_t)b * NF + f], __float_as_int(m));
            }
        }
}

extern "C" void kernel_launch(void* const* d_in, const int* in_sizes, int n_in,
                              void* d_out, int out_size, void* d_ws, size_t ws_size,
                              hipStream_t stream) {
    const float* x      = (const float*)d_in[0];
    const float* e1     = (const float*)d_in[1];
    const float* e2     = (const float*)d_in[2];
    const float* posVec = (const float*)d_in[3];
    const float* We1    = (const float*)d_in[4];
    const float* We2    = (const float*)d_in[5];
    const float* U      = (const float*)d_in[6];
    const float* conv_w = (const float*)d_in[7];
    const float* conv_b = (const float*)d_in[8];
    const float* rel_w  = (const float*)d_in[9];
    float* out = (float*)d_out;

    // workspace: convlf 67M | convfl 67M | Gp 67M | pxp 50.5M | cwb 1.2M
    //            Qh+Ql 1M | small 1M  -> 255.1 MB (< 256 MiB)
    char* p = (char*)d_ws;
    short* convlf = (short*)p;  p += (size_t)BB * LL * NF * 2;
    short* convfl = (short*)p;  p += (size_t)BB * NF * LL * 2;
    _Float16* Gp  = (_Float16*)p;  p += (size_t)BB * RR * LL * 2;
    short* pxp    = (short*)p;  p += (size_t)BB * LP * DD * 2;
    short* cwb    = (short*)p;  p += (size_t)NF * DWIN * 2;
    short* QhW    = (short*)p;  p += (size_t)RR * NF * 2;
    short* QlW    = (short*)p;  p += (size_t)RR * NF * 2;
    float* v1     = (float*)p;  p += (size_t)BB * DW * 4;
    float* v2     = (float*)p;  p += (size_t)BB * DW * 4;
    float* A1     = (float*)p;  p += (size_t)BB * LL * 4;
    float* A2     = (float*)p;  p += (size_t)BB * LL * 4;
    float* alpha  = (float*)p;  p += (size_t)BB * LL * 4;

    k_pack_px<<<(BB * LP * 48) / 256, 256, 0, stream>>>(x, posVec, pxp);
    k_pack_w<<<(NF * DWIN / 8) / 256, 256, 0, stream>>>(conv_w, cwb);
    k_ve<<<BB, DW, 0, stream>>>(We1, We2, e1, e2, v1, v2);
    k_logits<<<(BB * LL) / 4, 256, 0, stream>>>(x, v1, v2, A1, A2);
    k_alpha<<<BB, LL, 0, stream>>>(A1, A2, alpha);
    k_w2t<<<dim3(NF / 64, RR / 64), 256, 0, stream>>>(U, rel_w, QhW, QlW);
    k_conv_mfma<<<2048, 256, 0, stream>>>(pxp, cwb, conv_b, alpha, convlf, convfl);
    k_g_mfma<<<2048, 256, 0, stream>>>(QhW, QlW, convlf, Gp);
    k_softmax<<<(BB * RR) / 4, 256, 0, stream>>>(Gp);
    hipMemsetAsync(d_out, 0, (size_t)BB * NF * sizeof(float), stream);
    k_wo_mfma<<<2048, 256, 0, stream>>>(convfl, (const short*)Gp, out);
    hipMemcpyAsync(out + BB * NF, rel_w, (size_t)NF * RR * sizeof(float),
                   hipMemcpyDeviceToDevice, stream);
}

// Round 9
// 365.062 us; speedup vs baseline: 1.1126x; 1.1126x over previous
//
#include <hip/hip_runtime.h>
#include <hip/hip_bf16.h>

#define BB 128
#define LL 512
#define DW 256
#define DP 64
#define NF 512
#define DD 384       // D = DW + 2*DP
#define DWIN 1152    // 3*D
#define RR 512       // nr
#define LP 514       // LL + 2 pad rows

typedef __attribute__((ext_vector_type(8))) short short8;
typedef __attribute__((ext_vector_type(4))) short short4v;
typedef __attribute__((ext_vector_type(8))) _Float16 half8;
typedef __attribute__((ext_vector_type(4))) float f32x4;

typedef __attribute__((address_space(1))) const void* gas_t;
typedef __attribute__((address_space(3))) void* las_t;

__device__ __forceinline__ void stage16(const void* g, void* l) {
    __builtin_amdgcn_global_load_lds((gas_t)g, (las_t)l, 16, 0, 0);
}

__device__ inline short f2h(float v) {
    _Float16 h = (_Float16)v;
    return *reinterpret_cast<short*>(&h);
}
// XCD-chunked bijective swizzle (nwg % 8 == 0)
__device__ inline int xcd_swz(int bid, int nwg) {
    return (bid & 7) * (nwg >> 3) + (bid >> 3);
}

// ---------- small kernels (fp32-exact path for alpha) ----------
__global__ void k_ve(const float* __restrict__ We1, const float* __restrict__ We2,
                     const float* __restrict__ e1, const float* __restrict__ e2,
                     float* __restrict__ v1, float* __restrict__ v2) {
    int b = blockIdx.x;
    int d = threadIdx.x; // 256
    __shared__ float s1[DW], s2[DW];
    s1[d] = e1[b * DW + d];
    s2[d] = e2[b * DW + d];
    __syncthreads();
    float a1 = 0.f, a2 = 0.f;
    for (int e = 0; e < DW; ++e) {
        a1 += We1[d * DW + e] * s1[e];
        a2 += We2[d * DW + e] * s2[e];
    }
    v1[b * DW + d] = a1;
    v2[b * DW + d] = a2;
}

__global__ __launch_bounds__(256) void k_logits(
    const float* __restrict__ x,
    const float* __restrict__ v1, const float* __restrict__ v2,
    float* __restrict__ A1, float* __restrict__ A2) {
    int row = blockIdx.x * 4 + (threadIdx.x >> 6);   // b*LL + l
    int lane = threadIdx.x & 63;
    int b = row >> 9;
    f32x4 xv = *(const f32x4*)(x + (size_t)row * DW + lane * 4);
    f32x4 w1 = *(const f32x4*)(v1 + b * DW + lane * 4);
    f32x4 w2 = *(const f32x4*)(v2 + b * DW + lane * 4);
    float p1 = xv[0] * w1[0] + xv[1] * w1[1] + xv[2] * w1[2] + xv[3] * w1[3];
    float p2 = xv[0] * w2[0] + xv[1] * w2[1] + xv[2] * w2[2] + xv[3] * w2[3];
    for (int off = 32; off; off >>= 1) {
        p1 += __shfl_down(p1, off);
        p2 += __shfl_down(p2, off);
    }
    if (lane == 0) { A1[row] = p1; A2[row] = p2; }
}

__global__ void k_alpha(const float* __restrict__ A1, const float* __restrict__ A2,
                        float* __restrict__ alpha) {
    int b = blockIdx.x;
    int l = threadIdx.x; // 512
    __shared__ float s[LL];
    float a1 = A1[b * LL + l], a2 = A2[b * LL + l];

    s[l] = a1; __syncthreads();
    for (int st = 256; st; st >>= 1) { if (l < st) s[l] = fmaxf(s[l], s[l + st]); __syncthreads(); }
    float m1 = s[0]; __syncthreads();
    float e1x = expf(a1 - m1);
    s[l] = e1x; __syncthreads();
    for (int st = 256; st; st >>= 1) { if (l < st) s[l] += s[l + st]; __syncthreads(); }
    float d1 = s[0]; __syncthreads();

    s[l] = a2; __syncthreads();
    for (int st = 256; st; st >>= 1) { if (l < st) s[l] = fmaxf(s[l], s[l + st]); __syncthreads(); }
    float m2 = s[0]; __syncthreads();
    float e2x = expf(a2 - m2);
    s[l] = e2x; __syncthreads();
    for (int st = 256; st; st >>= 1) { if (l < st) s[l] += s[l + st]; __syncthreads(); }
    float d2 = s[0];

    alpha[b * LL + l] = 0.5f * (e1x / d1 + e2x / d2);
}

// ---------- packing: px_pad[b][row][d] f16, rows 0 and 513 zero ----------
__global__ __launch_bounds__(256) void k_pack_px(const float* __restrict__ x,
                                                 const float* __restrict__ pv,
                                                 short* __restrict__ pxp) {
    int idx = blockIdx.x * 256 + threadIdx.x;   // 128*514*48 = 3,158,016
    int d8 = (idx % 48) * 8;
    int row = (idx / 48) % LP;
    int b = idx / (48 * LP);
    short8 v = (short8){0, 0, 0, 0, 0, 0, 0, 0};
    if (row >= 1 && row <= LL) {
        int l = row - 1;
        const float* src = (d8 < DW) ? (x + ((size_t)b * LL + l) * DW + d8)
                                     : (pv + ((size_t)b * LL + l) * (2 * DP) + (d8 - DW));
        f32x4 u0 = *(const f32x4*)(src);
        f32x4 u1 = *(const f32x4*)(src + 4);
#pragma unroll
        for (int jj = 0; jj < 4; ++jj) { v[jj] = f2h(u0[jj]); v[jj + 4] = f2h(u1[jj]); }
    }
    *(short8*)(pxp + ((size_t)b * LP + row) * DD + d8) = v;
}

__global__ __launch_bounds__(256) void k_pack_w(const float* __restrict__ cw,
                                                short* __restrict__ cwb) {
    int idx = blockIdx.x * 256 + threadIdx.x;   // 512*1152/8 = 73,728
    const float* src = cw + (size_t)idx * 8;
    f32x4 u0 = *(const f32x4*)(src);
    f32x4 u1 = *(const f32x4*)(src + 4);
    short8 v;
#pragma unroll
    for (int jj = 0; jj < 4; ++jj) { v[jj] = f2h(u0[jj]); v[jj + 4] = f2h(u1[jj]); }
    *(short8*)(cwb + (size_t)idx * 8) = v;
}

// ---------- W2t[r][f] = sum_t rel_w[r,t]*U[f,t], f16 out ----------
__global__ void k_w2t(const float* __restrict__ U, const float* __restrict__ relw,
                      short* __restrict__ Qf) {
    __shared__ float As[16][65], Bs[16][65];
    int r0 = blockIdx.y * 64, f0 = blockIdx.x * 64;
    int tid = threadIdx.x, ty = tid >> 4, tx = tid & 15;
    float acc[4][4] = {};
    for (int k0 = 0; k0 < NF; k0 += 16) {
        for (int i = 0; i < 4; ++i) {
            int lin = tid + 256 * i;
            int kk = lin & 15, mm = lin >> 4;
            As[kk][mm] = relw[(r0 + mm) * NF + k0 + kk];
            Bs[kk][mm] = U[(f0 + mm) * NF + k0 + kk];
        }
        __syncthreads();
        for (int kk = 0; kk < 16; ++kk) {
            float av[4], bv[4];
            for (int i = 0; i < 4; ++i) av[i] = As[kk][ty * 4 + i];
            for (int j = 0; j < 4; ++j) bv[j] = Bs[kk][tx * 4 + j];
            for (int i = 0; i < 4; ++i)
                for (int j = 0; j < 4; ++j) acc[i][j] += av[i] * bv[j];
        }
        __syncthreads();
    }
    for (int i = 0; i < 4; ++i)
        for (int j = 0; j < 4; ++j)
            Qf[(size_t)(r0 + ty * 4 + i) * NF + f0 + tx * 4 + j] = f2h(acc[i][j]);
}

// ---------- conv MFMA via global_load_lds (f16) ----------
// A[l][k] = px_pad flat row, B[f][k] = cwb. Epilogue: conv_lf + conv_fl (LDS transpose).
__global__ __launch_bounds__(256) void k_conv_mfma(
    const short* __restrict__ pxp, const short* __restrict__ cwb,
    const float* __restrict__ conv_b, const float* __restrict__ alpha,
    short* __restrict__ conv_lf, short* __restrict__ conv_fl) {
    int wg = xcd_swz(blockIdx.x, 2048);
    int b = wg >> 4;
    int l0 = ((wg >> 2) & 3) * 128;
    int f0 = (wg & 3) * 128;
    int tid = threadIdx.x;
    int lane = tid & 63, w = tid >> 6;
    int wm = w >> 1, wn = w & 1;
    int lr = lane & 15, lg = lane >> 4;

    // union: K-loop As/Bs (2*8192B linear); epilogue T[128][136] (34816B)
    __shared__ __align__(16) char smem[34816];
    short (*As)[32] = (short(*)[32])smem;
    short (*Bs)[32] = (short(*)[32])(smem + 8192);
    short (*T)[136] = (short(*)[136])smem;

    f32x4 acc[4][4];
    for (int i = 0; i < 4; ++i)
        for (int j = 0; j < 4; ++j) acc[i][j] = (f32x4){0.f, 0.f, 0.f, 0.f};

    // staging: wave w stages rows [w*32, w*32+32), 16 rows per call.
    // LDS slot s of row r holds global chunk s ^ p(r), p(r) = (r>>1)&3  (bank-conflict-free)
    int rowA = lane >> 2;                       // 0..15
    int sw = (lane & 3) ^ ((rowA >> 1) & 3);    // pre-swizzled source slot
    const short* gA = pxp + ((size_t)b * LP + l0 + w * 32 + rowA) * DD + sw * 8;
    const short* gB = cwb + (size_t)(f0 + w * 32 + rowA) * DWIN + sw * 8;
    short* lA = &As[w * 32][0];
    short* lB = &Bs[w * 32][0];
    int rsw = (lg ^ ((lr >> 1) & 3)) * 8;       // read-side slot offset
    int rA = wm * 64, rB = wn * 64;

    for (int kb = 0; kb < 36; ++kb) {
        int k0 = kb * 32;
        stage16(gA + k0, lA);
        stage16(gA + 16 * DD + k0, lA + 16 * 32);
        stage16(gB + k0, lB);
        stage16(gB + (size_t)16 * DWIN + k0, lB + 16 * 32);
        __syncthreads();
        half8 af[4], bf[4];
#pragma unroll
        for (int mi = 0; mi < 4; ++mi)
            af[mi] = *(const half8*)(&As[rA + mi * 16 + lr][rsw]);
#pragma unroll
        for (int ni = 0; ni < 4; ++ni)
            bf[ni] = *(const half8*)(&Bs[rB + ni * 16 + lr][rsw]);
#pragma unroll
        for (int mi = 0; mi < 4; ++mi)
#pragma unroll
            for (int ni = 0; ni < 4; ++ni)
                acc[mi][ni] = __builtin_amdgcn_mfma_f32_16x16x32_f16(
                    af[mi], bf[ni], acc[mi][ni], 0, 0, 0);
        __syncthreads();
    }

    int lbase = l0 + wm * 64, fbase = f0 + wn * 64;
#pragma unroll
    for (int mi = 0; mi < 4; ++mi) {
        f32x4 av = *(const f32x4*)(alpha + (size_t)b * LL + lbase + mi * 16 + lg * 4);
        int lrow = lbase + mi * 16 + lg * 4;
#pragma unroll
        for (int ni = 0; ni < 4; ++ni) {
            int f = fbase + ni * 16 + lr;
            float bias = conv_b[f];
            short4v o;
#pragma unroll
            for (int r = 0; r < 4; ++r) {
                float val = tanhf(av[r] * acc[mi][ni][r] + bias);
                short sv = f2h(val);
                o[r] = sv;
                conv_lf[((size_t)b * LL + lrow + r) * NF + f] = sv;
            }
            *(short4v*)(&T[wn * 64 + ni * 16 + lr][wm * 64 + mi * 16 + lg * 4]) = o;
        }
    }
    __syncthreads();
#pragma unroll
    for (int i = 0; i < 8; ++i) {
        int lin = tid + 256 * i;
        int frow = lin >> 4;
        int q = lin & 15;
        short8 v = *(const short8*)(&T[frow][q * 8]);
        *(short8*)(conv_fl + ((size_t)b * NF + f0 + frow) * LL + l0 + q * 8) = v;
    }
}

// ---------- G MFMA: Gp[b][r][l] = sum_f Qf[r,f]*conv_lf[b,l,f], f16 out, K=512 ----------
__global__ __launch_bounds__(256) void k_g_mfma(
    const short* __restrict__ Qf,
    const short* __restrict__ convlf, _Float16* __restrict__ Gp) {
    int wg = xcd_swz(blockIdx.x, 2048);
    int b = wg >> 4;
    int r0 = ((wg >> 2) & 3) * 128;   // M
    int l0 = (wg & 3) * 128;          // N
    int tid = threadIdx.x, lane = tid & 63, w = tid >> 6;
    int wm = w >> 1, wn = w & 1;
    int lr = lane & 15, lg = lane >> 4;

    __shared__ __align__(16) short As[128][32];
    __shared__ __align__(16) short Bs[128][32];

    f32x4 acc[4][4];
    for (int i = 0; i < 4; ++i)
        for (int j = 0; j < 4; ++j) acc[i][j] = (f32x4){0.f, 0.f, 0.f, 0.f};

    int rowA = lane >> 2;
    int sw = (lane & 3) ^ ((rowA >> 1) & 3);
    const short* gA = Qf + (size_t)(r0 + w * 32 + rowA) * NF + sw * 8;
    const short* gB = convlf + (size_t)b * LL * NF + (size_t)(l0 + w * 32 + rowA) * NF + sw * 8;
    short* lA = &As[w * 32][0];
    short* lB = &Bs[w * 32][0];
    int rsw = (lg ^ ((lr >> 1) & 3)) * 8;
    int rA = wm * 64, rB = wn * 64;

    for (int kb = 0; kb < 16; ++kb) {
        int k0 = kb * 32;
        stage16(gA + k0, lA);
        stage16(gA + 16 * NF + k0, lA + 16 * 32);
        stage16(gB + k0, lB);
        stage16(gB + 16 * NF + k0, lB + 16 * 32);
        __syncthreads();
        half8 af[4], bf[4];
#pragma unroll
        for (int mi = 0; mi < 4; ++mi)
            af[mi] = *(const half8*)(&As[rA + mi * 16 + lr][rsw]);
#pragma unroll
        for (int ni = 0; ni < 4; ++ni)
            bf[ni] = *(const half8*)(&Bs[rB + ni * 16 + lr][rsw]);
#pragma unroll
        for (int mi = 0; mi < 4; ++mi)
#pragma unroll
            for (int ni = 0; ni < 4; ++ni)
                acc[mi][ni] = __builtin_amdgcn_mfma_f32_16x16x32_f16(
                    af[mi], bf[ni], acc[mi][ni], 0, 0, 0);
        __syncthreads();
    }

    int rbase = r0 + wm * 64, lbase = l0 + wn * 64;
#pragma unroll
    for (int mi = 0; mi < 4; ++mi)
#pragma unroll
        for (int ni = 0; ni < 4; ++ni)
#pragma unroll
            for (int rr = 0; rr < 4; ++rr) {
                int r = rbase + mi * 16 + lg * 4 + rr;
                int l = lbase + ni * 16 + lr;
                Gp[((size_t)b * RR + r) * LL + l] = (_Float16)acc[mi][ni][rr];
            }
}

// ---------- softmax over l per (b,r) row: f16 logits -> normalized f16 P, in place ----------
__global__ __launch_bounds__(256) void k_softmax(_Float16* __restrict__ Gp) {
    const float LOG2E = 1.4426950408889634f;
    int row = blockIdx.x * 4 + (threadIdx.x >> 6);   // b*RR + r
    int lane = threadIdx.x & 63;
    _Float16* base = Gp + (size_t)row * LL;
    half8 hv = *(const half8*)(base + lane * 8);
    float v[8];
#pragma unroll
    for (int j = 0; j < 8; ++j) v[j] = (float)hv[j];
    float m = v[0];
#pragma unroll
    for (int j = 1; j < 8; ++j) m = fmaxf(m, v[j]);
    for (int off = 1; off < 64; off <<= 1) m = fmaxf(m, __shfl_xor(m, off));
    float s = 0.f;
    float p[8];
#pragma unroll
    for (int j = 0; j < 8; ++j) { p[j] = exp2f((v[j] - m) * LOG2E); s += p[j]; }
    for (int off = 1; off < 64; off <<= 1) s += __shfl_xor(s, off);
    float inv = 1.f / s;
    short8 o;
#pragma unroll
    for (int j = 0; j < 8; ++j) o[j] = f2h(p[j] * inv);
    *(short8*)((short*)base + lane * 8) = o;
}

// ---------- wo MFMA: out[b,f] = relu(max_r sum_l conv_fl[b,f,l]*P[b,r,l]) ----------
__global__ __launch_bounds__(256) void k_wo_mfma(
    const short* __restrict__ convfl, const short* __restrict__ P,
    float* __restrict__ out) {
    int wg = xcd_swz(blockIdx.x, 2048);
    int b = wg >> 4;
    int f0 = ((wg >> 2) & 3) * 128;   // M
    int r0 = (wg & 3) * 128;          // N
    int tid = threadIdx.x, lane = tid & 63, w = tid >> 6;
    int wm = w >> 1, wn = w & 1;
    int lr = lane & 15, lg = lane >> 4;

    __shared__ __align__(16) short As[128][32];
    __shared__ __align__(16) short Bs[128][32];

    f32x4 acc[4][4];
    for (int i = 0; i < 4; ++i)
        for (int j = 0; j < 4; ++j) acc[i][j] = (f32x4){0.f, 0.f, 0.f, 0.f};

    int rowA = lane >> 2;
    int sw = (lane & 3) ^ ((rowA >> 1) & 3);
    const short* gA = convfl + (size_t)b * NF * LL + (size_t)(f0 + w * 32 + rowA) * LL + sw * 8;
    const short* gB = P + (size_t)b * RR * LL + (size_t)(r0 + w * 32 + rowA) * LL + sw * 8;
    short* lA = &As[w * 32][0];
    short* lB = &Bs[w * 32][0];
    int rsw = (lg ^ ((lr >> 1) & 3)) * 8;
    int rA = wm * 64, rB = wn * 64;

    for (int kb = 0; kb < 16; ++kb) {
        int k0 = kb * 32;
        stage16(gA + k0, lA);
        stage16(gA + 16 * LL + k0, lA + 16 * 32);
        stage16(gB + k0, lB);
        stage16(gB + 16 * LL + k0, lB + 16 * 32);
        __syncthreads();
        half8 af[4], bf[4];
#pragma unroll
        for (int mi = 0; mi < 4; ++mi)
            af[mi] = *(const half8*)(&As[rA + mi * 16 + lr][rsw]);
#pragma unroll
        for (int ni = 0; ni < 4; ++ni)
            bf[ni] = *(const half8*)(&Bs[rB + ni * 16 + lr][rsw]);
#pragma unroll
        for (int mi = 0; mi < 4; ++mi)
#pragma unroll
            for (int ni = 0; ni < 4; ++ni)
                acc[mi][ni] = __builtin_amdgcn_mfma_f32_16x16x32_f16(
                    af[mi], bf[ni], acc[mi][ni], 0, 0, 0);
        __syncthreads();
    }

    int fbase = f0 + wm * 64;
#pragma unroll
    for (int mi = 0; mi < 4; ++mi)
#pragma unroll
        for (int rr = 0; rr < 4; ++rr) {
            float m = acc[mi][0][rr];
#pragma unroll
            for (int ni = 1; ni < 4; ++ni) m = fmaxf(m, acc[mi][ni][rr]);
            m = fmaxf(m, __shfl_xor(m, 1));
            m = fmaxf(m, __shfl_xor(m, 2));
            m = fmaxf(m, __shfl_xor(m, 4));
            m = fmaxf(m, __shfl_xor(m, 8));
            if (lr == 0 && m > 0.f) {
                int f = fbase + mi * 16 + lg * 4 + rr;
                atomicMax((int*)&out[(size_t)b * NF + f], __float_as_int(m));
            }
        }
}

extern "C" void kernel_launch(void* const* d_in, const int* in_sizes, int n_in,
                              void* d_out, int out_size, void* d_ws, size_t ws_size,
                              hipStream_t stream) {
    const float* x      = (const float*)d_in[0];
    const float* e1     = (const float*)d_in[1];
    const float* e2     = (const float*)d_in[2];
    const float* posVec = (const float*)d_in[3];
    const float* We1    = (const float*)d_in[4];
    const float* We2    = (const float*)d_in[5];
    const float* U      = (const float*)d_in[6];
    const float* conv_w = (const float*)d_in[7];
    const float* conv_b = (const float*)d_in[8];
    const float* rel_w  = (const float*)d_in[9];
    float* out = (float*)d_out;

    // workspace: convlf 67M | convfl 67M | Gp 67M | pxp 50.5M | cwb 1.2M
    //            Qf 0.5M | small 1M  -> 254.6 MB (< 256 MiB)
    char* p = (char*)d_ws;
    short* convlf = (short*)p;  p += (size_t)BB * LL * NF * 2;
    short* convfl = (short*)p;  p += (size_t)BB * NF * LL * 2;
    _Float16* Gp  = (_Float16*)p;  p += (size_t)BB * RR * LL * 2;
    short* pxp    = (short*)p;  p += (size_t)BB * LP * DD * 2;
    short* cwb    = (short*)p;  p += (size_t)NF * DWIN * 2;
    short* QfW    = (short*)p;  p += (size_t)RR * NF * 2;
    float* v1     = (float*)p;  p += (size_t)BB * DW * 4;
    float* v2     = (float*)p;  p += (size_t)BB * DW * 4;
    float* A1     = (float*)p;  p += (size_t)BB * LL * 4;
    float* A2     = (float*)p;  p += (size_t)BB * LL * 4;
    float* alpha  = (float*)p;  p += (size_t)BB * LL * 4;

    k_pack_px<<<(BB * LP * 48) / 256, 256, 0, stream>>>(x, posVec, pxp);
    k_pack_w<<<(NF * DWIN / 8) / 256, 256, 0, stream>>>(conv_w, cwb);
    k_ve<<<BB, DW, 0, stream>>>(We1, We2, e1, e2, v1, v2);
    k_logits<<<(BB * LL) / 4, 256, 0, stream>>>(x, v1, v2, A1, A2);
    k_alpha<<<BB, LL, 0, stream>>>(A1, A2, alpha);
    k_w2t<<<dim3(NF / 64, RR / 64), 256, 0, stream>>>(U, rel_w, QfW);
    k_conv_mfma<<<2048, 256, 0, stream>>>(pxp, cwb, conv_b, alpha, convlf, convfl);
    k_g_mfma<<<2048, 256, 0, stream>>>(QfW, convlf, Gp);
    k_softmax<<<(BB * RR) / 4, 256, 0, stream>>>(Gp);
    hipMemsetAsync(d_out, 0, (size_t)BB * NF * sizeof(float), stream);
    k_wo_mfma<<<2048, 256, 0, stream>>>(convfl, (const short*)Gp, out);
    hipMemcpyAsync(out + BB * NF, rel_w, (size_t)NF * RR * sizeof(float),
                   hipMemcpyDeviceToDevice, stream);
}

// Round 10
// 357.387 us; speedup vs baseline: 1.1365x; 1.0215x over previous
//
#include <hip/hip_runtime.h>
#include <hip/hip_bf16.h>

#define BB 128
#define LL 512
#define DW 256
#define DP 64
#define NF 512
#define DD 384       // D = DW + 2*DP
#define DWIN 1152    // 3*D
#define RR 512       // nr
#define LP 514       // LL + 2 pad rows

typedef __attribute__((ext_vector_type(8))) short short8;
typedef __attribute__((ext_vector_type(4))) short short4v;
typedef __attribute__((ext_vector_type(8))) _Float16 half8;
typedef __attribute__((ext_vector_type(4))) float f32x4;

typedef __attribute__((address_space(1))) const void* gas_t;
typedef __attribute__((address_space(3))) void* las_t;

__device__ __forceinline__ void stage16(const void* g, void* l) {
    __builtin_amdgcn_global_load_lds((gas_t)g, (las_t)l, 16, 0, 0);
}

__device__ inline short f2h(float v) {
    _Float16 h = (_Float16)v;
    return *reinterpret_cast<short*>(&h);
}
// XCD-chunked bijective swizzle (nwg % 8 == 0)
__device__ inline int xcd_swz(int bid, int nwg) {
    return (bid & 7) * (nwg >> 3) + (bid >> 3);
}

// ---------- small kernels (fp32-exact path for alpha) ----------
__global__ void k_ve(const float* __restrict__ We1, const float* __restrict__ We2,
                     const float* __restrict__ e1, const float* __restrict__ e2,
                     float* __restrict__ v1, float* __restrict__ v2) {
    int b = blockIdx.x;
    int d = threadIdx.x; // 256
    __shared__ float s1[DW], s2[DW];
    s1[d] = e1[b * DW + d];
    s2[d] = e2[b * DW + d];
    __syncthreads();
    float a1 = 0.f, a2 = 0.f;
    for (int e = 0; e < DW; ++e) {
        a1 += We1[d * DW + e] * s1[e];
        a2 += We2[d * DW + e] * s2[e];
    }
    v1[b * DW + d] = a1;
    v2[b * DW + d] = a2;
}

__global__ __launch_bounds__(256) void k_logits(
    const float* __restrict__ x,
    const float* __restrict__ v1, const float* __restrict__ v2,
    float* __restrict__ A1, float* __restrict__ A2) {
    int row = blockIdx.x * 4 + (threadIdx.x >> 6);   // b*LL + l
    int lane = threadIdx.x & 63;
    int b = row >> 9;
    f32x4 xv = *(const f32x4*)(x + (size_t)row * DW + lane * 4);
    f32x4 w1 = *(const f32x4*)(v1 + b * DW + lane * 4);
    f32x4 w2 = *(const f32x4*)(v2 + b * DW + lane * 4);
    float p1 = xv[0] * w1[0] + xv[1] * w1[1] + xv[2] * w1[2] + xv[3] * w1[3];
    float p2 = xv[0] * w2[0] + xv[1] * w2[1] + xv[2] * w2[2] + xv[3] * w2[3];
    for (int off = 32; off; off >>= 1) {
        p1 += __shfl_down(p1, off);
        p2 += __shfl_down(p2, off);
    }
    if (lane == 0) { A1[row] = p1; A2[row] = p2; }
}

__global__ void k_alpha(const float* __restrict__ A1, const float* __restrict__ A2,
                        float* __restrict__ alpha) {
    int b = blockIdx.x;
    int l = threadIdx.x; // 512
    __shared__ float s[LL];
    float a1 = A1[b * LL + l], a2 = A2[b * LL + l];

    s[l] = a1; __syncthreads();
    for (int st = 256; st; st >>= 1) { if (l < st) s[l] = fmaxf(s[l], s[l + st]); __syncthreads(); }
    float m1 = s[0]; __syncthreads();
    float e1x = expf(a1 - m1);
    s[l] = e1x; __syncthreads();
    for (int st = 256; st; st >>= 1) { if (l < st) s[l] += s[l + st]; __syncthreads(); }
    float d1 = s[0]; __syncthreads();

    s[l] = a2; __syncthreads();
    for (int st = 256; st; st >>= 1) { if (l < st) s[l] = fmaxf(s[l], s[l + st]); __syncthreads(); }
    float m2 = s[0]; __syncthreads();
    float e2x = expf(a2 - m2);
    s[l] = e2x; __syncthreads();
    for (int st = 256; st; st >>= 1) { if (l < st) s[l] += s[l + st]; __syncthreads(); }
    float d2 = s[0];

    alpha[b * LL + l] = 0.5f * (e1x / d1 + e2x / d2);
}

// ---------- packing: px_pad[b][row][d] f16, rows 0 and 513 zero ----------
__global__ __launch_bounds__(256) void k_pack_px(const float* __restrict__ x,
                                                 const float* __restrict__ pv,
                                                 short* __restrict__ pxp) {
    int idx = blockIdx.x * 256 + threadIdx.x;   // 128*514*48 = 3,158,016
    int d8 = (idx % 48) * 8;
    int row = (idx / 48) % LP;
    int b = idx / (48 * LP);
    short8 v = (short8){0, 0, 0, 0, 0, 0, 0, 0};
    if (row >= 1 && row <= LL) {
        int l = row - 1;
        const float* src = (d8 < DW) ? (x + ((size_t)b * LL + l) * DW + d8)
                                     : (pv + ((size_t)b * LL + l) * (2 * DP) + (d8 - DW));
        f32x4 u0 = *(const f32x4*)(src);
        f32x4 u1 = *(const f32x4*)(src + 4);
#pragma unroll
        for (int jj = 0; jj < 4; ++jj) { v[jj] = f2h(u0[jj]); v[jj + 4] = f2h(u1[jj]); }
    }
    *(short8*)(pxp + ((size_t)b * LP + row) * DD + d8) = v;
}

__global__ __launch_bounds__(256) void k_pack_w(const float* __restrict__ cw,
                                                short* __restrict__ cwb) {
    int idx = blockIdx.x * 256 + threadIdx.x;   // 512*1152/8 = 73,728
    const float* src = cw + (size_t)idx * 8;
    f32x4 u0 = *(const f32x4*)(src);
    f32x4 u1 = *(const f32x4*)(src + 4);
    short8 v;
#pragma unroll
    for (int jj = 0; jj < 4; ++jj) { v[jj] = f2h(u0[jj]); v[jj + 4] = f2h(u1[jj]); }
    *(short8*)(cwb + (size_t)idx * 8) = v;
}

// ---------- W2t[r][f] = sum_t rel_w[r,t]*U[f,t], f16 out ----------
__global__ void k_w2t(const float* __restrict__ U, const float* __restrict__ relw,
                      short* __restrict__ Qf) {
    __shared__ float As[16][65], Bs[16][65];
    int r0 = blockIdx.y * 64, f0 = blockIdx.x * 64;
    int tid = threadIdx.x, ty = tid >> 4, tx = tid & 15;
    float acc[4][4] = {};
    for (int k0 = 0; k0 < NF; k0 += 16) {
        for (int i = 0; i < 4; ++i) {
            int lin = tid + 256 * i;
            int kk = lin & 15, mm = lin >> 4;
            As[kk][mm] = relw[(r0 + mm) * NF + k0 + kk];
            Bs[kk][mm] = U[(f0 + mm) * NF + k0 + kk];
        }
        __syncthreads();
        for (int kk = 0; kk < 16; ++kk) {
            float av[4], bv[4];
            for (int i = 0; i < 4; ++i) av[i] = As[kk][ty * 4 + i];
            for (int j = 0; j < 4; ++j) bv[j] = Bs[kk][tx * 4 + j];
            for (int i = 0; i < 4; ++i)
                for (int j = 0; j < 4; ++j) acc[i][j] += av[i] * bv[j];
        }
        __syncthreads();
    }
    for (int i = 0; i < 4; ++i)
        for (int j = 0; j < 4; ++j)
            Qf[(size_t)(r0 + ty * 4 + i) * NF + f0 + tx * 4 + j] = f2h(acc[i][j]);
}

// ================= BK=64 MFMA kernels =================
// LDS tile: rows[128] x 64 f16 (128B row = 32 banks -> bank depends only on slot).
// Stage: lane (rowA=lane>>3, slot=lane&7) stages global chunk slot^rowA; 8 rows/call.
// Read: chunk (kk*4+lg) of row r is at LDS slot (kk*4+lg)^(r&7).

// ---------- conv MFMA: A=pxp windowed rows, B=cwb; K=1152 (18 iters) ----------
__global__ __launch_bounds__(256) void k_conv_mfma(
    const short* __restrict__ pxp, const short* __restrict__ cwb,
    const float* __restrict__ conv_b, const float* __restrict__ alpha,
    short* __restrict__ conv_lf, short* __restrict__ conv_fl) {
    int wg = xcd_swz(blockIdx.x, 2048);
    int b = wg >> 4;
    int l0 = ((wg >> 2) & 3) * 128;
    int f0 = (wg & 3) * 128;
    int tid = threadIdx.x;
    int lane = tid & 63, w = tid >> 6;
    int wm = w >> 1, wn = w & 1;
    int lr = lane & 15, lg = lane >> 4;

    // union: K-loop As/Bs (2*16384B); epilogue T[128][136] (34816B)
    __shared__ __align__(16) char smem[34816];
    short (*As)[64] = (short(*)[64])smem;
    short (*Bs)[64] = (short(*)[64])(smem + 16384);
    short (*T)[136] = (short(*)[136])smem;

    f32x4 acc[4][4];
    for (int i = 0; i < 4; ++i)
        for (int j = 0; j < 4; ++j) acc[i][j] = (f32x4){0.f, 0.f, 0.f, 0.f};

    int rowA = lane >> 3;                 // 0..7
    int sw = (lane & 7) ^ rowA;           // pre-swizzled source slot
    const short* gA = pxp + ((size_t)b * LP + l0 + w * 32 + rowA) * DD + sw * 8;
    const short* gB = cwb + (size_t)(f0 + w * 32 + rowA) * DWIN + sw * 8;
    short* lA = &As[w * 32][0];
    short* lB = &Bs[w * 32][0];
    int rA = wm * 64, rB = wn * 64;
    int p7 = lr & 7;

    for (int kb = 0; kb < 18; ++kb) {
        int k0 = kb * 64;
#pragma unroll
        for (int c = 0; c < 4; ++c) {
            stage16(gA + (size_t)(8 * c) * DD + k0, lA + c * 8 * 64);
            stage16(gB + (size_t)(8 * c) * DWIN + k0, lB + c * 8 * 64);
        }
        __syncthreads();
#pragma unroll
        for (int kk = 0; kk < 2; ++kk) {
            half8 af[4], bf[4];
            int cs = ((kk << 2) + lg);
#pragma unroll
            for (int mi = 0; mi < 4; ++mi)
                af[mi] = *(const half8*)(&As[rA + mi * 16 + lr][(cs ^ p7) * 8]);
#pragma unroll
            for (int ni = 0; ni < 4; ++ni)
                bf[ni] = *(const half8*)(&Bs[rB + ni * 16 + lr][(cs ^ p7) * 8]);
#pragma unroll
            for (int mi = 0; mi < 4; ++mi)
#pragma unroll
                for (int ni = 0; ni < 4; ++ni)
                    acc[mi][ni] = __builtin_amdgcn_mfma_f32_16x16x32_f16(
                        af[mi], bf[ni], acc[mi][ni], 0, 0, 0);
        }
        __syncthreads();
    }

    int lbase = l0 + wm * 64, fbase = f0 + wn * 64;
#pragma unroll
    for (int mi = 0; mi < 4; ++mi) {
        f32x4 av = *(const f32x4*)(alpha + (size_t)b * LL + lbase + mi * 16 + lg * 4);
        int lrow = lbase + mi * 16 + lg * 4;
#pragma unroll
        for (int ni = 0; ni < 4; ++ni) {
            int f = fbase + ni * 16 + lr;
            float bias = conv_b[f];
            short4v o;
#pragma unroll
            for (int r = 0; r < 4; ++r) {
                float val = tanhf(av[r] * acc[mi][ni][r] + bias);
                short sv = f2h(val);
                o[r] = sv;
                conv_lf[((size_t)b * LL + lrow + r) * NF + f] = sv;
            }
            *(short4v*)(&T[wn * 64 + ni * 16 + lr][wm * 64 + mi * 16 + lg * 4]) = o;
        }
    }
    __syncthreads();
#pragma unroll
    for (int i = 0; i < 8; ++i) {
        int lin = tid + 256 * i;
        int frow = lin >> 4;
        int q = lin & 15;
        short8 v = *(const short8*)(&T[frow][q * 8]);
        *(short8*)(conv_fl + ((size_t)b * NF + f0 + frow) * LL + l0 + q * 8) = v;
    }
}

// ---------- G MFMA: Gp[b][r][l] = sum_f Qf[r,f]*conv_lf[b,l,f]; K=512 (8 iters) ----------
__global__ __launch_bounds__(256) void k_g_mfma(
    const short* __restrict__ Qf,
    const short* __restrict__ convlf, _Float16* __restrict__ Gp) {
    int wg = xcd_swz(blockIdx.x, 2048);
    int b = wg >> 4;
    int r0 = ((wg >> 2) & 3) * 128;   // M
    int l0 = (wg & 3) * 128;          // N
    int tid = threadIdx.x, lane = tid & 63, w = tid >> 6;
    int wm = w >> 1, wn = w & 1;
    int lr = lane & 15, lg = lane >> 4;

    __shared__ __align__(16) short As[128][64];
    __shared__ __align__(16) short Bs[128][64];

    f32x4 acc[4][4];
    for (int i = 0; i < 4; ++i)
        for (int j = 0; j < 4; ++j) acc[i][j] = (f32x4){0.f, 0.f, 0.f, 0.f};

    int rowA = lane >> 3;
    int sw = (lane & 7) ^ rowA;
    const short* gA = Qf + (size_t)(r0 + w * 32 + rowA) * NF + sw * 8;
    const short* gB = convlf + (size_t)b * LL * NF + (size_t)(l0 + w * 32 + rowA) * NF + sw * 8;
    short* lA = &As[w * 32][0];
    short* lB = &Bs[w * 32][0];
    int rA = wm * 64, rB = wn * 64;
    int p7 = lr & 7;

    for (int kb = 0; kb < 8; ++kb) {
        int k0 = kb * 64;
#pragma unroll
        for (int c = 0; c < 4; ++c) {
            stage16(gA + (size_t)(8 * c) * NF + k0, lA + c * 8 * 64);
            stage16(gB + (size_t)(8 * c) * NF + k0, lB + c * 8 * 64);
        }
        __syncthreads();
#pragma unroll
        for (int kk = 0; kk < 2; ++kk) {
            half8 af[4], bf[4];
            int cs = ((kk << 2) + lg);
#pragma unroll
            for (int mi = 0; mi < 4; ++mi)
                af[mi] = *(const half8*)(&As[rA + mi * 16 + lr][(cs ^ p7) * 8]);
#pragma unroll
            for (int ni = 0; ni < 4; ++ni)
                bf[ni] = *(const half8*)(&Bs[rB + ni * 16 + lr][(cs ^ p7) * 8]);
#pragma unroll
            for (int mi = 0; mi < 4; ++mi)
#pragma unroll
                for (int ni = 0; ni < 4; ++ni)
                    acc[mi][ni] = __builtin_amdgcn_mfma_f32_16x16x32_f16(
                        af[mi], bf[ni], acc[mi][ni], 0, 0, 0);
        }
        __syncthreads();
    }

    int rbase = r0 + wm * 64, lbase = l0 + wn * 64;
#pragma unroll
    for (int mi = 0; mi < 4; ++mi)
#pragma unroll
        for (int ni = 0; ni < 4; ++ni)
#pragma unroll
            for (int rr = 0; rr < 4; ++rr) {
                int r = rbase + mi * 16 + lg * 4 + rr;
                int l = lbase + ni * 16 + lr;
                Gp[((size_t)b * RR + r) * LL + l] = (_Float16)acc[mi][ni][rr];
            }
}

// ---------- softmax over l per (b,r) row: f16 logits -> normalized f16 P, in place ----------
__global__ __launch_bounds__(256) void k_softmax(_Float16* __restrict__ Gp) {
    const float LOG2E = 1.4426950408889634f;
    int row = blockIdx.x * 4 + (threadIdx.x >> 6);   // b*RR + r
    int lane = threadIdx.x & 63;
    _Float16* base = Gp + (size_t)row * LL;
    half8 hv = *(const half8*)(base + lane * 8);
    float v[8];
#pragma unroll
    for (int j = 0; j < 8; ++j) v[j] = (float)hv[j];
    float m = v[0];
#pragma unroll
    for (int j = 1; j < 8; ++j) m = fmaxf(m, v[j]);
    for (int off = 1; off < 64; off <<= 1) m = fmaxf(m, __shfl_xor(m, off));
    float s = 0.f;
    float p[8];
#pragma unroll
    for (int j = 0; j < 8; ++j) { p[j] = exp2f((v[j] - m) * LOG2E); s += p[j]; }
    for (int off = 1; off < 64; off <<= 1) s += __shfl_xor(s, off);
    float inv = 1.f / s;
    short8 o;
#pragma unroll
    for (int j = 0; j < 8; ++j) o[j] = f2h(p[j] * inv);
    *(short8*)((short*)base + lane * 8) = o;
}

// ---------- wo MFMA: out[b,f] = relu(max_r sum_l conv_fl[b,f,l]*P[b,r,l]); K=512 ----------
__global__ __launch_bounds__(256) void k_wo_mfma(
    const short* __restrict__ convfl, const short* __restrict__ P,
    float* __restrict__ out) {
    int wg = xcd_swz(blockIdx.x, 2048);
    int b = wg >> 4;
    int f0 = ((wg >> 2) & 3) * 128;   // M
    int r0 = (wg & 3) * 128;          // N
    int tid = threadIdx.x, lane = tid & 63, w = tid >> 6;
    int wm = w >> 1, wn = w & 1;
    int lr = lane & 15, lg = lane >> 4;

    __shared__ __align__(16) short As[128][64];
    __shared__ __align__(16) short Bs[128][64];

    f32x4 acc[4][4];
    for (int i = 0; i < 4; ++i)
        for (int j = 0; j < 4; ++j) acc[i][j] = (f32x4){0.f, 0.f, 0.f, 0.f};

    int rowA = lane >> 3;
    int sw = (lane & 7) ^ rowA;
    const short* gA = convfl + (size_t)b * NF * LL + (size_t)(f0 + w * 32 + rowA) * LL + sw * 8;
    const short* gB = P + (size_t)b * RR * LL + (size_t)(r0 + w * 32 + rowA) * LL + sw * 8;
    short* lA = &As[w * 32][0];
    short* lB = &Bs[w * 32][0];
    int rA = wm * 64, rB = wn * 64;
    int p7 = lr & 7;

    for (int kb = 0; kb < 8; ++kb) {
        int k0 = kb * 64;
#pragma unroll
        for (int c = 0; c < 4; ++c) {
            stage16(gA + (size_t)(8 * c) * LL + k0, lA + c * 8 * 64);
            stage16(gB + (size_t)(8 * c) * LL + k0, lB + c * 8 * 64);
        }
        __syncthreads();
#pragma unroll
        for (int kk = 0; kk < 2; ++kk) {
            half8 af[4], bf[4];
            int cs = ((kk << 2) + lg);
#pragma unroll
            for (int mi = 0; mi < 4; ++mi)
                af[mi] = *(const half8*)(&As[rA + mi * 16 + lr][(cs ^ p7) * 8]);
#pragma unroll
            for (int ni = 0; ni < 4; ++ni)
                bf[ni] = *(const half8*)(&Bs[rB + ni * 16 + lr][(cs ^ p7) * 8]);
#pragma unroll
            for (int mi = 0; mi < 4; ++mi)
#pragma unroll
                for (int ni = 0; ni < 4; ++ni)
                    acc[mi][ni] = __builtin_amdgcn_mfma_f32_16x16x32_f16(
                        af[mi], bf[ni], acc[mi][ni], 0, 0, 0);
        }
        __syncthreads();
    }

    int fbase = f0 + wm * 64;
#pragma unroll
    for (int mi = 0; mi < 4; ++mi)
#pragma unroll
        for (int rr = 0; rr < 4; ++rr) {
            float m = acc[mi][0][rr];
#pragma unroll
            for (int ni = 1; ni < 4; ++ni) m = fmaxf(m, acc[mi][ni][rr]);
            m = fmaxf(m, __shfl_xor(m, 1));
            m = fmaxf(m, __shfl_xor(m, 2));
            m = fmaxf(m, __shfl_xor(m, 4));
            m = fmaxf(m, __shfl_xor(m, 8));
            if (lr == 0 && m > 0.f) {
                int f = fbase + mi * 16 + lg * 4 + rr;
                atomicMax((int*)&out[(size_t)b * NF + f], __float_as_int(m));
            }
        }
}

extern "C" void kernel_launch(void* const* d_in, const int* in_sizes, int n_in,
                              void* d_out, int out_size, void* d_ws, size_t ws_size,
                              hipStream_t stream) {
    const float* x      = (const float*)d_in[0];
    const float* e1     = (const float*)d_in[1];
    const float* e2     = (const float*)d_in[2];
    const float* posVec = (const float*)d_in[3];
    const float* We1    = (const float*)d_in[4];
    const float* We2    = (const float*)d_in[5];
    const float* U      = (const float*)d_in[6];
    const float* conv_w = (const float*)d_in[7];
    const float* conv_b = (const float*)d_in[8];
    const float* rel_w  = (const float*)d_in[9];
    float* out = (float*)d_out;

    // workspace: convlf 67M | convfl 67M | Gp 67M | pxp 50.5M | cwb 1.2M
    //            Qf 0.5M | small 1M  -> 254.6 MB (< 256 MiB)
    char* p = (char*)d_ws;
    short* convlf = (short*)p;  p += (size_t)BB * LL * NF * 2;
    short* convfl = (short*)p;  p += (size_t)BB * NF * LL * 2;
    _Float16* Gp  = (_Float16*)p;  p += (size_t)BB * RR * LL * 2;
    short* pxp    = (short*)p;  p += (size_t)BB * LP * DD * 2;
    short* cwb    = (short*)p;  p += (size_t)NF * DWIN * 2;
    short* QfW    = (short*)p;  p += (size_t)RR * NF * 2;
    float* v1     = (float*)p;  p += (size_t)BB * DW * 4;
    float* v2     = (float*)p;  p += (size_t)BB * DW * 4;
    float* A1     = (float*)p;  p += (size_t)BB * LL * 4;
    float* A2     = (float*)p;  p += (size_t)BB * LL * 4;
    float* alpha  = (float*)p;  p += (size_t)BB * LL * 4;

    k_pack_px<<<(BB * LP * 48) / 256, 256, 0, stream>>>(x, posVec, pxp);
    k_pack_w<<<(NF * DWIN / 8) / 256, 256, 0, stream>>>(conv_w, cwb);
    k_ve<<<BB, DW, 0, stream>>>(We1, We2, e1, e2, v1, v2);
    k_logits<<<(BB * LL) / 4, 256, 0, stream>>>(x, v1, v2, A1, A2);
    k_alpha<<<BB, LL, 0, stream>>>(A1, A2, alpha);
    k_w2t<<<dim3(NF / 64, RR / 64), 256, 0, stream>>>(U, rel_w, QfW);
    k_conv_mfma<<<2048, 256, 0, stream>>>(pxp, cwb, conv_b, alpha, convlf, convfl);
    k_g_mfma<<<2048, 256, 0, stream>>>(QfW, convlf, Gp);
    k_softmax<<<(BB * RR) / 4, 256, 0, stream>>>(Gp);
    hipMemsetAsync(d_out, 0, (size_t)BB * NF * sizeof(float), stream);
    k_wo_mfma<<<2048, 256, 0, stream>>>(convfl, (const short*)Gp, out);
    hipMemcpyAsync(out + BB * NF, rel_w, (size_t)NF * RR * sizeof(float),
                   hipMemcpyDeviceToDevice, stream);
}

// Round 11
// 328.951 us; speedup vs baseline: 1.2348x; 1.0864x over previous
//
#include <hip/hip_runtime.h>
#include <hip/hip_bf16.h>

#define BB 128
#define LL 512
#define DW 256
#define DP 64
#define NF 512
#define DD 384       // D = DW + 2*DP
#define DWIN 1152    // 3*D
#define RR 512       // nr
#define LP 514       // LL + 2 pad rows

typedef __attribute__((ext_vector_type(8))) short short8;
typedef __attribute__((ext_vector_type(4))) short short4v;
typedef __attribute__((ext_vector_type(2))) short short2v;
typedef __attribute__((ext_vector_type(8))) _Float16 half8;
typedef __attribute__((ext_vector_type(4))) float f32x4;
typedef __attribute__((ext_vector_type(2))) float f32x2;

typedef __attribute__((address_space(1))) const void* gas_t;
typedef __attribute__((address_space(3))) void* las_t;

__device__ __forceinline__ void stage16(const void* g, void* l) {
    __builtin_amdgcn_global_load_lds((gas_t)g, (las_t)l, 16, 0, 0);
}

__device__ inline short f2h(float v) {
    _Float16 h = (_Float16)v;
    return *reinterpret_cast<short*>(&h);
}
// XCD-chunked bijective swizzle (nwg % 8 == 0)
__device__ inline int xcd_swz(int bid, int nwg) {
    return (bid & 7) * (nwg >> 3) + (bid >> 3);
}

// ---------- small kernels (fp32-exact path for alpha) ----------
__global__ void k_ve(const float* __restrict__ We1, const float* __restrict__ We2,
                     const float* __restrict__ e1, const float* __restrict__ e2,
                     float* __restrict__ v1, float* __restrict__ v2) {
    int b = blockIdx.x;
    int d = threadIdx.x; // 256
    __shared__ float s1[DW], s2[DW];
    s1[d] = e1[b * DW + d];
    s2[d] = e2[b * DW + d];
    __syncthreads();
    float a1 = 0.f, a2 = 0.f;
    for (int e = 0; e < DW; ++e) {
        a1 += We1[d * DW + e] * s1[e];
        a2 += We2[d * DW + e] * s2[e];
    }
    v1[b * DW + d] = a1;
    v2[b * DW + d] = a2;
}

// fused: pack px row to f16 AND compute logits (one x read total)
// one wave per padded row (rows 0 and 513 zero-filled, no logits)
__global__ __launch_bounds__(256) void k_pack_logits(
    const float* __restrict__ x, const float* __restrict__ pv,
    const float* __restrict__ v1, const float* __restrict__ v2,
    short* __restrict__ pxp, float* __restrict__ A1, float* __restrict__ A2) {
    int gr = blockIdx.x * 4 + (threadIdx.x >> 6);    // 0 .. BB*LP-1
    int lane = threadIdx.x & 63;
    int b = gr / LP;
    int rr = gr - b * LP;
    short* dst = pxp + (size_t)gr * DD;
    if (rr == 0 || rr == LP - 1) {
        *(short4v*)(dst + lane * 4) = (short4v){0, 0, 0, 0};
        *(short2v*)(dst + 256 + lane * 2) = (short2v){0, 0};
        return;
    }
    int l = rr - 1;
    f32x4 xv = *(const f32x4*)(x + ((size_t)b * LL + l) * DW + lane * 4);
    f32x2 pvv = *(const f32x2*)(pv + ((size_t)b * LL + l) * (2 * DP) + lane * 2);
    f32x4 w1 = *(const f32x4*)(v1 + b * DW + lane * 4);
    f32x4 w2 = *(const f32x4*)(v2 + b * DW + lane * 4);
    float p1 = xv[0] * w1[0] + xv[1] * w1[1] + xv[2] * w1[2] + xv[3] * w1[3];
    float p2 = xv[0] * w2[0] + xv[1] * w2[1] + xv[2] * w2[2] + xv[3] * w2[3];
    for (int off = 32; off; off >>= 1) {
        p1 += __shfl_down(p1, off);
        p2 += __shfl_down(p2, off);
    }
    short4v ox;
#pragma unroll
    for (int j = 0; j < 4; ++j) ox[j] = f2h(xv[j]);
    *(short4v*)(dst + lane * 4) = ox;
    short2v op;
    op[0] = f2h(pvv[0]);
    op[1] = f2h(pvv[1]);
    *(short2v*)(dst + 256 + lane * 2) = op;
    if (lane == 0) { A1[b * LL + l] = p1; A2[b * LL + l] = p2; }
}

__global__ void k_alpha(const float* __restrict__ A1, const float* __restrict__ A2,
                        float* __restrict__ alpha) {
    int b = blockIdx.x;
    int l = threadIdx.x; // 512
    __shared__ float s[LL];
    float a1 = A1[b * LL + l], a2 = A2[b * LL + l];

    s[l] = a1; __syncthreads();
    for (int st = 256; st; st >>= 1) { if (l < st) s[l] = fmaxf(s[l], s[l + st]); __syncthreads(); }
    float m1 = s[0]; __syncthreads();
    float e1x = expf(a1 - m1);
    s[l] = e1x; __syncthreads();
    for (int st = 256; st; st >>= 1) { if (l < st) s[l] += s[l + st]; __syncthreads(); }
    float d1 = s[0]; __syncthreads();

    s[l] = a2; __syncthreads();
    for (int st = 256; st; st >>= 1) { if (l < st) s[l] = fmaxf(s[l], s[l + st]); __syncthreads(); }
    float m2 = s[0]; __syncthreads();
    float e2x = expf(a2 - m2);
    s[l] = e2x; __syncthreads();
    for (int st = 256; st; st >>= 1) { if (l < st) s[l] += s[l + st]; __syncthreads(); }
    float d2 = s[0];

    alpha[b * LL + l] = 0.5f * (e1x / d1 + e2x / d2);
}

__global__ __launch_bounds__(256) void k_pack_w(const float* __restrict__ cw,
                                                short* __restrict__ cwb) {
    int idx = blockIdx.x * 256 + threadIdx.x;   // 512*1152/8 = 73,728
    const float* src = cw + (size_t)idx * 8;
    f32x4 u0 = *(const f32x4*)(src);
    f32x4 u1 = *(const f32x4*)(src + 4);
    short8 v;
#pragma unroll
    for (int jj = 0; jj < 4; ++jj) { v[jj] = f2h(u0[jj]); v[jj + 4] = f2h(u1[jj]); }
    *(short8*)(cwb + (size_t)idx * 8) = v;
}

// ---------- W2t[r][f] = sum_t rel_w[r,t]*U[f,t], f16 out ----------
__global__ void k_w2t(const float* __restrict__ U, const float* __restrict__ relw,
                      short* __restrict__ Qf) {
    __shared__ float As[16][65], Bs[16][65];
    int r0 = blockIdx.y * 64, f0 = blockIdx.x * 64;
    int tid = threadIdx.x, ty = tid >> 4, tx = tid & 15;
    float acc[4][4] = {};
    for (int k0 = 0; k0 < NF; k0 += 16) {
        for (int i = 0; i < 4; ++i) {
            int lin = tid + 256 * i;
            int kk = lin & 15, mm = lin >> 4;
            As[kk][mm] = relw[(r0 + mm) * NF + k0 + kk];
            Bs[kk][mm] = U[(f0 + mm) * NF + k0 + kk];
        }
        __syncthreads();
        for (int kk = 0; kk < 16; ++kk) {
            float av[4], bv[4];
            for (int i = 0; i < 4; ++i) av[i] = As[kk][ty * 4 + i];
            for (int j = 0; j < 4; ++j) bv[j] = Bs[kk][tx * 4 + j];
            for (int i = 0; i < 4; ++i)
                for (int j = 0; j < 4; ++j) acc[i][j] += av[i] * bv[j];
        }
        __syncthreads();
    }
    for (int i = 0; i < 4; ++i)
        for (int j = 0; j < 4; ++j)
            Qf[(size_t)(r0 + ty * 4 + i) * NF + f0 + tx * 4 + j] = f2h(acc[i][j]);
}

// ---------- conv MFMA via global_load_lds (f16), BK=32 (proven R9 form) ----------
__global__ __launch_bounds__(256) void k_conv_mfma(
    const short* __restrict__ pxp, const short* __restrict__ cwb,
    const float* __restrict__ conv_b, const float* __restrict__ alpha,
    short* __restrict__ conv_lf, short* __restrict__ conv_fl) {
    int wg = xcd_swz(blockIdx.x, 2048);
    int b = wg >> 4;
    int l0 = ((wg >> 2) & 3) * 128;
    int f0 = (wg & 3) * 128;
    int tid = threadIdx.x;
    int lane = tid & 63, w = tid >> 6;
    int wm = w >> 1, wn = w & 1;
    int lr = lane & 15, lg = lane >> 4;

    // union: K-loop As/Bs (2*8192B linear); epilogue T[128][136] (34816B)
    __shared__ __align__(16) char smem[34816];
    short (*As)[32] = (short(*)[32])smem;
    short (*Bs)[32] = (short(*)[32])(smem + 8192);
    short (*T)[136] = (short(*)[136])smem;

    f32x4 acc[4][4];
    for (int i = 0; i < 4; ++i)
        for (int j = 0; j < 4; ++j) acc[i][j] = (f32x4){0.f, 0.f, 0.f, 0.f};

    // staging: wave w stages rows [w*32, w*32+32), 16 rows per call.
    // LDS slot s of row r holds global chunk s ^ p(r), p(r) = (r>>1)&3  (bank-conflict-free)
    int rowA = lane >> 2;                       // 0..15
    int sw = (lane & 3) ^ ((rowA >> 1) & 3);    // pre-swizzled source slot
    const short* gA = pxp + ((size_t)b * LP + l0 + w * 32 + rowA) * DD + sw * 8;
    const short* gB = cwb + (size_t)(f0 + w * 32 + rowA) * DWIN + sw * 8;
    short* lA = &As[w * 32][0];
    short* lB = &Bs[w * 32][0];
    int rsw = (lg ^ ((lr >> 1) & 3)) * 8;       // read-side slot offset
    int rA = wm * 64, rB = wn * 64;

    for (int kb = 0; kb < 36; ++kb) {
        int k0 = kb * 32;
        stage16(gA + k0, lA);
        stage16(gA + 16 * DD + k0, lA + 16 * 32);
        stage16(gB + k0, lB);
        stage16(gB + (size_t)16 * DWIN + k0, lB + 16 * 32);
        __syncthreads();
        half8 af[4], bf[4];
#pragma unroll
        for (int mi = 0; mi < 4; ++mi)
            af[mi] = *(const half8*)(&As[rA + mi * 16 + lr][rsw]);
#pragma unroll
        for (int ni = 0; ni < 4; ++ni)
            bf[ni] = *(const half8*)(&Bs[rB + ni * 16 + lr][rsw]);
#pragma unroll
        for (int mi = 0; mi < 4; ++mi)
#pragma unroll
            for (int ni = 0; ni < 4; ++ni)
                acc[mi][ni] = __builtin_amdgcn_mfma_f32_16x16x32_f16(
                    af[mi], bf[ni], acc[mi][ni], 0, 0, 0);
        __syncthreads();
    }

    int lbase = l0 + wm * 64, fbase = f0 + wn * 64;
#pragma unroll
    for (int mi = 0; mi < 4; ++mi) {
        f32x4 av = *(const f32x4*)(alpha + (size_t)b * LL + lbase + mi * 16 + lg * 4);
        int lrow = lbase + mi * 16 + lg * 4;
#pragma unroll
        for (int ni = 0; ni < 4; ++ni) {
            int f = fbase + ni * 16 + lr;
            float bias = conv_b[f];
            short4v o;
#pragma unroll
            for (int r = 0; r < 4; ++r) {
                float val = tanhf(av[r] * acc[mi][ni][r] + bias);
                short sv = f2h(val);
                o[r] = sv;
                conv_lf[((size_t)b * LL + lrow + r) * NF + f] = sv;
            }
            *(short4v*)(&T[wn * 64 + ni * 16 + lr][wm * 64 + mi * 16 + lg * 4]) = o;
        }
    }
    __syncthreads();
#pragma unroll
    for (int i = 0; i < 8; ++i) {
        int lin = tid + 256 * i;
        int frow = lin >> 4;
        int q = lin & 15;
        short8 v = *(const short8*)(&T[frow][q * 8]);
        *(short8*)(conv_fl + ((size_t)b * NF + f0 + frow) * LL + l0 + q * 8) = v;
    }
}

// ================= BK=64 kernels (K panels L2-resident) =================
// LDS tile rows[128] x 64 f16. Stage: lane (rowA=lane>>3, slot=lane&7) stages
// chunk slot^rowA; read: chunk (kk*4+lg) of row r at slot (kk*4+lg)^(r&7).

// ---------- G MFMA: Gp[b][r][l] = sum_f Qf[r,f]*conv_lf[b,l,f]; K=512 (8 iters) ----------
__global__ __launch_bounds__(256) void k_g_mfma(
    const short* __restrict__ Qf,
    const short* __restrict__ convlf, _Float16* __restrict__ Gp) {
    int wg = xcd_swz(blockIdx.x, 2048);
    int b = wg >> 4;
    int r0 = ((wg >> 2) & 3) * 128;   // M
    int l0 = (wg & 3) * 128;          // N
    int tid = threadIdx.x, lane = tid & 63, w = tid >> 6;
    int wm = w >> 1, wn = w & 1;
    int lr = lane & 15, lg = lane >> 4;

    __shared__ __align__(16) short As[128][64];
    __shared__ __align__(16) short Bs[128][64];

    f32x4 acc[4][4];
    for (int i = 0; i < 4; ++i)
        for (int j = 0; j < 4; ++j) acc[i][j] = (f32x4){0.f, 0.f, 0.f, 0.f};

    int rowA = lane >> 3;
    int sw = (lane & 7) ^ rowA;
    const short* gA = Qf + (size_t)(r0 + w * 32 + rowA) * NF + sw * 8;
    const short* gB = convlf + (size_t)b * LL * NF + (size_t)(l0 + w * 32 + rowA) * NF + sw * 8;
    short* lA = &As[w * 32][0];
    short* lB = &Bs[w * 32][0];
    int rA = wm * 64, rB = wn * 64;
    int p7 = lr & 7;

    for (int kb = 0; kb < 8; ++kb) {
        int k0 = kb * 64;
#pragma unroll
        for (int c = 0; c < 4; ++c) {
            stage16(gA + (size_t)(8 * c) * NF + k0, lA + c * 8 * 64);
            stage16(gB + (size_t)(8 * c) * NF + k0, lB + c * 8 * 64);
        }
        __syncthreads();
#pragma unroll
        for (int kk = 0; kk < 2; ++kk) {
            half8 af[4], bf[4];
            int cs = ((kk << 2) + lg);
#pragma unroll
            for (int mi = 0; mi < 4; ++mi)
                af[mi] = *(const half8*)(&As[rA + mi * 16 + lr][(cs ^ p7) * 8]);
#pragma unroll
            for (int ni = 0; ni < 4; ++ni)
                bf[ni] = *(const half8*)(&Bs[rB + ni * 16 + lr][(cs ^ p7) * 8]);
#pragma unroll
            for (int mi = 0; mi < 4; ++mi)
#pragma unroll
                for (int ni = 0; ni < 4; ++ni)
                    acc[mi][ni] = __builtin_amdgcn_mfma_f32_16x16x32_f16(
                        af[mi], bf[ni], acc[mi][ni], 0, 0, 0);
        }
        __syncthreads();
    }

    int rbase = r0 + wm * 64, lbase = l0 + wn * 64;
#pragma unroll
    for (int mi = 0; mi < 4; ++mi)
#pragma unroll
        for (int ni = 0; ni < 4; ++ni)
#pragma unroll
            for (int rr = 0; rr < 4; ++rr) {
                int r = rbase + mi * 16 + lg * 4 + rr;
                int l = lbase + ni * 16 + lr;
                Gp[((size_t)b * RR + r) * LL + l] = (_Float16)acc[mi][ni][rr];
            }
}

// ---------- softmax over l per (b,r) row: f16 logits -> normalized f16 P, in place ----------
__global__ __launch_bounds__(256) void k_softmax(_Float16* __restrict__ Gp) {
    const float LOG2E = 1.4426950408889634f;
    int row = blockIdx.x * 4 + (threadIdx.x >> 6);   // b*RR + r
    int lane = threadIdx.x & 63;
    _Float16* base = Gp + (size_t)row * LL;
    half8 hv = *(const half8*)(base + lane * 8);
    float v[8];
#pragma unroll
    for (int j = 0; j < 8; ++j) v[j] = (float)hv[j];
    float m = v[0];
#pragma unroll
    for (int j = 1; j < 8; ++j) m = fmaxf(m, v[j]);
    for (int off = 1; off < 64; off <<= 1) m = fmaxf(m, __shfl_xor(m, off));
    float s = 0.f;
    float p[8];
#pragma unroll
    for (int j = 0; j < 8; ++j) { p[j] = exp2f((v[j] - m) * LOG2E); s += p[j]; }
    for (int off = 1; off < 64; off <<= 1) s += __shfl_xor(s, off);
    float inv = 1.f / s;
    short8 o;
#pragma unroll
    for (int j = 0; j < 8; ++j) o[j] = f2h(p[j] * inv);
    *(short8*)((short*)base + lane * 8) = o;
}

// ---------- wo MFMA: out[b,f] = relu(max_r sum_l conv_fl[b,f,l]*P[b,r,l]); K=512 ----------
__global__ __launch_bounds__(256) void k_wo_mfma(
    const short* __restrict__ convfl, const short* __restrict__ P,
    float* __restrict__ out) {
    int wg = xcd_swz(blockIdx.x, 2048);
    int b = wg >> 4;
    int f0 = ((wg >> 2) & 3) * 128;   // M
    int r0 = (wg & 3) * 128;          // N
    int tid = threadIdx.x, lane = tid & 63, w = tid >> 6;
    int wm = w >> 1, wn = w & 1;
    int lr = lane & 15, lg = lane >> 4;

    __shared__ __align__(16) short As[128][64];
    __shared__ __align__(16) short Bs[128][64];

    f32x4 acc[4][4];
    for (int i = 0; i < 4; ++i)
        for (int j = 0; j < 4; ++j) acc[i][j] = (f32x4){0.f, 0.f, 0.f, 0.f};

    int rowA = lane >> 3;
    int sw = (lane & 7) ^ rowA;
    const short* gA = convfl + (size_t)b * NF * LL + (size_t)(f0 + w * 32 + rowA) * LL + sw * 8;
    const short* gB = P + (size_t)b * RR * LL + (size_t)(r0 + w * 32 + rowA) * LL + sw * 8;
    short* lA = &As[w * 32][0];
    short* lB = &Bs[w * 32][0];
    int rA = wm * 64, rB = wn * 64;
    int p7 = lr & 7;

    for (int kb = 0; kb < 8; ++kb) {
        int k0 = kb * 64;
#pragma unroll
        for (int c = 0; c < 4; ++c) {
            stage16(gA + (size_t)(8 * c) * LL + k0, lA + c * 8 * 64);
            stage16(gB + (size_t)(8 * c) * LL + k0, lB + c * 8 * 64);
        }
        __syncthreads();
#pragma unroll
        for (int kk = 0; kk < 2; ++kk) {
            half8 af[4], bf[4];
            int cs = ((kk << 2) + lg);
#pragma unroll
            for (int mi = 0; mi < 4; ++mi)
                af[mi] = *(const half8*)(&As[rA + mi * 16 + lr][(cs ^ p7) * 8]);
#pragma unroll
            for (int ni = 0; ni < 4; ++ni)
                bf[ni] = *(const half8*)(&Bs[rB + ni * 16 + lr][(cs ^ p7) * 8]);
#pragma unroll
            for (int mi = 0; mi < 4; ++mi)
#pragma unroll
                for (int ni = 0; ni < 4; ++ni)
                    acc[mi][ni] = __builtin_amdgcn_mfma_f32_16x16x32_f16(
                        af[mi], bf[ni], acc[mi][ni], 0, 0, 0);
        }
        __syncthreads();
    }

    int fbase = f0 + wm * 64;
#pragma unroll
    for (int mi = 0; mi < 4; ++mi)
#pragma unroll
        for (int rr = 0; rr < 4; ++rr) {
            float m = acc[mi][0][rr];
#pragma unroll
            for (int ni = 1; ni < 4; ++ni) m = fmaxf(m, acc[mi][ni][rr]);
            m = fmaxf(m, __shfl_xor(m, 1));
            m = fmaxf(m, __shfl_xor(m, 2));
            m = fmaxf(m, __shfl_xor(m, 4));
            m = fmaxf(m, __shfl_xor(m, 8));
            if (lr == 0 && m > 0.f) {
                int f = fbase + mi * 16 + lg * 4 + rr;
                atomicMax((int*)&out[(size_t)b * NF + f], __float_as_int(m));
            }
        }
}

extern "C" void kernel_launch(void* const* d_in, const int* in_sizes, int n_in,
                              void* d_out, int out_size, void* d_ws, size_t ws_size,
                              hipStream_t stream) {
    const float* x      = (const float*)d_in[0];
    const float* e1     = (const float*)d_in[1];
    const float* e2     = (const float*)d_in[2];
    const float* posVec = (const float*)d_in[3];
    const float* We1    = (const float*)d_in[4];
    const float* We2    = (const float*)d_in[5];
    const float* U      = (const float*)d_in[6];
    const float* conv_w = (const float*)d_in[7];
    const float* conv_b = (const float*)d_in[8];
    const float* rel_w  = (const float*)d_in[9];
    float* out = (float*)d_out;

    // workspace: convlf 67M | convfl 67M | Gp 67M | pxp 50.5M | cwb 1.2M
    //            Qf 0.5M | small 1M  -> 254.6 MB (< 256 MiB)
    char* p = (char*)d_ws;
    short* convlf = (short*)p;  p += (size_t)BB * LL * NF * 2;
    short* convfl = (short*)p;  p += (size_t)BB * NF * LL * 2;
    _Float16* Gp  = (_Float16*)p;  p += (size_t)BB * RR * LL * 2;
    short* pxp    = (short*)p;  p += (size_t)BB * LP * DD * 2;
    short* cwb    = (short*)p;  p += (size_t)NF * DWIN * 2;
    short* QfW    = (short*)p;  p += (size_t)RR * NF * 2;
    float* v1     = (float*)p;  p += (size_t)BB * DW * 4;
    float* v2     = (float*)p;  p += (size_t)BB * DW * 4;
    float* A1     = (float*)p;  p += (size_t)BB * LL * 4;
    float* A2     = (float*)p;  p += (size_t)BB * LL * 4;
    float* alpha  = (float*)p;  p += (size_t)BB * LL * 4;

    k_ve<<<BB, DW, 0, stream>>>(We1, We2, e1, e2, v1, v2);
    k_pack_logits<<<(BB * LP) / 4, 256, 0, stream>>>(x, posVec, v1, v2, pxp, A1, A2);
    k_alpha<<<BB, LL, 0, stream>>>(A1, A2, alpha);
    k_pack_w<<<(NF * DWIN / 8) / 256, 256, 0, stream>>>(conv_w, cwb);
    k_w2t<<<dim3(NF / 64, RR / 64), 256, 0, stream>>>(U, rel_w, QfW);
    k_conv_mfma<<<2048, 256, 0, stream>>>(pxp, cwb, conv_b, alpha, convlf, convfl);
    k_g_mfma<<<2048, 256, 0, stream>>>(QfW, convlf, Gp);
    k_softmax<<<(BB * RR) / 4, 256, 0, stream>>>(Gp);
    hipMemsetAsync(d_out, 0, (size_t)BB * NF * sizeof(float), stream);
    k_wo_mfma<<<2048, 256, 0, stream>>>(convfl, (const short*)Gp, out);
    hipMemcpyAsync(out + BB * NF, rel_w, (size_t)NF * RR * sizeof(float),
                   hipMemcpyDeviceToDevice, stream);
}

// Round 12
// 328.078 us; speedup vs baseline: 1.2380x; 1.0027x over previous
//
#include <hip/hip_runtime.h>
#include <hip/hip_bf16.h>

#define BB 128
#define LL 512
#define DW 256
#define DP 64
#define NF 512
#define DD 384       // D = DW + 2*DP
#define DWIN 1152    // 3*D
#define RR 512       // nr
#define LP 514       // LL + 2 pad rows

typedef __attribute__((ext_vector_type(8))) short short8;
typedef __attribute__((ext_vector_type(4))) short short4v;
typedef __attribute__((ext_vector_type(2))) short short2v;
typedef __attribute__((ext_vector_type(8))) _Float16 half8;
typedef __attribute__((ext_vector_type(4))) float f32x4;
typedef __attribute__((ext_vector_type(2))) float f32x2;

typedef __attribute__((address_space(1))) const void* gas_t;
typedef __attribute__((address_space(3))) void* las_t;

__device__ __forceinline__ void stage16(const void* g, void* l) {
    __builtin_amdgcn_global_load_lds((gas_t)g, (las_t)l, 16, 0, 0);
}

__device__ inline short f2h(float v) {
    _Float16 h = (_Float16)v;
    return *reinterpret_cast<short*>(&h);
}
// XCD-chunked bijective swizzle (nwg % 8 == 0)
__device__ inline int xcd_swz(int bid, int nwg) {
    return (bid & 7) * (nwg >> 3) + (bid >> 3);
}

// ---------- small kernels (fp32-exact path for alpha) ----------
__global__ void k_ve(const float* __restrict__ We1, const float* __restrict__ We2,
                     const float* __restrict__ e1, const float* __restrict__ e2,
                     float* __restrict__ v1, float* __restrict__ v2) {
    int b = blockIdx.x;
    int d = threadIdx.x; // 256
    __shared__ float s1[DW], s2[DW];
    s1[d] = e1[b * DW + d];
    s2[d] = e2[b * DW + d];
    __syncthreads();
    float a1 = 0.f, a2 = 0.f;
    for (int e = 0; e < DW; ++e) {
        a1 += We1[d * DW + e] * s1[e];
        a2 += We2[d * DW + e] * s2[e];
    }
    v1[b * DW + d] = a1;
    v2[b * DW + d] = a2;
}

// fused: pack px row to f16 AND compute logits (one x read total)
__global__ __launch_bounds__(256) void k_pack_logits(
    const float* __restrict__ x, const float* __restrict__ pv,
    const float* __restrict__ v1, const float* __restrict__ v2,
    short* __restrict__ pxp, float* __restrict__ A1, float* __restrict__ A2) {
    int gr = blockIdx.x * 4 + (threadIdx.x >> 6);    // 0 .. BB*LP-1
    int lane = threadIdx.x & 63;
    int b = gr / LP;
    int rr = gr - b * LP;
    short* dst = pxp + (size_t)gr * DD;
    if (rr == 0 || rr == LP - 1) {
        *(short4v*)(dst + lane * 4) = (short4v){0, 0, 0, 0};
        *(short2v*)(dst + 256 + lane * 2) = (short2v){0, 0};
        return;
    }
    int l = rr - 1;
    f32x4 xv = *(const f32x4*)(x + ((size_t)b * LL + l) * DW + lane * 4);
    f32x2 pvv = *(const f32x2*)(pv + ((size_t)b * LL + l) * (2 * DP) + lane * 2);
    f32x4 w1 = *(const f32x4*)(v1 + b * DW + lane * 4);
    f32x4 w2 = *(const f32x4*)(v2 + b * DW + lane * 4);
    float p1 = xv[0] * w1[0] + xv[1] * w1[1] + xv[2] * w1[2] + xv[3] * w1[3];
    float p2 = xv[0] * w2[0] + xv[1] * w2[1] + xv[2] * w2[2] + xv[3] * w2[3];
    for (int off = 32; off; off >>= 1) {
        p1 += __shfl_down(p1, off);
        p2 += __shfl_down(p2, off);
    }
    short4v ox;
#pragma unroll
    for (int j = 0; j < 4; ++j) ox[j] = f2h(xv[j]);
    *(short4v*)(dst + lane * 4) = ox;
    short2v op;
    op[0] = f2h(pvv[0]);
    op[1] = f2h(pvv[1]);
    *(short2v*)(dst + 256 + lane * 2) = op;
    if (lane == 0) { A1[b * LL + l] = p1; A2[b * LL + l] = p2; }
}

__global__ void k_alpha(const float* __restrict__ A1, const float* __restrict__ A2,
                        float* __restrict__ alpha) {
    int b = blockIdx.x;
    int l = threadIdx.x; // 512
    __shared__ float s[LL];
    float a1 = A1[b * LL + l], a2 = A2[b * LL + l];

    s[l] = a1; __syncthreads();
    for (int st = 256; st; st >>= 1) { if (l < st) s[l] = fmaxf(s[l], s[l + st]); __syncthreads(); }
    float m1 = s[0]; __syncthreads();
    float e1x = expf(a1 - m1);
    s[l] = e1x; __syncthreads();
    for (int st = 256; st; st >>= 1) { if (l < st) s[l] += s[l + st]; __syncthreads(); }
    float d1 = s[0]; __syncthreads();

    s[l] = a2; __syncthreads();
    for (int st = 256; st; st >>= 1) { if (l < st) s[l] = fmaxf(s[l], s[l + st]); __syncthreads(); }
    float m2 = s[0]; __syncthreads();
    float e2x = expf(a2 - m2);
    s[l] = e2x; __syncthreads();
    for (int st = 256; st; st >>= 1) { if (l < st) s[l] += s[l + st]; __syncthreads(); }
    float d2 = s[0];

    alpha[b * LL + l] = 0.5f * (e1x / d1 + e2x / d2);
}

__global__ __launch_bounds__(256) void k_pack_w(const float* __restrict__ cw,
                                                short* __restrict__ cwb) {
    int idx = blockIdx.x * 256 + threadIdx.x;   // 512*1152/8 = 73,728
    const float* src = cw + (size_t)idx * 8;
    f32x4 u0 = *(const f32x4*)(src);
    f32x4 u1 = *(const f32x4*)(src + 4);
    short8 v;
#pragma unroll
    for (int jj = 0; jj < 4; ++jj) { v[jj] = f2h(u0[jj]); v[jj + 4] = f2h(u1[jj]); }
    *(short8*)(cwb + (size_t)idx * 8) = v;
}

// ---------- W2t[r][f] = sum_t rel_w[r,t]*U[f,t], f16 out ----------
__global__ void k_w2t(const float* __restrict__ U, const float* __restrict__ relw,
                      short* __restrict__ Qf) {
    __shared__ float As[16][65], Bs[16][65];
    int r0 = blockIdx.y * 64, f0 = blockIdx.x * 64;
    int tid = threadIdx.x, ty = tid >> 4, tx = tid & 15;
    float acc[4][4] = {};
    for (int k0 = 0; k0 < NF; k0 += 16) {
        for (int i = 0; i < 4; ++i) {
            int lin = tid + 256 * i;
            int kk = lin & 15, mm = lin >> 4;
            As[kk][mm] = relw[(r0 + mm) * NF + k0 + kk];
            Bs[kk][mm] = U[(f0 + mm) * NF + k0 + kk];
        }
        __syncthreads();
        for (int kk = 0; kk < 16; ++kk) {
            float av[4], bv[4];
            for (int i = 0; i < 4; ++i) av[i] = As[kk][ty * 4 + i];
            for (int j = 0; j < 4; ++j) bv[j] = Bs[kk][tx * 4 + j];
            for (int i = 0; i < 4; ++i)
                for (int j = 0; j < 4; ++j) acc[i][j] += av[i] * bv[j];
        }
        __syncthreads();
    }
    for (int i = 0; i < 4; ++i)
        for (int j = 0; j < 4; ++j)
            Qf[(size_t)(r0 + ty * 4 + i) * NF + f0 + tx * 4 + j] = f2h(acc[i][j]);
}

// ---------- conv MFMA via global_load_lds (f16), BK=32 (proven R9 form) ----------
__global__ __launch_bounds__(256) void k_conv_mfma(
    const short* __restrict__ pxp, const short* __restrict__ cwb,
    const float* __restrict__ conv_b, const float* __restrict__ alpha,
    short* __restrict__ conv_lf, short* __restrict__ conv_fl) {
    int wg = xcd_swz(blockIdx.x, 2048);
    int b = wg >> 4;
    int l0 = ((wg >> 2) & 3) * 128;
    int f0 = (wg & 3) * 128;
    int tid = threadIdx.x;
    int lane = tid & 63, w = tid >> 6;
    int wm = w >> 1, wn = w & 1;
    int lr = lane & 15, lg = lane >> 4;

    // union: K-loop As/Bs (2*8192B linear); epilogue T[128][136] (34816B)
    __shared__ __align__(16) char smem[34816];
    short (*As)[32] = (short(*)[32])smem;
    short (*Bs)[32] = (short(*)[32])(smem + 8192);
    short (*T)[136] = (short(*)[136])smem;

    f32x4 acc[4][4];
    for (int i = 0; i < 4; ++i)
        for (int j = 0; j < 4; ++j) acc[i][j] = (f32x4){0.f, 0.f, 0.f, 0.f};

    int rowA = lane >> 2;                       // 0..15
    int sw = (lane & 3) ^ ((rowA >> 1) & 3);    // pre-swizzled source slot
    const short* gA = pxp + ((size_t)b * LP + l0 + w * 32 + rowA) * DD + sw * 8;
    const short* gB = cwb + (size_t)(f0 + w * 32 + rowA) * DWIN + sw * 8;
    short* lA = &As[w * 32][0];
    short* lB = &Bs[w * 32][0];
    int rsw = (lg ^ ((lr >> 1) & 3)) * 8;       // read-side slot offset
    int rA = wm * 64, rB = wn * 64;

    for (int kb = 0; kb < 36; ++kb) {
        int k0 = kb * 32;
        stage16(gA + k0, lA);
        stage16(gA + 16 * DD + k0, lA + 16 * 32);
        stage16(gB + k0, lB);
        stage16(gB + (size_t)16 * DWIN + k0, lB + 16 * 32);
        __syncthreads();
        half8 af[4], bf[4];
#pragma unroll
        for (int mi = 0; mi < 4; ++mi)
            af[mi] = *(const half8*)(&As[rA + mi * 16 + lr][rsw]);
#pragma unroll
        for (int ni = 0; ni < 4; ++ni)
            bf[ni] = *(const half8*)(&Bs[rB + ni * 16 + lr][rsw]);
#pragma unroll
        for (int mi = 0; mi < 4; ++mi)
#pragma unroll
            for (int ni = 0; ni < 4; ++ni)
                acc[mi][ni] = __builtin_amdgcn_mfma_f32_16x16x32_f16(
                    af[mi], bf[ni], acc[mi][ni], 0, 0, 0);
        __syncthreads();
    }

    int lbase = l0 + wm * 64, fbase = f0 + wn * 64;
#pragma unroll
    for (int mi = 0; mi < 4; ++mi) {
        f32x4 av = *(const f32x4*)(alpha + (size_t)b * LL + lbase + mi * 16 + lg * 4);
        int lrow = lbase + mi * 16 + lg * 4;
#pragma unroll
        for (int ni = 0; ni < 4; ++ni) {
            int f = fbase + ni * 16 + lr;
            float bias = conv_b[f];
            short4v o;
#pragma unroll
            for (int r = 0; r < 4; ++r) {
                float val = tanhf(av[r] * acc[mi][ni][r] + bias);
                short sv = f2h(val);
                o[r] = sv;
                conv_lf[((size_t)b * LL + lrow + r) * NF + f] = sv;
            }
            *(short4v*)(&T[wn * 64 + ni * 16 + lr][wm * 64 + mi * 16 + lg * 4]) = o;
        }
    }
    __syncthreads();
#pragma unroll
    for (int i = 0; i < 8; ++i) {
        int lin = tid + 256 * i;
        int frow = lin >> 4;
        int q = lin & 15;
        short8 v = *(const short8*)(&T[frow][q * 8]);
        *(short8*)(conv_fl + ((size_t)b * NF + f0 + frow) * LL + l0 + q * 8) = v;
    }
}

// ---------- G+softmax fused: P[b][r][l] = softmax_l( Qf[r,:]·conv_lf[b,l,:] ) ----------
// tile: 128 r x 512 l (full rows), K=512, BK=64, 512 threads (2x4 waves)
__global__ __launch_bounds__(512) void k_g_mfma(
    const short* __restrict__ Qf,
    const short* __restrict__ convlf, _Float16* __restrict__ Gp) {
    const float LOG2E = 1.4426950408889634f;
    int wg = xcd_swz(blockIdx.x, 512);
    int b = wg >> 2;                  // 0..127
    int r0 = (wg & 3) * 128;
    int tid = threadIdx.x, lane = tid & 63, w = tid >> 6;
    int wm = w >> 2, wn = w & 3;      // 2 x 4 wave grid
    int lr = lane & 15, lg = lane >> 4;

    // A tile 128x64 f16 = 16KB; B tile 512x64 f16 = 64KB
    __shared__ __align__(16) char smem[81920];
    short* Ab = (short*)smem;
    short* Bb = (short*)(smem + 16384);
    float (*rowred)[4] = (float(*)[4])smem;   // epilogue reuse (2KB)

    f32x4 acc[4][8];
#pragma unroll
    for (int i = 0; i < 4; ++i)
#pragma unroll
        for (int j = 0; j < 8; ++j) acc[i][j] = (f32x4){0.f, 0.f, 0.f, 0.f};

    // staging: flat thread tid covers row tid>>3, slot tid&7 per 64-row call
    int trow = tid >> 3;                   // 0..63
    int sw = (tid & 7) ^ (trow & 7);       // pre-swizzled source chunk
    const short* gA = Qf + (size_t)(r0 + trow) * NF + sw * 8;
    const short* gB = convlf + (size_t)b * LL * NF + (size_t)trow * NF + sw * 8;
    short* lAd = Ab + w * 512;             // per-wave dest base (shorts)
    short* lBd = Bb + w * 512;
    int p7 = lr & 7;

    for (int kb = 0; kb < 8; ++kb) {
        int k0 = kb * 64;
#pragma unroll
        for (int c = 0; c < 2; ++c)
            stage16(gA + (size_t)(64 * c) * NF + k0, lAd + c * 4096);
#pragma unroll
        for (int c = 0; c < 8; ++c)
            stage16(gB + (size_t)(64 * c) * NF + k0, lBd + c * 4096);
        __syncthreads();
#pragma unroll
        for (int kk = 0; kk < 2; ++kk) {
            int cs = (kk << 2) + lg;
            half8 af[4], bf[8];
#pragma unroll
            for (int mi = 0; mi < 4; ++mi)
                af[mi] = *(const half8*)(Ab + (wm * 64 + mi * 16 + lr) * 64 + ((cs ^ p7) * 8));
#pragma unroll
            for (int ni = 0; ni < 8; ++ni)
                bf[ni] = *(const half8*)(Bb + (wn * 128 + ni * 16 + lr) * 64 + ((cs ^ p7) * 8));
#pragma unroll
            for (int mi = 0; mi < 4; ++mi)
#pragma unroll
                for (int ni = 0; ni < 8; ++ni)
                    acc[mi][ni] = __builtin_amdgcn_mfma_f32_16x16x32_f16(
                        af[mi], bf[ni], acc[mi][ni], 0, 0, 0);
        }
        __syncthreads();
    }

    // ---- in-register softmax over full l rows ----
    // lane holds rows r_loc = wm*64 + mi*16 + lg*4 + rr, l = wn*128 + ni*16 + lr
    float mrow[4][4];
#pragma unroll
    for (int mi = 0; mi < 4; ++mi)
#pragma unroll
        for (int rr = 0; rr < 4; ++rr) {
            float m = acc[mi][0][rr];
#pragma unroll
            for (int ni = 1; ni < 8; ++ni) m = fmaxf(m, acc[mi][ni][rr]);
            m = fmaxf(m, __shfl_xor(m, 1));
            m = fmaxf(m, __shfl_xor(m, 2));
            m = fmaxf(m, __shfl_xor(m, 4));
            m = fmaxf(m, __shfl_xor(m, 8));
            mrow[mi][rr] = m;
        }
    if (lr == 0) {
#pragma unroll
        for (int mi = 0; mi < 4; ++mi)
#pragma unroll
            for (int rr = 0; rr < 4; ++rr)
                rowred[wm * 64 + mi * 16 + lg * 4 + rr][wn] = mrow[mi][rr];
    }
    __syncthreads();
#pragma unroll
    for (int mi = 0; mi < 4; ++mi)
#pragma unroll
        for (int rr = 0; rr < 4; ++rr) {
            f32x4 rv = *(const f32x4*)rowred[wm * 64 + mi * 16 + lg * 4 + rr];
            mrow[mi][rr] = fmaxf(fmaxf(rv[0], rv[1]), fmaxf(rv[2], rv[3]));
        }
    __syncthreads();
    float srow[4][4];
#pragma unroll
    for (int mi = 0; mi < 4; ++mi)
#pragma unroll
        for (int rr = 0; rr < 4; ++rr) {
            float s = 0.f;
            float m = mrow[mi][rr];
#pragma unroll
            for (int ni = 0; ni < 8; ++ni) {
                float pp = exp2f((acc[mi][ni][rr] - m) * LOG2E);
                acc[mi][ni][rr] = pp;
                s += pp;
            }
            s += __shfl_xor(s, 1);
            s += __shfl_xor(s, 2);
            s += __shfl_xor(s, 4);
            s += __shfl_xor(s, 8);
            srow[mi][rr] = s;
        }
    if (lr == 0) {
#pragma unroll
        for (int mi = 0; mi < 4; ++mi)
#pragma unroll
            for (int rr = 0; rr < 4; ++rr)
                rowred[wm * 64 + mi * 16 + lg * 4 + rr][wn] = srow[mi][rr];
    }
    __syncthreads();
#pragma unroll
    for (int mi = 0; mi < 4; ++mi)
#pragma unroll
        for (int rr = 0; rr < 4; ++rr) {
            f32x4 rv = *(const f32x4*)rowred[wm * 64 + mi * 16 + lg * 4 + rr];
            srow[mi][rr] = 1.f / (rv[0] + rv[1] + rv[2] + rv[3]);
        }

    // ---- write normalized P (f16) ----
#pragma unroll
    for (int mi = 0; mi < 4; ++mi)
#pragma unroll
        for (int ni = 0; ni < 8; ++ni)
#pragma unroll
            for (int rr = 0; rr < 4; ++rr) {
                int r = r0 + wm * 64 + mi * 16 + lg * 4 + rr;
                int l = wn * 128 + ni * 16 + lr;
                Gp[((size_t)b * RR + r) * LL + l] = (_Float16)(acc[mi][ni][rr] * srow[mi][rr]);
            }
}

// ---------- wo MFMA: out[b,f] = relu(max_r sum_l conv_fl[b,f,l]*P[b,r,l]); K=512 ----------
__global__ __launch_bounds__(256) void k_wo_mfma(
    const short* __restrict__ convfl, const short* __restrict__ P,
    float* __restrict__ out) {
    int wg = xcd_swz(blockIdx.x, 2048);
    int b = wg >> 4;
    int f0 = ((wg >> 2) & 3) * 128;   // M
    int r0 = (wg & 3) * 128;          // N
    int tid = threadIdx.x, lane = tid & 63, w = tid >> 6;
    int wm = w >> 1, wn = w & 1;
    int lr = lane & 15, lg = lane >> 4;

    __shared__ __align__(16) short As[128][64];
    __shared__ __align__(16) short Bs[128][64];

    f32x4 acc[4][4];
    for (int i = 0; i < 4; ++i)
        for (int j = 0; j < 4; ++j) acc[i][j] = (f32x4){0.f, 0.f, 0.f, 0.f};

    int rowA = lane >> 3;
    int sw = (lane & 7) ^ rowA;
    const short* gA = convfl + (size_t)b * NF * LL + (size_t)(f0 + w * 32 + rowA) * LL + sw * 8;
    const short* gB = P + (size_t)b * RR * LL + (size_t)(r0 + w * 32 + rowA) * LL + sw * 8;
    short* lA = &As[w * 32][0];
    short* lB = &Bs[w * 32][0];
    int rA = wm * 64, rB = wn * 64;
    int p7 = lr & 7;

    for (int kb = 0; kb < 8; ++kb) {
        int k0 = kb * 64;
#pragma unroll
        for (int c = 0; c < 4; ++c) {
            stage16(gA + (size_t)(8 * c) * LL + k0, lA + c * 8 * 64);
            stage16(gB + (size_t)(8 * c) * LL + k0, lB + c * 8 * 64);
        }
        __syncthreads();
#pragma unroll
        for (int kk = 0; kk < 2; ++kk) {
            half8 af[4], bf[4];
            int cs = ((kk << 2) + lg);
#pragma unroll
            for (int mi = 0; mi < 4; ++mi)
                af[mi] = *(const half8*)(&As[rA + mi * 16 + lr][(cs ^ p7) * 8]);
#pragma unroll
            for (int ni = 0; ni < 4; ++ni)
                bf[ni] = *(const half8*)(&Bs[rB + ni * 16 + lr][(cs ^ p7) * 8]);
#pragma unroll
            for (int mi = 0; mi < 4; ++mi)
#pragma unroll
                for (int ni = 0; ni < 4; ++ni)
                    acc[mi][ni] = __builtin_amdgcn_mfma_f32_16x16x32_f16(
                        af[mi], bf[ni], acc[mi][ni], 0, 0, 0);
        }
        __syncthreads();
    }

    int fbase = f0 + wm * 64;
#pragma unroll
    for (int mi = 0; mi < 4; ++mi)
#pragma unroll
        for (int rr = 0; rr < 4; ++rr) {
            float m = acc[mi][0][rr];
#pragma unroll
            for (int ni = 1; ni < 4; ++ni) m = fmaxf(m, acc[mi][ni][rr]);
            m = fmaxf(m, __shfl_xor(m, 1));
            m = fmaxf(m, __shfl_xor(m, 2));
            m = fmaxf(m, __shfl_xor(m, 4));
            m = fmaxf(m, __shfl_xor(m, 8));
            if (lr == 0 && m > 0.f) {
                int f = fbase + mi * 16 + lg * 4 + rr;
                atomicMax((int*)&out[(size_t)b * NF + f], __float_as_int(m));
            }
        }
}

extern "C" void kernel_launch(void* const* d_in, const int* in_sizes, int n_in,
                              void* d_out, int out_size, void* d_ws, size_t ws_size,
                              hipStream_t stream) {
    const float* x      = (const float*)d_in[0];
    const float* e1     = (const float*)d_in[1];
    const float* e2     = (const float*)d_in[2];
    const float* posVec = (const float*)d_in[3];
    const float* We1    = (const float*)d_in[4];
    const float* We2    = (const float*)d_in[5];
    const float* U      = (const float*)d_in[6];
    const float* conv_w = (const float*)d_in[7];
    const float* conv_b = (const float*)d_in[8];
    const float* rel_w  = (const float*)d_in[9];
    float* out = (float*)d_out;

    // workspace: convlf 67M | convfl 67M | Gp 67M | pxp 50.5M | cwb 1.2M
    //            Qf 0.5M | small 1M  -> 254.6 MB (< 256 MiB)
    char* p = (char*)d_ws;
    short* convlf = (short*)p;  p += (size_t)BB * LL * NF * 2;
    short* convfl = (short*)p;  p += (size_t)BB * NF * LL * 2;
    _Float16* Gp  = (_Float16*)p;  p += (size_t)BB * RR * LL * 2;
    short* pxp    = (short*)p;  p += (size_t)BB * LP * DD * 2;
    short* cwb    = (short*)p;  p += (size_t)NF * DWIN * 2;
    short* QfW    = (short*)p;  p += (size_t)RR * NF * 2;
    float* v1     = (float*)p;  p += (size_t)BB * DW * 4;
    float* v2     = (float*)p;  p += (size_t)BB * DW * 4;
    float* A1     = (float*)p;  p += (size_t)BB * LL * 4;
    float* A2     = (float*)p;  p += (size_t)BB * LL * 4;
    float* alpha  = (float*)p;  p += (size_t)BB * LL * 4;

    k_ve<<<BB, DW, 0, stream>>>(We1, We2, e1, e2, v1, v2);
    k_pack_logits<<<(BB * LP) / 4, 256, 0, stream>>>(x, posVec, v1, v2, pxp, A1, A2);
    k_alpha<<<BB, LL, 0, stream>>>(A1, A2, alpha);
    k_pack_w<<<(NF * DWIN / 8) / 256, 256, 0, stream>>>(conv_w, cwb);
    k_w2t<<<dim3(NF / 64, RR / 64), 256, 0, stream>>>(U, rel_w, QfW);
    k_conv_mfma<<<2048, 256, 0, stream>>>(pxp, cwb, conv_b, alpha, convlf, convfl);
    k_g_mfma<<<512, 512, 0, stream>>>(QfW, convlf, Gp);
    hipMemsetAsync(d_out, 0, (size_t)BB * NF * sizeof(float), stream);
    k_wo_mfma<<<2048, 256, 0, stream>>>(convfl, (const short*)Gp, out);
    hipMemcpyAsync(out + BB * NF, rel_w, (size_t)NF * RR * sizeof(float),
                   hipMemcpyDeviceToDevice, stream);
}

// Round 13
// 326.735 us; speedup vs baseline: 1.2431x; 1.0041x over previous
//
#include <hip/hip_runtime.h>
#include <hip/hip_bf16.h>

#define BB 128
#define LL 512
#define DW 256
#define DP 64
#define NF 512
#define DD 384       // D = DW + 2*DP
#define DWIN 1152    // 3*D
#define RR 512       // nr
#define LP 514       // LL + 2 pad rows

typedef __attribute__((ext_vector_type(8))) short short8;
typedef __attribute__((ext_vector_type(4))) short short4v;
typedef __attribute__((ext_vector_type(2))) short short2v;
typedef __attribute__((ext_vector_type(8))) _Float16 half8;
typedef __attribute__((ext_vector_type(4))) float f32x4;
typedef __attribute__((ext_vector_type(2))) float f32x2;

typedef __attribute__((address_space(1))) const void* gas_t;
typedef __attribute__((address_space(3))) void* las_t;

__device__ __forceinline__ void stage16(const void* g, void* l) {
    __builtin_amdgcn_global_load_lds((gas_t)g, (las_t)l, 16, 0, 0);
}

__device__ inline short f2h(float v) {
    _Float16 h = (_Float16)v;
    return *reinterpret_cast<short*>(&h);
}
// XCD-chunked bijective swizzle (nwg % 8 == 0)
__device__ inline int xcd_swz(int bid, int nwg) {
    return (bid & 7) * (nwg >> 3) + (bid >> 3);
}

// ---------- small kernels (fp32-exact path for alpha) ----------
__global__ void k_ve(const float* __restrict__ We1, const float* __restrict__ We2,
                     const float* __restrict__ e1, const float* __restrict__ e2,
                     float* __restrict__ v1, float* __restrict__ v2) {
    int b = blockIdx.x;
    int d = threadIdx.x; // 256
    __shared__ float s1[DW], s2[DW];
    s1[d] = e1[b * DW + d];
    s2[d] = e2[b * DW + d];
    __syncthreads();
    float a1 = 0.f, a2 = 0.f;
    for (int e = 0; e < DW; ++e) {
        a1 += We1[d * DW + e] * s1[e];
        a2 += We2[d * DW + e] * s2[e];
    }
    v1[b * DW + d] = a1;
    v2[b * DW + d] = a2;
}

// fused: pack px row to f16 AND compute logits (one x read total)
__global__ __launch_bounds__(256) void k_pack_logits(
    const float* __restrict__ x, const float* __restrict__ pv,
    const float* __restrict__ v1, const float* __restrict__ v2,
    short* __restrict__ pxp, float* __restrict__ A1, float* __restrict__ A2) {
    int gr = blockIdx.x * 4 + (threadIdx.x >> 6);    // 0 .. BB*LP-1
    int lane = threadIdx.x & 63;
    int b = gr / LP;
    int rr = gr - b * LP;
    short* dst = pxp + (size_t)gr * DD;
    if (rr == 0 || rr == LP - 1) {
        *(short4v*)(dst + lane * 4) = (short4v){0, 0, 0, 0};
        *(short2v*)(dst + 256 + lane * 2) = (short2v){0, 0};
        return;
    }
    int l = rr - 1;
    f32x4 xv = *(const f32x4*)(x + ((size_t)b * LL + l) * DW + lane * 4);
    f32x2 pvv = *(const f32x2*)(pv + ((size_t)b * LL + l) * (2 * DP) + lane * 2);
    f32x4 w1 = *(const f32x4*)(v1 + b * DW + lane * 4);
    f32x4 w2 = *(const f32x4*)(v2 + b * DW + lane * 4);
    float p1 = xv[0] * w1[0] + xv[1] * w1[1] + xv[2] * w1[2] + xv[3] * w1[3];
    float p2 = xv[0] * w2[0] + xv[1] * w2[1] + xv[2] * w2[2] + xv[3] * w2[3];
    for (int off = 32; off; off >>= 1) {
        p1 += __shfl_down(p1, off);
        p2 += __shfl_down(p2, off);
    }
    short4v ox;
#pragma unroll
    for (int j = 0; j < 4; ++j) ox[j] = f2h(xv[j]);
    *(short4v*)(dst + lane * 4) = ox;
    short2v op;
    op[0] = f2h(pvv[0]);
    op[1] = f2h(pvv[1]);
    *(short2v*)(dst + 256 + lane * 2) = op;
    if (lane == 0) { A1[b * LL + l] = p1; A2[b * LL + l] = p2; }
}

__global__ void k_alpha(const float* __restrict__ A1, const float* __restrict__ A2,
                        float* __restrict__ alpha) {
    int b = blockIdx.x;
    int l = threadIdx.x; // 512
    __shared__ float s[LL];
    float a1 = A1[b * LL + l], a2 = A2[b * LL + l];

    s[l] = a1; __syncthreads();
    for (int st = 256; st; st >>= 1) { if (l < st) s[l] = fmaxf(s[l], s[l + st]); __syncthreads(); }
    float m1 = s[0]; __syncthreads();
    float e1x = expf(a1 - m1);
    s[l] = e1x; __syncthreads();
    for (int st = 256; st; st >>= 1) { if (l < st) s[l] += s[l + st]; __syncthreads(); }
    float d1 = s[0]; __syncthreads();

    s[l] = a2; __syncthreads();
    for (int st = 256; st; st >>= 1) { if (l < st) s[l] = fmaxf(s[l], s[l + st]); __syncthreads(); }
    float m2 = s[0]; __syncthreads();
    float e2x = expf(a2 - m2);
    s[l] = e2x; __syncthreads();
    for (int st = 256; st; st >>= 1) { if (l < st) s[l] += s[l + st]; __syncthreads(); }
    float d2 = s[0];

    alpha[b * LL + l] = 0.5f * (e1x / d1 + e2x / d2);
}

__global__ __launch_bounds__(256) void k_pack_w(const float* __restrict__ cw,
                                                short* __restrict__ cwb) {
    int idx = blockIdx.x * 256 + threadIdx.x;   // 512*1152/8 = 73,728
    const float* src = cw + (size_t)idx * 8;
    f32x4 u0 = *(const f32x4*)(src);
    f32x4 u1 = *(const f32x4*)(src + 4);
    short8 v;
#pragma unroll
    for (int jj = 0; jj < 4; ++jj) { v[jj] = f2h(u0[jj]); v[jj + 4] = f2h(u1[jj]); }
    *(short8*)(cwb + (size_t)idx * 8) = v;
}

// ---------- W2t[r][f] = sum_t rel_w[r,t]*U[f,t], f16 out ----------
__global__ void k_w2t(const float* __restrict__ U, const float* __restrict__ relw,
                      short* __restrict__ Qf) {
    __shared__ float As[16][65], Bs[16][65];
    int r0 = blockIdx.y * 64, f0 = blockIdx.x * 64;
    int tid = threadIdx.x, ty = tid >> 4, tx = tid & 15;
    float acc[4][4] = {};
    for (int k0 = 0; k0 < NF; k0 += 16) {
        for (int i = 0; i < 4; ++i) {
            int lin = tid + 256 * i;
            int kk = lin & 15, mm = lin >> 4;
            As[kk][mm] = relw[(r0 + mm) * NF + k0 + kk];
            Bs[kk][mm] = U[(f0 + mm) * NF + k0 + kk];
        }
        __syncthreads();
        for (int kk = 0; kk < 16; ++kk) {
            float av[4], bv[4];
            for (int i = 0; i < 4; ++i) av[i] = As[kk][ty * 4 + i];
            for (int j = 0; j < 4; ++j) bv[j] = Bs[kk][tx * 4 + j];
            for (int i = 0; i < 4; ++i)
                for (int j = 0; j < 4; ++j) acc[i][j] += av[i] * bv[j];
        }
        __syncthreads();
    }
    for (int i = 0; i < 4; ++i)
        for (int j = 0; j < 4; ++j)
            Qf[(size_t)(r0 + ty * 4 + i) * NF + f0 + tx * 4 + j] = f2h(acc[i][j]);
}

// ---------- conv MFMA, BK=32, counted-vmcnt double-buffered pipeline ----------
__global__ __launch_bounds__(256) void k_conv_mfma(
    const short* __restrict__ pxp, const short* __restrict__ cwb,
    const float* __restrict__ conv_b, const float* __restrict__ alpha,
    short* __restrict__ conv_lf, short* __restrict__ conv_fl) {
    int wg = xcd_swz(blockIdx.x, 2048);
    int b = wg >> 4;
    int l0 = ((wg >> 2) & 3) * 128;
    int f0 = (wg & 3) * 128;
    int tid = threadIdx.x;
    int lane = tid & 63, w = tid >> 6;
    int wm = w >> 1, wn = w & 1;
    int lr = lane & 15, lg = lane >> 4;

    // dbuf: buf t at smem + (t&1)*16384 {A 8192, B 8192}; epilogue T[128][136]
    __shared__ __align__(16) char smem[34816];
    short (*T)[136] = (short(*)[136])smem;

    f32x4 acc[4][4];
    for (int i = 0; i < 4; ++i)
        for (int j = 0; j < 4; ++j) acc[i][j] = (f32x4){0.f, 0.f, 0.f, 0.f};

    int rowA = lane >> 2;                       // 0..15
    int sw = (lane & 3) ^ ((rowA >> 1) & 3);    // pre-swizzled source slot
    const short* gA = pxp + ((size_t)b * LP + l0 + w * 32 + rowA) * DD + sw * 8;
    const short* gB = cwb + (size_t)(f0 + w * 32 + rowA) * DWIN + sw * 8;
    int rsw = (lg ^ ((lr >> 1) & 3)) * 8;       // read-side slot offset
    int rA = wm * 64, rB = wn * 64;

    // prologue: stage tile 0 into buf 0 (4 loads/thread)
    {
        char* nbuf = smem;
        stage16(gA, nbuf + w * 2048);
        stage16(gA + 16 * DD, nbuf + w * 2048 + 1024);
        stage16(gB, nbuf + 8192 + w * 2048);
        stage16(gB + (size_t)16 * DWIN, nbuf + 8192 + w * 2048 + 1024);
    }

    for (int t = 0; t < 36; ++t) {
        char* cbuf = smem + (t & 1) * 16384;
        if (t + 1 < 36) {
            char* nbuf = smem + ((t + 1) & 1) * 16384;
            int k0 = (t + 1) * 32;
            stage16(gA + k0, nbuf + w * 2048);
            stage16(gA + 16 * DD + k0, nbuf + w * 2048 + 1024);
            stage16(gB + k0, nbuf + 8192 + w * 2048);
            stage16(gB + (size_t)16 * DWIN + k0, nbuf + 8192 + w * 2048 + 1024);
            asm volatile("s_waitcnt vmcnt(4)" ::: "memory");   // tile t landed; t+1 in flight
        } else {
            asm volatile("s_waitcnt vmcnt(0)" ::: "memory");
        }
        __builtin_amdgcn_s_barrier();
        __builtin_amdgcn_sched_barrier(0);
        const short (*Ac)[32] = (const short(*)[32])cbuf;
        const short (*Bc)[32] = (const short(*)[32])(cbuf + 8192);
        half8 af[4], bf[4];
#pragma unroll
        for (int mi = 0; mi < 4; ++mi)
            af[mi] = *(const half8*)(&Ac[rA + mi * 16 + lr][rsw]);
#pragma unroll
        for (int ni = 0; ni < 4; ++ni)
            bf[ni] = *(const half8*)(&Bc[rB + ni * 16 + lr][rsw]);
#pragma unroll
        for (int mi = 0; mi < 4; ++mi)
#pragma unroll
            for (int ni = 0; ni < 4; ++ni)
                acc[mi][ni] = __builtin_amdgcn_mfma_f32_16x16x32_f16(
                    af[mi], bf[ni], acc[mi][ni], 0, 0, 0);
        __builtin_amdgcn_sched_barrier(0);
        __builtin_amdgcn_s_barrier();           // release buf[t&1] for overwrite at t+1
        __builtin_amdgcn_sched_barrier(0);
    }

    int lbase = l0 + wm * 64, fbase = f0 + wn * 64;
#pragma unroll
    for (int mi = 0; mi < 4; ++mi) {
        f32x4 av = *(const f32x4*)(alpha + (size_t)b * LL + lbase + mi * 16 + lg * 4);
        int lrow = lbase + mi * 16 + lg * 4;
#pragma unroll
        for (int ni = 0; ni < 4; ++ni) {
            int f = fbase + ni * 16 + lr;
            float bias = conv_b[f];
            short4v o;
#pragma unroll
            for (int r = 0; r < 4; ++r) {
                float val = tanhf(av[r] * acc[mi][ni][r] + bias);
                short sv = f2h(val);
                o[r] = sv;
                conv_lf[((size_t)b * LL + lrow + r) * NF + f] = sv;
            }
            *(short4v*)(&T[wn * 64 + ni * 16 + lr][wm * 64 + mi * 16 + lg * 4]) = o;
        }
    }
    __syncthreads();
#pragma unroll
    for (int i = 0; i < 8; ++i) {
        int lin = tid + 256 * i;
        int frow = lin >> 4;
        int q = lin & 15;
        short8 v = *(const short8*)(&T[frow][q * 8]);
        *(short8*)(conv_fl + ((size_t)b * NF + f0 + frow) * LL + l0 + q * 8) = v;
    }
}

// ---------- G+softmax fused: P[b][r][l] = softmax_l( Qf[r,:]·conv_lf[b,l,:] ) ----------
// tile: 128 r x 512 l (full rows), K=512, BK=64, 512 threads (2x4 waves)
__global__ __launch_bounds__(512) void k_g_mfma(
    const short* __restrict__ Qf,
    const short* __restrict__ convlf, _Float16* __restrict__ Gp) {
    const float LOG2E = 1.4426950408889634f;
    int wg = xcd_swz(blockIdx.x, 512);
    int b = wg >> 2;                  // 0..127
    int r0 = (wg & 3) * 128;
    int tid = threadIdx.x, lane = tid & 63, w = tid >> 6;
    int wm = w >> 2, wn = w & 3;      // 2 x 4 wave grid
    int lr = lane & 15, lg = lane >> 4;

    // A tile 128x64 f16 = 16KB; B tile 512x64 f16 = 64KB
    __shared__ __align__(16) char smem[81920];
    short* Ab = (short*)smem;
    short* Bb = (short*)(smem + 16384);
    float (*rowred)[4] = (float(*)[4])smem;   // epilogue reuse (2KB)

    f32x4 acc[4][8];
#pragma unroll
    for (int i = 0; i < 4; ++i)
#pragma unroll
        for (int j = 0; j < 8; ++j) acc[i][j] = (f32x4){0.f, 0.f, 0.f, 0.f};

    int trow = tid >> 3;                   // 0..63
    int sw = (tid & 7) ^ (trow & 7);       // pre-swizzled source chunk
    const short* gA = Qf + (size_t)(r0 + trow) * NF + sw * 8;
    const short* gB = convlf + (size_t)b * LL * NF + (size_t)trow * NF + sw * 8;
    short* lAd = Ab + w * 512;             // per-wave dest base (shorts)
    short* lBd = Bb + w * 512;
    int p7 = lr & 7;

    for (int kb = 0; kb < 8; ++kb) {
        int k0 = kb * 64;
#pragma unroll
        for (int c = 0; c < 2; ++c)
            stage16(gA + (size_t)(64 * c) * NF + k0, lAd + c * 4096);
#pragma unroll
        for (int c = 0; c < 8; ++c)
            stage16(gB + (size_t)(64 * c) * NF + k0, lBd + c * 4096);
        __syncthreads();
#pragma unroll
        for (int kk = 0; kk < 2; ++kk) {
            int cs = (kk << 2) + lg;
            half8 af[4], bf[8];
#pragma unroll
            for (int mi = 0; mi < 4; ++mi)
                af[mi] = *(const half8*)(Ab + (wm * 64 + mi * 16 + lr) * 64 + ((cs ^ p7) * 8));
#pragma unroll
            for (int ni = 0; ni < 8; ++ni)
                bf[ni] = *(const half8*)(Bb + (wn * 128 + ni * 16 + lr) * 64 + ((cs ^ p7) * 8));
#pragma unroll
            for (int mi = 0; mi < 4; ++mi)
#pragma unroll
                for (int ni = 0; ni < 8; ++ni)
                    acc[mi][ni] = __builtin_amdgcn_mfma_f32_16x16x32_f16(
                        af[mi], bf[ni], acc[mi][ni], 0, 0, 0);
        }
        __syncthreads();
    }

    // ---- in-register softmax over full l rows ----
    float mrow[4][4];
#pragma unroll
    for (int mi = 0; mi < 4; ++mi)
#pragma unroll
        for (int rr = 0; rr < 4; ++rr) {
            float m = acc[mi][0][rr];
#pragma unroll
            for (int ni = 1; ni < 8; ++ni) m = fmaxf(m, acc[mi][ni][rr]);
            m = fmaxf(m, __shfl_xor(m, 1));
            m = fmaxf(m, __shfl_xor(m, 2));
            m = fmaxf(m, __shfl_xor(m, 4));
            m = fmaxf(m, __shfl_xor(m, 8));
            mrow[mi][rr] = m;
        }
    if (lr == 0) {
#pragma unroll
        for (int mi = 0; mi < 4; ++mi)
#pragma unroll
            for (int rr = 0; rr < 4; ++rr)
                rowred[wm * 64 + mi * 16 + lg * 4 + rr][wn] = mrow[mi][rr];
    }
    __syncthreads();
#pragma unroll
    for (int mi = 0; mi < 4; ++mi)
#pragma unroll
        for (int rr = 0; rr < 4; ++rr) {
            f32x4 rv = *(const f32x4*)rowred[wm * 64 + mi * 16 + lg * 4 + rr];
            mrow[mi][rr] = fmaxf(fmaxf(rv[0], rv[1]), fmaxf(rv[2], rv[3]));
        }
    __syncthreads();
    float srow[4][4];
#pragma unroll
    for (int mi = 0; mi < 4; ++mi)
#pragma unroll
        for (int rr = 0; rr < 4; ++rr) {
            float s = 0.f;
            float m = mrow[mi][rr];
#pragma unroll
            for (int ni = 0; ni < 8; ++ni) {
                float pp = exp2f((acc[mi][ni][rr] - m) * LOG2E);
                acc[mi][ni][rr] = pp;
                s += pp;
            }
            s += __shfl_xor(s, 1);
            s += __shfl_xor(s, 2);
            s += __shfl_xor(s, 4);
            s += __shfl_xor(s, 8);
            srow[mi][rr] = s;
        }
    if (lr == 0) {
#pragma unroll
        for (int mi = 0; mi < 4; ++mi)
#pragma unroll
            for (int rr = 0; rr < 4; ++rr)
                rowred[wm * 64 + mi * 16 + lg * 4 + rr][wn] = srow[mi][rr];
    }
    __syncthreads();
#pragma unroll
    for (int mi = 0; mi < 4; ++mi)
#pragma unroll
        for (int rr = 0; rr < 4; ++rr) {
            f32x4 rv = *(const f32x4*)rowred[wm * 64 + mi * 16 + lg * 4 + rr];
            srow[mi][rr] = 1.f / (rv[0] + rv[1] + rv[2] + rv[3]);
        }

    // ---- write normalized P (f16) ----
#pragma unroll
    for (int mi = 0; mi < 4; ++mi)
#pragma unroll
        for (int ni = 0; ni < 8; ++ni)
#pragma unroll
            for (int rr = 0; rr < 4; ++rr) {
                int r = r0 + wm * 64 + mi * 16 + lg * 4 + rr;
                int l = wn * 128 + ni * 16 + lr;
                Gp[((size_t)b * RR + r) * LL + l] = (_Float16)(acc[mi][ni][rr] * srow[mi][rr]);
            }
}

// ---------- wo MFMA, BK=64, counted-vmcnt double-buffered pipeline ----------
__global__ __launch_bounds__(256) void k_wo_mfma(
    const short* __restrict__ convfl, const short* __restrict__ P,
    float* __restrict__ out) {
    int wg = xcd_swz(blockIdx.x, 2048);
    int b = wg >> 4;
    int f0 = ((wg >> 2) & 3) * 128;   // M
    int r0 = (wg & 3) * 128;          // N
    int tid = threadIdx.x, lane = tid & 63, w = tid >> 6;
    int wm = w >> 1, wn = w & 1;
    int lr = lane & 15, lg = lane >> 4;

    // dbuf: buf t at smem + (t&1)*32768 {A 16384, B 16384}
    __shared__ __align__(16) char smem[65536];

    f32x4 acc[4][4];
    for (int i = 0; i < 4; ++i)
        for (int j = 0; j < 4; ++j) acc[i][j] = (f32x4){0.f, 0.f, 0.f, 0.f};

    int rowA = lane >> 3;
    int sw = (lane & 7) ^ rowA;
    const short* gA = convfl + (size_t)b * NF * LL + (size_t)(f0 + w * 32 + rowA) * LL + sw * 8;
    const short* gB = P + (size_t)b * RR * LL + (size_t)(r0 + w * 32 + rowA) * LL + sw * 8;
    int rA = wm * 64, rB = wn * 64;
    int p7 = lr & 7;

    // prologue: stage tile 0 into buf 0 (8 loads/thread)
    {
        char* nbuf = smem;
#pragma unroll
        for (int c = 0; c < 4; ++c) {
            stage16(gA + (size_t)(8 * c) * LL, nbuf + w * 4096 + c * 1024);
            stage16(gB + (size_t)(8 * c) * LL, nbuf + 16384 + w * 4096 + c * 1024);
        }
    }

    for (int t = 0; t < 8; ++t) {
        char* cbuf = smem + (t & 1) * 32768;
        if (t + 1 < 8) {
            char* nbuf = smem + ((t + 1) & 1) * 32768;
            int k0 = (t + 1) * 64;
#pragma unroll
            for (int c = 0; c < 4; ++c) {
                stage16(gA + (size_t)(8 * c) * LL + k0, nbuf + w * 4096 + c * 1024);
                stage16(gB + (size_t)(8 * c) * LL + k0, nbuf + 16384 + w * 4096 + c * 1024);
            }
            asm volatile("s_waitcnt vmcnt(8)" ::: "memory");
        } else {
            asm volatile("s_waitcnt vmcnt(0)" ::: "memory");
        }
        __builtin_amdgcn_s_barrier();
        __builtin_amdgcn_sched_barrier(0);
        const short (*Ac)[64] = (const short(*)[64])cbuf;
        const short (*Bc)[64] = (const short(*)[64])(cbuf + 16384);
#pragma unroll
        for (int kk = 0; kk < 2; ++kk) {
            half8 af[4], bf[4];
            int cs = ((kk << 2) + lg);
#pragma unroll
            for (int mi = 0; mi < 4; ++mi)
                af[mi] = *(const half8*)(&Ac[rA + mi * 16 + lr][(cs ^ p7) * 8]);
#pragma unroll
            for (int ni = 0; ni < 4; ++ni)
                bf[ni] = *(const half8*)(&Bc[rB + ni * 16 + lr][(cs ^ p7) * 8]);
#pragma unroll
            for (int mi = 0; mi < 4; ++mi)
#pragma unroll
                for (int ni = 0; ni < 4; ++ni)
                    acc[mi][ni] = __builtin_amdgcn_mfma_f32_16x16x32_f16(
                        af[mi], bf[ni], acc[mi][ni], 0, 0, 0);
        }
        __builtin_amdgcn_sched_barrier(0);
        __builtin_amdgcn_s_barrier();
        __builtin_amdgcn_sched_barrier(0);
    }

    int fbase = f0 + wm * 64;
#pragma unroll
    for (int mi = 0; mi < 4; ++mi)
#pragma unroll
        for (int rr = 0; rr < 4; ++rr) {
            float m = acc[mi][0][rr];
#pragma unroll
            for (int ni = 1; ni < 4; ++ni) m = fmaxf(m, acc[mi][ni][rr]);
            m = fmaxf(m, __shfl_xor(m, 1));
            m = fmaxf(m, __shfl_xor(m, 2));
            m = fmaxf(m, __shfl_xor(m, 4));
            m = fmaxf(m, __shfl_xor(m, 8));
            if (lr == 0 && m > 0.f) {
                int f = fbase + mi * 16 + lg * 4 + rr;
                atomicMax((int*)&out[(size_t)b * NF + f], __float_as_int(m));
            }
        }
}

extern "C" void kernel_launch(void* const* d_in, const int* in_sizes, int n_in,
                              void* d_out, int out_size, void* d_ws, size_t ws_size,
                              hipStream_t stream) {
    const float* x      = (const float*)d_in[0];
    const float* e1     = (const float*)d_in[1];
    const float* e2     = (const float*)d_in[2];
    const float* posVec = (const float*)d_in[3];
    const float* We1    = (const float*)d_in[4];
    const float* We2    = (const float*)d_in[5];
    const float* U      = (const float*)d_in[6];
    const float* conv_w = (const float*)d_in[7];
    const float* conv_b = (const float*)d_in[8];
    const float* rel_w  = (const float*)d_in[9];
    float* out = (float*)d_out;

    // workspace: convlf 67M | convfl 67M | Gp 67M | pxp 50.5M | cwb 1.2M
    //            Qf 0.5M | small 1M  -> 254.6 MB (< 256 MiB)
    char* p = (char*)d_ws;
    short* convlf = (short*)p;  p += (size_t)BB * LL * NF * 2;
    short* convfl = (short*)p;  p += (size_t)BB * NF * LL * 2;
    _Float16* Gp  = (_Float16*)p;  p += (size_t)BB * RR * LL * 2;
    short* pxp    = (short*)p;  p += (size_t)BB * LP * DD * 2;
    short* cwb    = (short*)p;  p += (size_t)NF * DWIN * 2;
    short* QfW    = (short*)p;  p += (size_t)RR * NF * 2;
    float* v1     = (float*)p;  p += (size_t)BB * DW * 4;
    float* v2     = (float*)p;  p += (size_t)BB * DW * 4;
    float* A1     = (float*)p;  p += (size_t)BB * LL * 4;
    float* A2     = (float*)p;  p += (size_t)BB * LL * 4;
    float* alpha  = (float*)p;  p += (size_t)BB * LL * 4;

    k_ve<<<BB, DW, 0, stream>>>(We1, We2, e1, e2, v1, v2);
    k_pack_logits<<<(BB * LP) / 4, 256, 0, stream>>>(x, posVec, v1, v2, pxp, A1, A2);
    k_alpha<<<BB, LL, 0, stream>>>(A1, A2, alpha);
    k_pack_w<<<(NF * DWIN / 8) / 256, 256, 0, stream>>>(conv_w, cwb);
    k_w2t<<<dim3(NF / 64, RR / 64), 256, 0, stream>>>(U, rel_w, QfW);
    k_conv_mfma<<<2048, 256, 0, stream>>>(pxp, cwb, conv_b, alpha, convlf, convfl);
    k_g_mfma<<<512, 512, 0, stream>>>(QfW, convlf, Gp);
    hipMemsetAsync(d_out, 0, (size_t)BB * NF * sizeof(float), stream);
    k_wo_mfma<<<2048, 256, 0, stream>>>(convfl, (const short*)Gp, out);
    hipMemcpyAsync(out + BB * NF, rel_w, (size_t)NF * RR * sizeof(float),
                   hipMemcpyDeviceToDevice, stream);
}

// Round 14
// 315.503 us; speedup vs baseline: 1.2874x; 1.0356x over previous
//
#include <hip/hip_runtime.h>
#include <hip/hip_bf16.h>

#define BB 128
#define LL 512
#define DW 256
#define DP 64
#define NF 512
#define DD 384       // D = DW + 2*DP
#define DWIN 1152    // 3*D
#define RR 512       // nr
#define LP 514       // LL + 2 pad rows

typedef __attribute__((ext_vector_type(8))) short short8;
typedef __attribute__((ext_vector_type(4))) short short4v;
typedef __attribute__((ext_vector_type(2))) short short2v;
typedef __attribute__((ext_vector_type(8))) _Float16 half8;
typedef __attribute__((ext_vector_type(4))) float f32x4;
typedef __attribute__((ext_vector_type(2))) float f32x2;

typedef __attribute__((address_space(1))) const void* gas_t;
typedef __attribute__((address_space(3))) void* las_t;

__device__ __forceinline__ void stage16(const void* g, void* l) {
    __builtin_amdgcn_global_load_lds((gas_t)g, (las_t)l, 16, 0, 0);
}

__device__ inline short f2h(float v) {
    _Float16 h = (_Float16)v;
    return *reinterpret_cast<short*>(&h);
}
// XCD-chunked bijective swizzle (nwg % 8 == 0)
__device__ inline int xcd_swz(int bid, int nwg) {
    return (bid & 7) * (nwg >> 3) + (bid >> 3);
}

// ---------- small kernels (fp32-exact path for alpha) ----------
__global__ void k_ve(const float* __restrict__ We1, const float* __restrict__ We2,
                     const float* __restrict__ e1, const float* __restrict__ e2,
                     float* __restrict__ v1, float* __restrict__ v2) {
    int b = blockIdx.x;
    int d = threadIdx.x; // 256
    __shared__ float s1[DW], s2[DW];
    s1[d] = e1[b * DW + d];
    s2[d] = e2[b * DW + d];
    __syncthreads();
    float a1 = 0.f, a2 = 0.f;
    for (int e = 0; e < DW; ++e) {
        a1 += We1[d * DW + e] * s1[e];
        a2 += We2[d * DW + e] * s2[e];
    }
    v1[b * DW + d] = a1;
    v2[b * DW + d] = a2;
}

// fused: pack px row to f16 AND compute logits (one x read total)
__global__ __launch_bounds__(256) void k_pack_logits(
    const float* __restrict__ x, const float* __restrict__ pv,
    const float* __restrict__ v1, const float* __restrict__ v2,
    short* __restrict__ pxp, float* __restrict__ A1, float* __restrict__ A2) {
    int gr = blockIdx.x * 4 + (threadIdx.x >> 6);    // 0 .. BB*LP-1
    int lane = threadIdx.x & 63;
    int b = gr / LP;
    int rr = gr - b * LP;
    short* dst = pxp + (size_t)gr * DD;
    if (rr == 0 || rr == LP - 1) {
        *(short4v*)(dst + lane * 4) = (short4v){0, 0, 0, 0};
        *(short2v*)(dst + 256 + lane * 2) = (short2v){0, 0};
        return;
    }
    int l = rr - 1;
    f32x4 xv = *(const f32x4*)(x + ((size_t)b * LL + l) * DW + lane * 4);
    f32x2 pvv = *(const f32x2*)(pv + ((size_t)b * LL + l) * (2 * DP) + lane * 2);
    f32x4 w1 = *(const f32x4*)(v1 + b * DW + lane * 4);
    f32x4 w2 = *(const f32x4*)(v2 + b * DW + lane * 4);
    float p1 = xv[0] * w1[0] + xv[1] * w1[1] + xv[2] * w1[2] + xv[3] * w1[3];
    float p2 = xv[0] * w2[0] + xv[1] * w2[1] + xv[2] * w2[2] + xv[3] * w2[3];
    for (int off = 32; off; off >>= 1) {
        p1 += __shfl_down(p1, off);
        p2 += __shfl_down(p2, off);
    }
    short4v ox;
#pragma unroll
    for (int j = 0; j < 4; ++j) ox[j] = f2h(xv[j]);
    *(short4v*)(dst + lane * 4) = ox;
    short2v op;
    op[0] = f2h(pvv[0]);
    op[1] = f2h(pvv[1]);
    *(short2v*)(dst + 256 + lane * 2) = op;
    if (lane == 0) { A1[b * LL + l] = p1; A2[b * LL + l] = p2; }
}

__global__ void k_alpha(const float* __restrict__ A1, const float* __restrict__ A2,
                        float* __restrict__ alpha) {
    int b = blockIdx.x;
    int l = threadIdx.x; // 512
    __shared__ float s[LL];
    float a1 = A1[b * LL + l], a2 = A2[b * LL + l];

    s[l] = a1; __syncthreads();
    for (int st = 256; st; st >>= 1) { if (l < st) s[l] = fmaxf(s[l], s[l + st]); __syncthreads(); }
    float m1 = s[0]; __syncthreads();
    float e1x = expf(a1 - m1);
    s[l] = e1x; __syncthreads();
    for (int st = 256; st; st >>= 1) { if (l < st) s[l] += s[l + st]; __syncthreads(); }
    float d1 = s[0]; __syncthreads();

    s[l] = a2; __syncthreads();
    for (int st = 256; st; st >>= 1) { if (l < st) s[l] = fmaxf(s[l], s[l + st]); __syncthreads(); }
    float m2 = s[0]; __syncthreads();
    float e2x = expf(a2 - m2);
    s[l] = e2x; __syncthreads();
    for (int st = 256; st; st >>= 1) { if (l < st) s[l] += s[l + st]; __syncthreads(); }
    float d2 = s[0];

    alpha[b * LL + l] = 0.5f * (e1x / d1 + e2x / d2);
}

__global__ __launch_bounds__(256) void k_pack_w(const float* __restrict__ cw,
                                                short* __restrict__ cwb) {
    int idx = blockIdx.x * 256 + threadIdx.x;   // 512*1152/8 = 73,728
    const float* src = cw + (size_t)idx * 8;
    f32x4 u0 = *(const f32x4*)(src);
    f32x4 u1 = *(const f32x4*)(src + 4);
    short8 v;
#pragma unroll
    for (int jj = 0; jj < 4; ++jj) { v[jj] = f2h(u0[jj]); v[jj + 4] = f2h(u1[jj]); }
    *(short8*)(cwb + (size_t)idx * 8) = v;
}

// ---------- W2t[r][f] = sum_t rel_w[r,t]*U[f,t], f16 out ----------
__global__ void k_w2t(const float* __restrict__ U, const float* __restrict__ relw,
                      short* __restrict__ Qf) {
    __shared__ float As[16][65], Bs[16][65];
    int r0 = blockIdx.y * 64, f0 = blockIdx.x * 64;
    int tid = threadIdx.x, ty = tid >> 4, tx = tid & 15;
    float acc[4][4] = {};
    for (int k0 = 0; k0 < NF; k0 += 16) {
        for (int i = 0; i < 4; ++i) {
            int lin = tid + 256 * i;
            int kk = lin & 15, mm = lin >> 4;
            As[kk][mm] = relw[(r0 + mm) * NF + k0 + kk];
            Bs[kk][mm] = U[(f0 + mm) * NF + k0 + kk];
        }
        __syncthreads();
        for (int kk = 0; kk < 16; ++kk) {
            float av[4], bv[4];
            for (int i = 0; i < 4; ++i) av[i] = As[kk][ty * 4 + i];
            for (int j = 0; j < 4; ++j) bv[j] = Bs[kk][tx * 4 + j];
            for (int i = 0; i < 4; ++i)
                for (int j = 0; j < 4; ++j) acc[i][j] += av[i] * bv[j];
        }
        __syncthreads();
    }
    for (int i = 0; i < 4; ++i)
        for (int j = 0; j < 4; ++j)
            Qf[(size_t)(r0 + ty * 4 + i) * NF + f0 + tx * 4 + j] = f2h(acc[i][j]);
}

// ---------- conv MFMA: 256x256 tile, 8 waves, BK=64, dbuf, deep reuse ----------
// A[l][k]=pxp windowed flat rows, B[f][k]=cwb. K=1152 (18 tiles of 64).
// Per wave: 128(l) x 64(f) output, acc[8][4]. One barrier per K-tile.
__global__ __launch_bounds__(512, 2) void k_conv_mfma(
    const short* __restrict__ pxp, const short* __restrict__ cwb,
    const float* __restrict__ conv_b, const float* __restrict__ alpha,
    short* __restrict__ conv_lf, short* __restrict__ conv_fl) {
    int wg = xcd_swz(blockIdx.x, 512);
    int b = wg >> 2;
    int bl0 = ((wg >> 1) & 1) * 256;
    int bf0 = (wg & 1) * 256;
    int tid = threadIdx.x;
    int lane = tid & 63, w = tid >> 6;      // 8 waves
    int wm = w >> 2, wn = w & 3;            // 2(m) x 4(n)
    int lr = lane & 15, lg = lane >> 4;

    // dbuf: tile t at smem + (t&1)*65536 { A[256][64] 32KB, B[256][64] 32KB }
    // epilogue union: T[256 f][256 l] f16 = 128KB with 16B-chunk XOR swizzle
    __shared__ __align__(16) char smem[131072];

    f32x4 acc[8][4];
#pragma unroll
    for (int i = 0; i < 8; ++i)
#pragma unroll
        for (int j = 0; j < 4; ++j) acc[i][j] = (f32x4){0.f, 0.f, 0.f, 0.f};

    // staging geometry: per sweep c (64 rows), wave w covers rows c*64+w*8+(lane>>3),
    // slot = lane&7 holds global chunk slot^ (row&7); row&7 == (lane>>3)&7
    int srow = lane >> 3;                     // 0..7
    int sw = (lane & 7) ^ srow;               // pre-swizzled source chunk
    const short* gA = pxp + ((size_t)b * LP + bl0 + w * 8 + srow) * DD + sw * 8;
    const short* gB = cwb + (size_t)(bf0 + w * 8 + srow) * DWIN + sw * 8;
    int p7 = lr & 7;

    // prologue: stage tile 0 into buf 0
    {
        char* nb = smem;
#pragma unroll
        for (int c = 0; c < 4; ++c) {
            stage16(gA + (size_t)(64 * c) * DD, nb + (c * 64 + w * 8) * 128);
            stage16(gB + (size_t)(64 * c) * DWIN, nb + 32768 + (c * 64 + w * 8) * 128);
        }
    }
    __syncthreads();

    for (int kt = 0; kt < 18; ++kt) {
        const char* cb = smem + (kt & 1) * 65536;
        // issue-early: stage tile kt+1 into the other buffer
        if (kt + 1 < 18) {
            char* nb = smem + ((kt + 1) & 1) * 65536;
            int k0 = (kt + 1) * 64;
#pragma unroll
            for (int c = 0; c < 4; ++c) {
                stage16(gA + (size_t)(64 * c) * DD + k0, nb + (c * 64 + w * 8) * 128);
                stage16(gB + (size_t)(64 * c) * DWIN + k0, nb + 32768 + (c * 64 + w * 8) * 128);
            }
        }
        // B fragments: all 4 n-frags x 2 k-slices (reused across both m-halves)
        half8 bf[4][2];
#pragma unroll
        for (int ni = 0; ni < 4; ++ni)
#pragma unroll
            for (int ks = 0; ks < 2; ++ks) {
                int cs = ks * 4 + lg;
                bf[ni][ks] = *(const half8*)(cb + 32768 +
                    (wn * 64 + ni * 16 + lr) * 128 + ((cs ^ p7) * 16));
            }
#pragma unroll
        for (int mh = 0; mh < 2; ++mh) {
            half8 af[4][2];
#pragma unroll
            for (int mi = 0; mi < 4; ++mi)
#pragma unroll
                for (int ks = 0; ks < 2; ++ks) {
                    int cs = ks * 4 + lg;
                    af[mi][ks] = *(const half8*)(cb +
                        (wm * 128 + mh * 64 + mi * 16 + lr) * 128 + ((cs ^ p7) * 16));
                }
            __builtin_amdgcn_s_setprio(1);
#pragma unroll
            for (int mi = 0; mi < 4; ++mi)
#pragma unroll
                for (int ni = 0; ni < 4; ++ni)
#pragma unroll
                    for (int ks = 0; ks < 2; ++ks)
                        acc[mh * 4 + mi][ni] = __builtin_amdgcn_mfma_f32_16x16x32_f16(
                            af[mi][ks], bf[ni][ks], acc[mh * 4 + mi][ni], 0, 0, 0);
            __builtin_amdgcn_s_setprio(0);
        }
        __syncthreads();   // drains kt+1 loads (full-tile cover) + releases cb
    }

    // ---- epilogue: tanh once; conv_lf direct; conv_fl via swizzled T union ----
    // T byte addr: row*512 + ((chunk16 ^ (row&31))<<4) + (col&7)*2, row=f_local, col=l_local
    char* T = smem;
#pragma unroll
    for (int mi = 0; mi < 8; ++mi) {
        int lloc = wm * 128 + mi * 16 + lg * 4;
        int l = bl0 + lloc;
        f32x4 av = *(const f32x4*)(alpha + (size_t)b * LL + l);
#pragma unroll
        for (int ni = 0; ni < 4; ++ni) {
            int floc = wn * 64 + ni * 16 + lr;
            int f = bf0 + floc;
            float bias = conv_b[f];
            short4v o;
#pragma unroll
            for (int r = 0; r < 4; ++r) {
                float val = tanhf(av[r] * acc[mi][ni][r] + bias);
                short sv = f2h(val);
                o[r] = sv;
                conv_lf[((size_t)b * LL + l + r) * NF + f] = sv;
            }
            int c16 = lloc >> 3;
            *(short4v*)(T + floc * 512 + ((c16 ^ (floc & 31)) << 4) + (lloc & 7) * 2) = o;
        }
    }
    __syncthreads();
#pragma unroll
    for (int i = 0; i < 16; ++i) {
        int lin = tid + 512 * i;            // 0..8191
        int frow = lin >> 5;                // 0..255
        int c16 = lin & 31;
        short8 v = *(const short8*)(T + frow * 512 + ((c16 ^ (frow & 31)) << 4));
        *(short8*)(conv_fl + ((size_t)b * NF + bf0 + frow) * LL + bl0 + c16 * 8) = v;
    }
}

// ---------- G+softmax fused: P[b][r][l] = softmax_l( Qf[r,:]·conv_lf[b,l,:] ) ----------
// tile: 128 r x 512 l (full rows), K=512, BK=64, 512 threads (2x4 waves)
__global__ __launch_bounds__(512) void k_g_mfma(
    const short* __restrict__ Qf,
    const short* __restrict__ convlf, _Float16* __restrict__ Gp) {
    const float LOG2E = 1.4426950408889634f;
    int wg = xcd_swz(blockIdx.x, 512);
    int b = wg >> 2;                  // 0..127
    int r0 = (wg & 3) * 128;
    int tid = threadIdx.x, lane = tid & 63, w = tid >> 6;
    int wm = w >> 2, wn = w & 3;      // 2 x 4 wave grid
    int lr = lane & 15, lg = lane >> 4;

    // A tile 128x64 f16 = 16KB; B tile 512x64 f16 = 64KB
    __shared__ __align__(16) char smem[81920];
    short* Ab = (short*)smem;
    short* Bb = (short*)(smem + 16384);
    float (*rowred)[4] = (float(*)[4])smem;   // epilogue reuse (2KB)

    f32x4 acc[4][8];
#pragma unroll
    for (int i = 0; i < 4; ++i)
#pragma unroll
        for (int j = 0; j < 8; ++j) acc[i][j] = (f32x4){0.f, 0.f, 0.f, 0.f};

    int trow = tid >> 3;                   // 0..63
    int sw = (tid & 7) ^ (trow & 7);       // pre-swizzled source chunk
    const short* gA = Qf + (size_t)(r0 + trow) * NF + sw * 8;
    const short* gB = convlf + (size_t)b * LL * NF + (size_t)trow * NF + sw * 8;
    short* lAd = Ab + w * 512;             // per-wave dest base (shorts)
    short* lBd = Bb + w * 512;
    int p7 = lr & 7;

    for (int kb = 0; kb < 8; ++kb) {
        int k0 = kb * 64;
#pragma unroll
        for (int c = 0; c < 2; ++c)
            stage16(gA + (size_t)(64 * c) * NF + k0, lAd + c * 4096);
#pragma unroll
        for (int c = 0; c < 8; ++c)
            stage16(gB + (size_t)(64 * c) * NF + k0, lBd + c * 4096);
        __syncthreads();
#pragma unroll
        for (int kk = 0; kk < 2; ++kk) {
            int cs = (kk << 2) + lg;
            half8 af[4], bf[8];
#pragma unroll
            for (int mi = 0; mi < 4; ++mi)
                af[mi] = *(const half8*)(Ab + (wm * 64 + mi * 16 + lr) * 64 + ((cs ^ p7) * 8));
#pragma unroll
            for (int ni = 0; ni < 8; ++ni)
                bf[ni] = *(const half8*)(Bb + (wn * 128 + ni * 16 + lr) * 64 + ((cs ^ p7) * 8));
#pragma unroll
            for (int mi = 0; mi < 4; ++mi)
#pragma unroll
                for (int ni = 0; ni < 8; ++ni)
                    acc[mi][ni] = __builtin_amdgcn_mfma_f32_16x16x32_f16(
                        af[mi], bf[ni], acc[mi][ni], 0, 0, 0);
        }
        __syncthreads();
    }

    // ---- in-register softmax over full l rows ----
    float mrow[4][4];
#pragma unroll
    for (int mi = 0; mi < 4; ++mi)
#pragma unroll
        for (int rr = 0; rr < 4; ++rr) {
            float m = acc[mi][0][rr];
#pragma unroll
            for (int ni = 1; ni < 8; ++ni) m = fmaxf(m, acc[mi][ni][rr]);
            m = fmaxf(m, __shfl_xor(m, 1));
            m = fmaxf(m, __shfl_xor(m, 2));
            m = fmaxf(m, __shfl_xor(m, 4));
            m = fmaxf(m, __shfl_xor(m, 8));
            mrow[mi][rr] = m;
        }
    if (lr == 0) {
#pragma unroll
        for (int mi = 0; mi < 4; ++mi)
#pragma unroll
            for (int rr = 0; rr < 4; ++rr)
                rowred[wm * 64 + mi * 16 + lg * 4 + rr][wn] = mrow[mi][rr];
    }
    __syncthreads();
#pragma unroll
    for (int mi = 0; mi < 4; ++mi)
#pragma unroll
        for (int rr = 0; rr < 4; ++rr) {
            f32x4 rv = *(const f32x4*)rowred[wm * 64 + mi * 16 + lg * 4 + rr];
            mrow[mi][rr] = fmaxf(fmaxf(rv[0], rv[1]), fmaxf(rv[2], rv[3]));
        }
    __syncthreads();
    float srow[4][4];
#pragma unroll
    for (int mi = 0; mi < 4; ++mi)
#pragma unroll
        for (int rr = 0; rr < 4; ++rr) {
            float s = 0.f;
            float m = mrow[mi][rr];
#pragma unroll
            for (int ni = 0; ni < 8; ++ni) {
                float pp = exp2f((acc[mi][ni][rr] - m) * LOG2E);
                acc[mi][ni][rr] = pp;
                s += pp;
            }
            s += __shfl_xor(s, 1);
            s += __shfl_xor(s, 2);
            s += __shfl_xor(s, 4);
            s += __shfl_xor(s, 8);
            srow[mi][rr] = s;
        }
    if (lr == 0) {
#pragma unroll
        for (int mi = 0; mi < 4; ++mi)
#pragma unroll
            for (int rr = 0; rr < 4; ++rr)
                rowred[wm * 64 + mi * 16 + lg * 4 + rr][wn] = srow[mi][rr];
    }
    __syncthreads();
#pragma unroll
    for (int mi = 0; mi < 4; ++mi)
#pragma unroll
        for (int rr = 0; rr < 4; ++rr) {
            f32x4 rv = *(const f32x4*)rowred[wm * 64 + mi * 16 + lg * 4 + rr];
            srow[mi][rr] = 1.f / (rv[0] + rv[1] + rv[2] + rv[3]);
        }

    // ---- write normalized P (f16) ----
#pragma unroll
    for (int mi = 0; mi < 4; ++mi)
#pragma unroll
        for (int ni = 0; ni < 8; ++ni)
#pragma unroll
            for (int rr = 0; rr < 4; ++rr) {
                int r = r0 + wm * 64 + mi * 16 + lg * 4 + rr;
                int l = wn * 128 + ni * 16 + lr;
                Gp[((size_t)b * RR + r) * LL + l] = (_Float16)(acc[mi][ni][rr] * srow[mi][rr]);
            }
}

// ---------- wo MFMA, BK=64, counted-vmcnt double-buffered pipeline ----------
__global__ __launch_bounds__(256) void k_wo_mfma(
    const short* __restrict__ convfl, const short* __restrict__ P,
    float* __restrict__ out) {
    int wg = xcd_swz(blockIdx.x, 2048);
    int b = wg >> 4;
    int f0 = ((wg >> 2) & 3) * 128;   // M
    int r0 = (wg & 3) * 128;          // N
    int tid = threadIdx.x, lane = tid & 63, w = tid >> 6;
    int wm = w >> 1, wn = w & 1;
    int lr = lane & 15, lg = lane >> 4;

    // dbuf: buf t at smem + (t&1)*32768 {A 16384, B 16384}
    __shared__ __align__(16) char smem[65536];

    f32x4 acc[4][4];
    for (int i = 0; i < 4; ++i)
        for (int j = 0; j < 4; ++j) acc[i][j] = (f32x4){0.f, 0.f, 0.f, 0.f};

    int rowA = lane >> 3;
    int sw = (lane & 7) ^ rowA;
    const short* gA = convfl + (size_t)b * NF * LL + (size_t)(f0 + w * 32 + rowA) * LL + sw * 8;
    const short* gB = P + (size_t)b * RR * LL + (size_t)(r0 + w * 32 + rowA) * LL + sw * 8;
    int rA = wm * 64, rB = wn * 64;
    int p7 = lr & 7;

    // prologue: stage tile 0 into buf 0 (8 loads/thread)
    {
        char* nbuf = smem;
#pragma unroll
        for (int c = 0; c < 4; ++c) {
            stage16(gA + (size_t)(8 * c) * LL, nbuf + w * 4096 + c * 1024);
            stage16(gB + (size_t)(8 * c) * LL, nbuf + 16384 + w * 4096 + c * 1024);
        }
    }

    for (int t = 0; t < 8; ++t) {
        char* cbuf = smem + (t & 1) * 32768;
        if (t + 1 < 8) {
            char* nbuf = smem + ((t + 1) & 1) * 32768;
            int k0 = (t + 1) * 64;
#pragma unroll
            for (int c = 0; c < 4; ++c) {
                stage16(gA + (size_t)(8 * c) * LL + k0, nbuf + w * 4096 + c * 1024);
                stage16(gB + (size_t)(8 * c) * LL + k0, nbuf + 16384 + w * 4096 + c * 1024);
            }
            asm volatile("s_waitcnt vmcnt(8)" ::: "memory");
        } else {
            asm volatile("s_waitcnt vmcnt(0)" ::: "memory");
        }
        __builtin_amdgcn_s_barrier();
        __builtin_amdgcn_sched_barrier(0);
        const short (*Ac)[64] = (const short(*)[64])cbuf;
        const short (*Bc)[64] = (const short(*)[64])(cbuf + 16384);
#pragma unroll
        for (int kk = 0; kk < 2; ++kk) {
            half8 af[4], bf[4];
            int cs = ((kk << 2) + lg);
#pragma unroll
            for (int mi = 0; mi < 4; ++mi)
                af[mi] = *(const half8*)(&Ac[rA + mi * 16 + lr][(cs ^ p7) * 8]);
#pragma unroll
            for (int ni = 0; ni < 4; ++ni)
                bf[ni] = *(const half8*)(&Bc[rB + ni * 16 + lr][(cs ^ p7) * 8]);
#pragma unroll
            for (int mi = 0; mi < 4; ++mi)
#pragma unroll
                for (int ni = 0; ni < 4; ++ni)
                    acc[mi][ni] = __builtin_amdgcn_mfma_f32_16x16x32_f16(
                        af[mi], bf[ni], acc[mi][ni], 0, 0, 0);
        }
        __builtin_amdgcn_sched_barrier(0);
        __builtin_amdgcn_s_barrier();
        __builtin_amdgcn_sched_barrier(0);
    }

    int fbase = f0 + wm * 64;
#pragma unroll
    for (int mi = 0; mi < 4; ++mi)
#pragma unroll
        for (int rr = 0; rr < 4; ++rr) {
            float m = acc[mi][0][rr];
#pragma unroll
            for (int ni = 1; ni < 4; ++ni) m = fmaxf(m, acc[mi][ni][rr]);
            m = fmaxf(m, __shfl_xor(m, 1));
            m = fmaxf(m, __shfl_xor(m, 2));
            m = fmaxf(m, __shfl_xor(m, 4));
            m = fmaxf(m, __shfl_xor(m, 8));
            if (lr == 0 && m > 0.f) {
                int f = fbase + mi * 16 + lg * 4 + rr;
                atomicMax((int*)&out[(size_t)b * NF + f], __float_as_int(m));
            }
        }
}

extern "C" void kernel_launch(void* const* d_in, const int* in_sizes, int n_in,
                              void* d_out, int out_size, void* d_ws, size_t ws_size,
                              hipStream_t stream) {
    const float* x      = (const float*)d_in[0];
    const float* e1     = (const float*)d_in[1];
    const float* e2     = (const float*)d_in[2];
    const float* posVec = (const float*)d_in[3];
    const float* We1    = (const float*)d_in[4];
    const float* We2    = (const float*)d_in[5];
    const float* U      = (const float*)d_in[6];
    const float* conv_w = (const float*)d_in[7];
    const float* conv_b = (const float*)d_in[8];
    const float* rel_w  = (const float*)d_in[9];
    float* out = (float*)d_out;

    // workspace: convlf 67M | convfl 67M | Gp 67M | pxp 50.5M | cwb 1.2M
    //            Qf 0.5M | small 1M  -> 254.6 MB (< 256 MiB)
    char* p = (char*)d_ws;
    short* convlf = (short*)p;  p += (size_t)BB * LL * NF * 2;
    short* convfl = (short*)p;  p += (size_t)BB * NF * LL * 2;
    _Float16* Gp  = (_Float16*)p;  p += (size_t)BB * RR * LL * 2;
    short* pxp    = (short*)p;  p += (size_t)BB * LP * DD * 2;
    short* cwb    = (short*)p;  p += (size_t)NF * DWIN * 2;
    short* QfW    = (short*)p;  p += (size_t)RR * NF * 2;
    float* v1     = (float*)p;  p += (size_t)BB * DW * 4;
    float* v2     = (float*)p;  p += (size_t)BB * DW * 4;
    float* A1     = (float*)p;  p += (size_t)BB * LL * 4;
    float* A2     = (float*)p;  p += (size_t)BB * LL * 4;
    float* alpha  = (float*)p;  p += (size_t)BB * LL * 4;

    k_ve<<<BB, DW, 0, stream>>>(We1, We2, e1, e2, v1, v2);
    k_pack_logits<<<(BB * LP) / 4, 256, 0, stream>>>(x, posVec, v1, v2, pxp, A1, A2);
    k_alpha<<<BB, LL, 0, stream>>>(A1, A2, alpha);
    k_pack_w<<<(NF * DWIN / 8) / 256, 256, 0, stream>>>(conv_w, cwb);
    k_w2t<<<dim3(NF / 64, RR / 64), 256, 0, stream>>>(U, rel_w, QfW);
    k_conv_mfma<<<512, 512, 0, stream>>>(pxp, cwb, conv_b, alpha, convlf, convfl);
    k_g_mfma<<<512, 512, 0, stream>>>(QfW, convlf, Gp);
    hipMemsetAsync(d_out, 0, (size_t)BB * NF * sizeof(float), stream);
    k_wo_mfma<<<2048, 256, 0, stream>>>(convfl, (const short*)Gp, out);
    hipMemcpyAsync(out + BB * NF, rel_w, (size_t)NF * RR * sizeof(float),
                   hipMemcpyDeviceToDevice, stream);
}

// Round 15
// 306.629 us; speedup vs baseline: 1.3246x; 1.0289x over previous
//
#include <hip/hip_runtime.h>
#include <hip/hip_bf16.h>

#define BB 128
#define LL 512
#define DW 256
#define DP 64
#define NF 512
#define DD 384       // D = DW + 2*DP
#define DWIN 1152    // 3*D
#define RR 512       // nr
#define LP 514       // LL + 2 pad rows

typedef __attribute__((ext_vector_type(8))) short short8;
typedef __attribute__((ext_vector_type(4))) short short4v;
typedef __attribute__((ext_vector_type(2))) short short2v;
typedef __attribute__((ext_vector_type(8))) _Float16 half8;
typedef __attribute__((ext_vector_type(4))) float f32x4;
typedef __attribute__((ext_vector_type(2))) float f32x2;

typedef __attribute__((address_space(1))) const void* gas_t;
typedef __attribute__((address_space(3))) void* las_t;

__device__ __forceinline__ void stage16(const void* g, void* l) {
    __builtin_amdgcn_global_load_lds((gas_t)g, (las_t)l, 16, 0, 0);
}

__device__ inline short f2h(float v) {
    _Float16 h = (_Float16)v;
    return *reinterpret_cast<short*>(&h);
}
// XCD-chunked bijective swizzle (nwg % 8 == 0)
__device__ inline int xcd_swz(int bid, int nwg) {
    return (bid & 7) * (nwg >> 3) + (bid >> 3);
}

// ---------- small kernels (fp32-exact path for alpha) ----------
__global__ void k_ve(const float* __restrict__ We1, const float* __restrict__ We2,
                     const float* __restrict__ e1, const float* __restrict__ e2,
                     float* __restrict__ v1, float* __restrict__ v2) {
    int b = blockIdx.x;
    int d = threadIdx.x; // 256
    __shared__ float s1[DW], s2[DW];
    s1[d] = e1[b * DW + d];
    s2[d] = e2[b * DW + d];
    __syncthreads();
    float a1 = 0.f, a2 = 0.f;
    for (int e = 0; e < DW; ++e) {
        a1 += We1[d * DW + e] * s1[e];
        a2 += We2[d * DW + e] * s2[e];
    }
    v1[b * DW + d] = a1;
    v2[b * DW + d] = a2;
}

// fused: pack px row to f16 AND compute logits (one x read total)
__global__ __launch_bounds__(256) void k_pack_logits(
    const float* __restrict__ x, const float* __restrict__ pv,
    const float* __restrict__ v1, const float* __restrict__ v2,
    short* __restrict__ pxp, float* __restrict__ A1, float* __restrict__ A2) {
    int gr = blockIdx.x * 4 + (threadIdx.x >> 6);    // 0 .. BB*LP-1
    int lane = threadIdx.x & 63;
    int b = gr / LP;
    int rr = gr - b * LP;
    short* dst = pxp + (size_t)gr * DD;
    if (rr == 0 || rr == LP - 1) {
        *(short4v*)(dst + lane * 4) = (short4v){0, 0, 0, 0};
        *(short2v*)(dst + 256 + lane * 2) = (short2v){0, 0};
        return;
    }
    int l = rr - 1;
    f32x4 xv = *(const f32x4*)(x + ((size_t)b * LL + l) * DW + lane * 4);
    f32x2 pvv = *(const f32x2*)(pv + ((size_t)b * LL + l) * (2 * DP) + lane * 2);
    f32x4 w1 = *(const f32x4*)(v1 + b * DW + lane * 4);
    f32x4 w2 = *(const f32x4*)(v2 + b * DW + lane * 4);
    float p1 = xv[0] * w1[0] + xv[1] * w1[1] + xv[2] * w1[2] + xv[3] * w1[3];
    float p2 = xv[0] * w2[0] + xv[1] * w2[1] + xv[2] * w2[2] + xv[3] * w2[3];
    for (int off = 32; off; off >>= 1) {
        p1 += __shfl_down(p1, off);
        p2 += __shfl_down(p2, off);
    }
    short4v ox;
#pragma unroll
    for (int j = 0; j < 4; ++j) ox[j] = f2h(xv[j]);
    *(short4v*)(dst + lane * 4) = ox;
    short2v op;
    op[0] = f2h(pvv[0]);
    op[1] = f2h(pvv[1]);
    *(short2v*)(dst + 256 + lane * 2) = op;
    if (lane == 0) { A1[b * LL + l] = p1; A2[b * LL + l] = p2; }
}

__global__ void k_alpha(const float* __restrict__ A1, const float* __restrict__ A2,
                        float* __restrict__ alpha) {
    int b = blockIdx.x;
    int l = threadIdx.x; // 512
    __shared__ float s[LL];
    float a1 = A1[b * LL + l], a2 = A2[b * LL + l];

    s[l] = a1; __syncthreads();
    for (int st = 256; st; st >>= 1) { if (l < st) s[l] = fmaxf(s[l], s[l + st]); __syncthreads(); }
    float m1 = s[0]; __syncthreads();
    float e1x = expf(a1 - m1);
    s[l] = e1x; __syncthreads();
    for (int st = 256; st; st >>= 1) { if (l < st) s[l] += s[l + st]; __syncthreads(); }
    float d1 = s[0]; __syncthreads();

    s[l] = a2; __syncthreads();
    for (int st = 256; st; st >>= 1) { if (l < st) s[l] = fmaxf(s[l], s[l + st]); __syncthreads(); }
    float m2 = s[0]; __syncthreads();
    float e2x = expf(a2 - m2);
    s[l] = e2x; __syncthreads();
    for (int st = 256; st; st >>= 1) { if (l < st) s[l] += s[l + st]; __syncthreads(); }
    float d2 = s[0];

    alpha[b * LL + l] = 0.5f * (e1x / d1 + e2x / d2);
}

__global__ __launch_bounds__(256) void k_pack_w(const float* __restrict__ cw,
                                                short* __restrict__ cwb) {
    int idx = blockIdx.x * 256 + threadIdx.x;   // 512*1152/8 = 73,728
    const float* src = cw + (size_t)idx * 8;
    f32x4 u0 = *(const f32x4*)(src);
    f32x4 u1 = *(const f32x4*)(src + 4);
    short8 v;
#pragma unroll
    for (int jj = 0; jj < 4; ++jj) { v[jj] = f2h(u0[jj]); v[jj + 4] = f2h(u1[jj]); }
    *(short8*)(cwb + (size_t)idx * 8) = v;
}

// ---------- W2t[r][f] = sum_t rel_w[r,t]*U[f,t], f16 out ----------
__global__ void k_w2t(const float* __restrict__ U, const float* __restrict__ relw,
                      short* __restrict__ Qf) {
    __shared__ float As[16][65], Bs[16][65];
    int r0 = blockIdx.y * 64, f0 = blockIdx.x * 64;
    int tid = threadIdx.x, ty = tid >> 4, tx = tid & 15;
    float acc[4][4] = {};
    for (int k0 = 0; k0 < NF; k0 += 16) {
        for (int i = 0; i < 4; ++i) {
            int lin = tid + 256 * i;
            int kk = lin & 15, mm = lin >> 4;
            As[kk][mm] = relw[(r0 + mm) * NF + k0 + kk];
            Bs[kk][mm] = U[(f0 + mm) * NF + k0 + kk];
        }
        __syncthreads();
        for (int kk = 0; kk < 16; ++kk) {
            float av[4], bv[4];
            for (int i = 0; i < 4; ++i) av[i] = As[kk][ty * 4 + i];
            for (int j = 0; j < 4; ++j) bv[j] = Bs[kk][tx * 4 + j];
            for (int i = 0; i < 4; ++i)
                for (int j = 0; j < 4; ++j) acc[i][j] += av[i] * bv[j];
        }
        __syncthreads();
    }
    for (int i = 0; i < 4; ++i)
        for (int j = 0; j < 4; ++j)
            Qf[(size_t)(r0 + ty * 4 + i) * NF + f0 + tx * 4 + j] = f2h(acc[i][j]);
}

// ---------- conv MFMA: 256x256 tile, 16 waves (4m x 4n), BK=64, dbuf ----------
// A[l][k]=pxp windowed flat rows, B[f][k]=cwb. K=1152 (18 tiles of 64).
// Per wave: 64(l) x 64(f) output, acc[4][4]. One barrier per K-tile.
__global__ __launch_bounds__(1024) void k_conv_mfma(
    const short* __restrict__ pxp, const short* __restrict__ cwb,
    const float* __restrict__ conv_b, const float* __restrict__ alpha,
    short* __restrict__ conv_lf, short* __restrict__ conv_fl) {
    int wg = xcd_swz(blockIdx.x, 512);
    int b = wg >> 2;
    int bl0 = ((wg >> 1) & 1) * 256;
    int bf0 = (wg & 1) * 256;
    int tid = threadIdx.x;
    int lane = tid & 63, w = tid >> 6;      // 16 waves
    int wm = w >> 2, wn = w & 3;            // 4(m) x 4(n)
    int lr = lane & 15, lg = lane >> 4;

    // dbuf: tile t at smem + (t&1)*65536 { A[256][64] 32KB, B[256][64] 32KB }
    // epilogue union: T[256 f][256 l] f16 = 128KB with 16B-chunk XOR swizzle
    __shared__ __align__(16) char smem[131072];

    f32x4 acc[4][4];
#pragma unroll
    for (int i = 0; i < 4; ++i)
#pragma unroll
        for (int j = 0; j < 4; ++j) acc[i][j] = (f32x4){0.f, 0.f, 0.f, 0.f};

    // staging: per call 128 rows; wave w covers rows w*8+(lane>>3), chunk lane&7;
    // call c adds 128 rows. slot s of row r holds global chunk s ^ (r&7).
    int srow = lane >> 3;                     // 0..7
    int sw = (lane & 7) ^ srow;               // pre-swizzled source chunk
    const short* gA = pxp + ((size_t)b * LP + bl0 + w * 8 + srow) * DD + sw * 8;
    const short* gB = cwb + (size_t)(bf0 + w * 8 + srow) * DWIN + sw * 8;
    int p7 = lr & 7;

    // prologue: stage tile 0 into buf 0
    {
        char* nb = smem;
#pragma unroll
        for (int c = 0; c < 2; ++c) {
            stage16(gA + (size_t)(128 * c) * DD, nb + (c * 128 + w * 8) * 128);
            stage16(gB + (size_t)(128 * c) * DWIN, nb + 32768 + (c * 128 + w * 8) * 128);
        }
    }
    __syncthreads();

    for (int kt = 0; kt < 18; ++kt) {
        const char* cb = smem + (kt & 1) * 65536;
        // issue-early: stage tile kt+1 into the other buffer
        if (kt + 1 < 18) {
            char* nb = smem + ((kt + 1) & 1) * 65536;
            int k0 = (kt + 1) * 64;
#pragma unroll
            for (int c = 0; c < 2; ++c) {
                stage16(gA + (size_t)(128 * c) * DD + k0, nb + (c * 128 + w * 8) * 128);
                stage16(gB + (size_t)(128 * c) * DWIN + k0, nb + 32768 + (c * 128 + w * 8) * 128);
            }
        }
#pragma unroll
        for (int ks = 0; ks < 2; ++ks) {
            int cs = ks * 4 + lg;
            int slot = (cs ^ p7) * 16;
            half8 af[4], bf[4];
#pragma unroll
            for (int mi = 0; mi < 4; ++mi)
                af[mi] = *(const half8*)(cb + (wm * 64 + mi * 16 + lr) * 128 + slot);
#pragma unroll
            for (int ni = 0; ni < 4; ++ni)
                bf[ni] = *(const half8*)(cb + 32768 + (wn * 64 + ni * 16 + lr) * 128 + slot);
            __builtin_amdgcn_s_setprio(1);
#pragma unroll
            for (int mi = 0; mi < 4; ++mi)
#pragma unroll
                for (int ni = 0; ni < 4; ++ni)
                    acc[mi][ni] = __builtin_amdgcn_mfma_f32_16x16x32_f16(
                        af[mi], bf[ni], acc[mi][ni], 0, 0, 0);
            __builtin_amdgcn_s_setprio(0);
        }
        __syncthreads();   // drains kt+1 loads (full-tile cover) + releases cb
    }

    // ---- epilogue: tanh once; conv_lf direct; conv_fl via swizzled T union ----
    // T byte addr: frow*512 + ((c16 ^ (frow&31))<<4) + (lloc&7)*2, frow=f_local, lloc=l_local
    char* T = smem;
#pragma unroll
    for (int mi = 0; mi < 4; ++mi) {
        int lloc = wm * 64 + mi * 16 + lg * 4;
        int l = bl0 + lloc;
        f32x4 av = *(const f32x4*)(alpha + (size_t)b * LL + l);
#pragma unroll
        for (int ni = 0; ni < 4; ++ni) {
            int floc = wn * 64 + ni * 16 + lr;
            int f = bf0 + floc;
            float bias = conv_b[f];
            short4v o;
#pragma unroll
            for (int r = 0; r < 4; ++r) {
                float val = tanhf(av[r] * acc[mi][ni][r] + bias);
                short sv = f2h(val);
                o[r] = sv;
                conv_lf[((size_t)b * LL + l + r) * NF + f] = sv;
            }
            int c16 = lloc >> 3;
            *(short4v*)(T + floc * 512 + ((c16 ^ (floc & 31)) << 4) + (lloc & 7) * 2) = o;
        }
    }
    __syncthreads();
#pragma unroll
    for (int i = 0; i < 8; ++i) {
        int lin = tid + 1024 * i;           // 0..8191
        int frow = lin >> 5;                // 0..255
        int c16 = lin & 31;
        short8 v = *(const short8*)(T + frow * 512 + ((c16 ^ (frow & 31)) << 4));
        *(short8*)(conv_fl + ((size_t)b * NF + bf0 + frow) * LL + bl0 + c16 * 8) = v;
    }
}

// ---------- G+softmax fused: P[b][r][l] = softmax_l( Qf[r,:]·conv_lf[b,l,:] ) ----------
// tile: 128 r x 512 l (full rows), K=512, BK=64, 512 threads (2x4 waves)
__global__ __launch_bounds__(512) void k_g_mfma(
    const short* __restrict__ Qf,
    const short* __restrict__ convlf, _Float16* __restrict__ Gp) {
    const float LOG2E = 1.4426950408889634f;
    int wg = xcd_swz(blockIdx.x, 512);
    int b = wg >> 2;                  // 0..127
    int r0 = (wg & 3) * 128;
    int tid = threadIdx.x, lane = tid & 63, w = tid >> 6;
    int wm = w >> 2, wn = w & 3;      // 2 x 4 wave grid
    int lr = lane & 15, lg = lane >> 4;

    // A tile 128x64 f16 = 16KB; B tile 512x64 f16 = 64KB
    __shared__ __align__(16) char smem[81920];
    short* Ab = (short*)smem;
    short* Bb = (short*)(smem + 16384);
    float (*rowred)[4] = (float(*)[4])smem;   // epilogue reuse (2KB)

    f32x4 acc[4][8];
#pragma unroll
    for (int i = 0; i < 4; ++i)
#pragma unroll
        for (int j = 0; j < 8; ++j) acc[i][j] = (f32x4){0.f, 0.f, 0.f, 0.f};

    int trow = tid >> 3;                   // 0..63
    int sw = (tid & 7) ^ (trow & 7);       // pre-swizzled source chunk
    const short* gA = Qf + (size_t)(r0 + trow) * NF + sw * 8;
    const short* gB = convlf + (size_t)b * LL * NF + (size_t)trow * NF + sw * 8;
    short* lAd = Ab + w * 512;             // per-wave dest base (shorts)
    short* lBd = Bb + w * 512;
    int p7 = lr & 7;

    for (int kb = 0; kb < 8; ++kb) {
        int k0 = kb * 64;
#pragma unroll
        for (int c = 0; c < 2; ++c)
            stage16(gA + (size_t)(64 * c) * NF + k0, lAd + c * 4096);
#pragma unroll
        for (int c = 0; c < 8; ++c)
            stage16(gB + (size_t)(64 * c) * NF + k0, lBd + c * 4096);
        __syncthreads();
#pragma unroll
        for (int kk = 0; kk < 2; ++kk) {
            int cs = (kk << 2) + lg;
            half8 af[4], bf[8];
#pragma unroll
            for (int mi = 0; mi < 4; ++mi)
                af[mi] = *(const half8*)(Ab + (wm * 64 + mi * 16 + lr) * 64 + ((cs ^ p7) * 8));
#pragma unroll
            for (int ni = 0; ni < 8; ++ni)
                bf[ni] = *(const half8*)(Bb + (wn * 128 + ni * 16 + lr) * 64 + ((cs ^ p7) * 8));
#pragma unroll
            for (int mi = 0; mi < 4; ++mi)
#pragma unroll
                for (int ni = 0; ni < 8; ++ni)
                    acc[mi][ni] = __builtin_amdgcn_mfma_f32_16x16x32_f16(
                        af[mi], bf[ni], acc[mi][ni], 0, 0, 0);
        }
        __syncthreads();
    }

    // ---- in-register softmax over full l rows ----
    float mrow[4][4];
#pragma unroll
    for (int mi = 0; mi < 4; ++mi)
#pragma unroll
        for (int rr = 0; rr < 4; ++rr) {
            float m = acc[mi][0][rr];
#pragma unroll
            for (int ni = 1; ni < 8; ++ni) m = fmaxf(m, acc[mi][ni][rr]);
            m = fmaxf(m, __shfl_xor(m, 1));
            m = fmaxf(m, __shfl_xor(m, 2));
            m = fmaxf(m, __shfl_xor(m, 4));
            m = fmaxf(m, __shfl_xor(m, 8));
            mrow[mi][rr] = m;
        }
    if (lr == 0) {
#pragma unroll
        for (int mi = 0; mi < 4; ++mi)
#pragma unroll
            for (int rr = 0; rr < 4; ++rr)
                rowred[wm * 64 + mi * 16 + lg * 4 + rr][wn] = mrow[mi][rr];
    }
    __syncthreads();
#pragma unroll
    for (int mi = 0; mi < 4; ++mi)
#pragma unroll
        for (int rr = 0; rr < 4; ++rr) {
            f32x4 rv = *(const f32x4*)rowred[wm * 64 + mi * 16 + lg * 4 + rr];
            mrow[mi][rr] = fmaxf(fmaxf(rv[0], rv[1]), fmaxf(rv[2], rv[3]));
        }
    __syncthreads();
    float srow[4][4];
#pragma unroll
    for (int mi = 0; mi < 4; ++mi)
#pragma unroll
        for (int rr = 0; rr < 4; ++rr) {
            float s = 0.f;
            float m = mrow[mi][rr];
#pragma unroll
            for (int ni = 0; ni < 8; ++ni) {
                float pp = exp2f((acc[mi][ni][rr] - m) * LOG2E);
                acc[mi][ni][rr] = pp;
                s += pp;
            }
            s += __shfl_xor(s, 1);
            s += __shfl_xor(s, 2);
            s += __shfl_xor(s, 4);
            s += __shfl_xor(s, 8);
            srow[mi][rr] = s;
        }
    if (lr == 0) {
#pragma unroll
        for (int mi = 0; mi < 4; ++mi)
#pragma unroll
            for (int rr = 0; rr < 4; ++rr)
                rowred[wm * 64 + mi * 16 + lg * 4 + rr][wn] = srow[mi][rr];
    }
    __syncthreads();
#pragma unroll
    for (int mi = 0; mi < 4; ++mi)
#pragma unroll
        for (int rr = 0; rr < 4; ++rr) {
            f32x4 rv = *(const f32x4*)rowred[wm * 64 + mi * 16 + lg * 4 + rr];
            srow[mi][rr] = 1.f / (rv[0] + rv[1] + rv[2] + rv[3]);
        }

    // ---- write normalized P (f16) ----
#pragma unroll
    for (int mi = 0; mi < 4; ++mi)
#pragma unroll
        for (int ni = 0; ni < 8; ++ni)
#pragma unroll
            for (int rr = 0; rr < 4; ++rr) {
                int r = r0 + wm * 64 + mi * 16 + lg * 4 + rr;
                int l = wn * 128 + ni * 16 + lr;
                Gp[((size_t)b * RR + r) * LL + l] = (_Float16)(acc[mi][ni][rr] * srow[mi][rr]);
            }
}

// ---------- wo MFMA, BK=64, counted-vmcnt double-buffered pipeline ----------
__global__ __launch_bounds__(256) void k_wo_mfma(
    const short* __restrict__ convfl, const short* __restrict__ P,
    float* __restrict__ out) {
    int wg = xcd_swz(blockIdx.x, 2048);
    int b = wg >> 4;
    int f0 = ((wg >> 2) & 3) * 128;   // M
    int r0 = (wg & 3) * 128;          // N
    int tid = threadIdx.x, lane = tid & 63, w = tid >> 6;
    int wm = w >> 1, wn = w & 1;
    int lr = lane & 15, lg = lane >> 4;

    // dbuf: buf t at smem + (t&1)*32768 {A 16384, B 16384}
    __shared__ __align__(16) char smem[65536];

    f32x4 acc[4][4];
    for (int i = 0; i < 4; ++i)
        for (int j = 0; j < 4; ++j) acc[i][j] = (f32x4){0.f, 0.f, 0.f, 0.f};

    int rowA = lane >> 3;
    int sw = (lane & 7) ^ rowA;
    const short* gA = convfl + (size_t)b * NF * LL + (size_t)(f0 + w * 32 + rowA) * LL + sw * 8;
    const short* gB = P + (size_t)b * RR * LL + (size_t)(r0 + w * 32 + rowA) * LL + sw * 8;
    int rA = wm * 64, rB = wn * 64;
    int p7 = lr & 7;

    // prologue: stage tile 0 into buf 0 (8 loads/thread)
    {
        char* nbuf = smem;
#pragma unroll
        for (int c = 0; c < 4; ++c) {
            stage16(gA + (size_t)(8 * c) * LL, nbuf + w * 4096 + c * 1024);
            stage16(gB + (size_t)(8 * c) * LL, nbuf + 16384 + w * 4096 + c * 1024);
        }
    }

    for (int t = 0; t < 8; ++t) {
        char* cbuf = smem + (t & 1) * 32768;
        if (t + 1 < 8) {
            char* nbuf = smem + ((t + 1) & 1) * 32768;
            int k0 = (t + 1) * 64;
#pragma unroll
            for (int c = 0; c < 4; ++c) {
                stage16(gA + (size_t)(8 * c) * LL + k0, nbuf + w * 4096 + c * 1024);
                stage16(gB + (size_t)(8 * c) * LL + k0, nbuf + 16384 + w * 4096 + c * 1024);
            }
            asm volatile("s_waitcnt vmcnt(8)" ::: "memory");
        } else {
            asm volatile("s_waitcnt vmcnt(0)" ::: "memory");
        }
        __builtin_amdgcn_s_barrier();
        __builtin_amdgcn_sched_barrier(0);
        const short (*Ac)[64] = (const short(*)[64])cbuf;
        const short (*Bc)[64] = (const short(*)[64])(cbuf + 16384);
#pragma unroll
        for (int kk = 0; kk < 2; ++kk) {
            half8 af[4], bf[4];
            int cs = ((kk << 2) + lg);
#pragma unroll
            for (int mi = 0; mi < 4; ++mi)
                af[mi] = *(const half8*)(&Ac[rA + mi * 16 + lr][(cs ^ p7) * 8]);
#pragma unroll
            for (int ni = 0; ni < 4; ++ni)
                bf[ni] = *(const half8*)(&Bc[rB + ni * 16 + lr][(cs ^ p7) * 8]);
#pragma unroll
            for (int mi = 0; mi < 4; ++mi)
#pragma unroll
                for (int ni = 0; ni < 4; ++ni)
                    acc[mi][ni] = __builtin_amdgcn_mfma_f32_16x16x32_f16(
                        af[mi], bf[ni], acc[mi][ni], 0, 0, 0);
        }
        __builtin_amdgcn_sched_barrier(0);
        __builtin_amdgcn_s_barrier();
        __builtin_amdgcn_sched_barrier(0);
    }

    int fbase = f0 + wm * 64;
#pragma unroll
    for (int mi = 0; mi < 4; ++mi)
#pragma unroll
        for (int rr = 0; rr < 4; ++rr) {
            float m = acc[mi][0][rr];
#pragma unroll
            for (int ni = 1; ni < 4; ++ni) m = fmaxf(m, acc[mi][ni][rr]);
            m = fmaxf(m, __shfl_xor(m, 1));
            m = fmaxf(m, __shfl_xor(m, 2));
            m = fmaxf(m, __shfl_xor(m, 4));
            m = fmaxf(m, __shfl_xor(m, 8));
            if (lr == 0 && m > 0.f) {
                int f = fbase + mi * 16 + lg * 4 + rr;
                atomicMax((int*)&out[(size_t)b * NF + f], __float_as_int(m));
            }
        }
}

extern "C" void kernel_launch(void* const* d_in, const int* in_sizes, int n_in,
                              void* d_out, int out_size, void* d_ws, size_t ws_size,
                              hipStream_t stream) {
    const float* x      = (const float*)d_in[0];
    const float* e1     = (const float*)d_in[1];
    const float* e2     = (const float*)d_in[2];
    const float* posVec = (const float*)d_in[3];
    const float* We1    = (const float*)d_in[4];
    const float* We2    = (const float*)d_in[5];
    const float* U      = (const float*)d_in[6];
    const float* conv_w = (const float*)d_in[7];
    const float* conv_b = (const float*)d_in[8];
    const float* rel_w  = (const float*)d_in[9];
    float* out = (float*)d_out;

    // workspace: convlf 67M | convfl 67M | Gp 67M | pxp 50.5M | cwb 1.2M
    //            Qf 0.5M | small 1M  -> 254.6 MB (< 256 MiB)
    char* p = (char*)d_ws;
    short* convlf = (short*)p;  p += (size_t)BB * LL * NF * 2;
    short* convfl = (short*)p;  p += (size_t)BB * NF * LL * 2;
    _Float16* Gp  = (_Float16*)p;  p += (size_t)BB * RR * LL * 2;
    short* pxp    = (short*)p;  p += (size_t)BB * LP * DD * 2;
    short* cwb    = (short*)p;  p += (size_t)NF * DWIN * 2;
    short* QfW    = (short*)p;  p += (size_t)RR * NF * 2;
    float* v1     = (float*)p;  p += (size_t)BB * DW * 4;
    float* v2     = (float*)p;  p += (size_t)BB * DW * 4;
    float* A1     = (float*)p;  p += (size_t)BB * LL * 4;
    float* A2     = (float*)p;  p += (size_t)BB * LL * 4;
    float* alpha  = (float*)p;  p += (size_t)BB * LL * 4;

    k_ve<<<BB, DW, 0, stream>>>(We1, We2, e1, e2, v1, v2);
    k_pack_logits<<<(BB * LP) / 4, 256, 0, stream>>>(x, posVec, v1, v2, pxp, A1, A2);
    k_alpha<<<BB, LL, 0, stream>>>(A1, A2, alpha);
    k_pack_w<<<(NF * DWIN / 8) / 256, 256, 0, stream>>>(conv_w, cwb);
    k_w2t<<<dim3(NF / 64, RR / 64), 256, 0, stream>>>(U, rel_w, QfW);
    k_conv_mfma<<<512, 1024, 0, stream>>>(pxp, cwb, conv_b, alpha, convlf, convfl);
    k_g_mfma<<<512, 512, 0, stream>>>(QfW, convlf, Gp);
    hipMemsetAsync(d_out, 0, (size_t)BB * NF * sizeof(float), stream);
    k_wo_mfma<<<2048, 256, 0, stream>>>(convfl, (const short*)Gp, out);
    hipMemcpyAsync(out + BB * NF, rel_w, (size_t)NF * RR * sizeof(float),
                   hipMemcpyDeviceToDevice, stream);
}